// Round 3
// baseline (957.735 us; speedup 1.0000x reference)
//
#include <hip/hip_runtime.h>
#include <hip/hip_bf16.h>
#include <math.h>

// Problem constants
#define B_SZ 4
#define L_SZ 8192
#define DM 512           // D_MODEL
#define DMEM 512         // D_MEM
#define M1 (B_SZ * (L_SZ - 1))   // 32764 rows for the av GEMM
#define M2 (B_SZ * L_SZ)         // 32768 rows for GEMM2/3

typedef _Float16 h16;
typedef __attribute__((ext_vector_type(2))) _Float16 f16x2;
typedef __attribute__((ext_vector_type(4))) _Float16 f16x4;
typedef __attribute__((ext_vector_type(8))) _Float16 f16x8;
typedef __attribute__((ext_vector_type(4))) float f32x4;

#define MFMA16(a, b, c) __builtin_amdgcn_mfma_f32_16x16x32_f16((a), (b), (c), 0, 0, 0)

// ---------------------------------------------------------------------------
// Precompute: fp32 -> fp16 single (activations)
// ---------------------------------------------------------------------------
__global__ __launch_bounds__(256) void conv_single(
    const float* __restrict__ src, h16* __restrict__ dst, int n4)
{
    int i = blockIdx.x * 256 + threadIdx.x;
    if (i >= n4) return;
    float4 v = ((const float4*)src)[i];
    f16x4 o = { (h16)v.x, (h16)v.y, (h16)v.z, (h16)v.w };
    ((f16x4*)dst)[i] = o;
}

// Precompute: fp32 -> fp16 hi/lo split (weights)
__global__ __launch_bounds__(256) void conv_split(
    const float* __restrict__ src, h16* __restrict__ h, h16* __restrict__ l, int n4)
{
    int i = blockIdx.x * 256 + threadIdx.x;
    if (i >= n4) return;
    float4 v = ((const float4*)src)[i];
    f16x4 hh, ll;
    hh.x = (h16)v.x; ll.x = (h16)(v.x - (float)hh.x);
    hh.y = (h16)v.y; ll.y = (h16)(v.y - (float)hh.y);
    hh.z = (h16)v.z; ll.z = (h16)(v.z - (float)hh.z);
    hh.w = (h16)v.w; ll.w = (h16)(v.w - (float)hh.w);
    ((f16x4*)h)[i] = hh;
    ((f16x4*)l)[i] = ll;
}

// ---------------------------------------------------------------------------
// GEMM1 (grouped x4, fp16 A x split-fp16 W, 2 MFMA terms) + NRU combine.
// BM=128, BN=64 per group (x4 groups), BK=32. 4 waves (2m x 2n).
// ---------------------------------------------------------------------------
__global__ __launch_bounds__(256) void gemm_av_mfma(
    const h16* __restrict__ xh, const h16* __restrict__ Wh, const h16* __restrict__ Wl,
    const float* __restrict__ bav, float* __restrict__ ms_inp)
{
    __shared__ __align__(16) h16 As[128][40];
    __shared__ __align__(16) h16 Bh[4][64][40];
    __shared__ __align__(16) h16 Bl[4][64][40];

    const int tid  = threadIdx.x;
    const int lane = tid & 63;
    const int w    = tid >> 6;
    const int wm   = (w & 1) * 64;
    const int wn   = (w >> 1) * 32;
    const int bm   = blockIdx.x * 128;
    const int bn   = blockIdx.y * 64;
    const int ln   = lane & 15;
    const int ko   = (lane >> 4) * 8;

    // staging addresses (fixed per thread; only k0 varies)
    const h16* asrc[2]; h16* adst[2];
    #pragma unroll
    for (int i = 0; i < 2; ++i) {
        int s = tid + i * 256;
        int row = s >> 2, cc = s & 3;
        int m = bm + row;
        int mg = m < M1 ? m : (M1 - 1);
        int xr = mg + mg / (L_SZ - 1);          // skip last l of each batch
        asrc[i] = xh + (size_t)xr * DM + cc * 8;
        adst[i] = &As[row][cc * 8];
    }
    const h16 *bsH[4], *bsL[4]; h16 *bdH[4], *bdL[4];
    #pragma unroll
    for (int i = 0; i < 4; ++i) {
        int s = tid + i * 256;
        int g = s >> 8, rem = s & 255;
        int n = rem >> 2, cc = rem & 3;
        size_t off = (size_t)(g * 512 + bn + n) * DM + cc * 8;
        bsH[i] = Wh + off; bsL[i] = Wl + off;
        bdH[i] = &Bh[g][n][cc * 8]; bdL[i] = &Bl[g][n][cc * 8];
    }

    f32x4 acc[4][4][2];     // [g][fm][fn]
    #pragma unroll
    for (int g = 0; g < 4; ++g)
        #pragma unroll
        for (int a = 0; a < 4; ++a)
            #pragma unroll
            for (int b = 0; b < 2; ++b) acc[g][a][b] = (f32x4){0.f, 0.f, 0.f, 0.f};

    int4 ra[2], rh[4], rl[4];
    #pragma unroll
    for (int i = 0; i < 2; ++i) ra[i] = *(const int4*)asrc[i];
    #pragma unroll
    for (int i = 0; i < 4; ++i) { rh[i] = *(const int4*)bsH[i]; rl[i] = *(const int4*)bsL[i]; }

    for (int k0 = 0; k0 < DM; k0 += 32) {
        __syncthreads();
        #pragma unroll
        for (int i = 0; i < 2; ++i) *(int4*)adst[i] = ra[i];
        #pragma unroll
        for (int i = 0; i < 4; ++i) { *(int4*)bdH[i] = rh[i]; *(int4*)bdL[i] = rl[i]; }
        __syncthreads();
        if (k0 + 32 < DM) {     // issue next-tile loads before compute
            #pragma unroll
            for (int i = 0; i < 2; ++i) ra[i] = *(const int4*)(asrc[i] + k0 + 32);
            #pragma unroll
            for (int i = 0; i < 4; ++i) {
                rh[i] = *(const int4*)(bsH[i] + k0 + 32);
                rl[i] = *(const int4*)(bsL[i] + k0 + 32);
            }
        }
        f16x8 a[4];
        #pragma unroll
        for (int fm = 0; fm < 4; ++fm) a[fm] = *(const f16x8*)&As[wm + fm * 16 + ln][ko];
        #pragma unroll
        for (int g = 0; g < 4; ++g) {
            #pragma unroll
            for (int fn = 0; fn < 2; ++fn) {
                f16x8 bh = *(const f16x8*)&Bh[g][wn + fn * 16 + ln][ko];
                f16x8 bl = *(const f16x8*)&Bl[g][wn + fn * 16 + ln][ko];
                #pragma unroll
                for (int fm = 0; fm < 4; ++fm) {
                    acc[g][fm][fn] = MFMA16(a[fm], bh, acc[g][fm][fn]);
                    acc[g][fm][fn] = MFMA16(a[fm], bl, acc[g][fm][fn]);
                }
            }
        }
    }

    const int lm = (lane >> 4) * 4;
    #pragma unroll
    for (int fm = 0; fm < 4; ++fm) {
        #pragma unroll
        for (int fn = 0; fn < 2; ++fn) {
            int n = bn + wn + fn * 16 + ln;
            float b0 = bav[n], b1 = bav[n + 512], b2 = bav[n + 1024], b3 = bav[n + 1536];
            #pragma unroll
            for (int i = 0; i < 4; ++i) {
                int m = bm + wm + fm * 16 + lm + i;
                if (m < M1) {
                    float a0 = acc[0][fm][fn][i] + b0;
                    float a1 = acc[1][fm][fn][i] + b1;
                    float a2 = acc[2][fm][fn][i] + b2;
                    float a3 = acc[3][fm][fn][i] + b3;
                    ms_inp[(size_t)m * DMEM + n] = a0 * a1 - a2 * a3;
                }
            }
        }
    }
}

// ---------------------------------------------------------------------------
// Chunked cumsum (fp32), pass3 emits fp16 ms.
// ---------------------------------------------------------------------------
__global__ __launch_bounds__(256) void scan_pass1(
    const float* __restrict__ ms_inp, float* __restrict__ csum)
{
    int c = blockIdx.x, b = blockIdx.y;
    int l0 = c * 128;
    int len = min(128, (L_SZ - 1) - l0);
    int t = threadIdx.x;
    const float2* p = (const float2*)(ms_inp + ((size_t)b * (L_SZ - 1) + l0) * DMEM) + t;
    float2 s = make_float2(0.f, 0.f);
    for (int i = 0; i < len; ++i) {
        float2 v = p[(size_t)i * 256];
        s.x += v.x; s.y += v.y;
    }
    ((float2*)(csum + ((size_t)b * 64 + c) * DMEM))[t] = s;
}

__global__ __launch_bounds__(256) void scan_pass2(float* __restrict__ csum)
{
    int idx = blockIdx.x * 256 + threadIdx.x;
    int b = idx >> 9, d = idx & 511;
    float run = 0.f;
    float* p = csum + (size_t)b * 64 * DMEM + d;
    for (int c = 0; c < 64; ++c) {
        float t = p[(size_t)c * DMEM];
        p[(size_t)c * DMEM] = run;
        run += t;
    }
}

__global__ __launch_bounds__(256) void scan_pass3(
    const float* __restrict__ ms_inp, const float* __restrict__ csum,
    h16* __restrict__ msh)
{
    int c = blockIdx.x, b = blockIdx.y;
    int l0 = c * 128;
    int len = min(128, (L_SZ - 1) - l0);
    int t = threadIdx.x;
    float2 run = ((const float2*)(csum + ((size_t)b * 64 + c) * DMEM))[t];
    const float2* p = (const float2*)(ms_inp + ((size_t)b * (L_SZ - 1) + l0) * DMEM) + t;
    f16x2* q = (f16x2*)(msh + ((size_t)b * L_SZ + l0 + 1) * DMEM) + t;
    if (c == 0) {
        f16x2 z = { (h16)0.f, (h16)0.f };
        ((f16x2*)(msh + (size_t)b * L_SZ * DMEM))[t] = z;
    }
    for (int i = 0; i < len; ++i) {
        float2 v = p[(size_t)i * 256];
        run.x += v.x; run.y += v.y;
        f16x2 o = { (h16)run.x, (h16)run.y };
        q[(size_t)i * 256] = o;
    }
}

// ---------------------------------------------------------------------------
// GEMM2 (fp16 A x split-fp16 W) + exact GELU -> fp16 y. K=1024 (x || ms).
// BM=128, BN=128, BK=32. 4 waves (2x2), each 64m x 64n.
// ---------------------------------------------------------------------------
__global__ __launch_bounds__(256) void gemm_go_mfma(
    const h16* __restrict__ xh, const h16* __restrict__ msh,
    const h16* __restrict__ Wh, const h16* __restrict__ Wl,
    const float* __restrict__ bgo, h16* __restrict__ yh)
{
    __shared__ __align__(16) h16 As[128][40];
    __shared__ __align__(16) h16 Bh[128][40];
    __shared__ __align__(16) h16 Bl[128][40];

    const int tid  = threadIdx.x;
    const int lane = tid & 63;
    const int w    = tid >> 6;
    const int wm   = (w & 1) * 64;
    const int wn   = (w >> 1) * 64;
    const int bm   = blockIdx.x * 128;
    const int bn   = blockIdx.y * 128;
    const int ln   = lane & 15;
    const int ko   = (lane >> 4) * 8;

    const h16 *axs[2], *ams[2]; h16* adst[2];
    #pragma unroll
    for (int i = 0; i < 2; ++i) {
        int s = tid + i * 256;
        int row = s >> 2, cc = s & 3;
        size_t off = (size_t)(bm + row) * DM + cc * 8;
        axs[i] = xh + off; ams[i] = msh + off;
        adst[i] = &As[row][cc * 8];
    }
    const h16 *bsH[2], *bsL[2]; h16 *bdH[2], *bdL[2];
    #pragma unroll
    for (int i = 0; i < 2; ++i) {
        int s = tid + i * 256;
        int n = s >> 2, cc = s & 3;
        size_t off = (size_t)(bn + n) * 1024 + cc * 8;
        bsH[i] = Wh + off; bsL[i] = Wl + off;
        bdH[i] = &Bh[n][cc * 8]; bdL[i] = &Bl[n][cc * 8];
    }

    f32x4 acc[4][4];
    #pragma unroll
    for (int a = 0; a < 4; ++a)
        #pragma unroll
        for (int b = 0; b < 4; ++b) acc[a][b] = (f32x4){0.f, 0.f, 0.f, 0.f};

    int4 ra[2], rh[2], rl[2];
    #pragma unroll
    for (int i = 0; i < 2; ++i) {
        ra[i] = *(const int4*)axs[i];
        rh[i] = *(const int4*)bsH[i];
        rl[i] = *(const int4*)bsL[i];
    }

    for (int k0 = 0; k0 < 1024; k0 += 32) {
        __syncthreads();
        #pragma unroll
        for (int i = 0; i < 2; ++i) {
            *(int4*)adst[i] = ra[i];
            *(int4*)bdH[i] = rh[i];
            *(int4*)bdL[i] = rl[i];
        }
        __syncthreads();
        if (k0 + 32 < 1024) {
            int kn = k0 + 32;
            #pragma unroll
            for (int i = 0; i < 2; ++i) {
                ra[i] = (kn < 512) ? *(const int4*)(axs[i] + kn)
                                   : *(const int4*)(ams[i] + (kn - 512));
                rh[i] = *(const int4*)(bsH[i] + kn);
                rl[i] = *(const int4*)(bsL[i] + kn);
            }
        }
        f16x8 a[4];
        #pragma unroll
        for (int fm = 0; fm < 4; ++fm) a[fm] = *(const f16x8*)&As[wm + fm * 16 + ln][ko];
        #pragma unroll
        for (int fn = 0; fn < 4; ++fn) {
            f16x8 bh = *(const f16x8*)&Bh[wn + fn * 16 + ln][ko];
            f16x8 bl = *(const f16x8*)&Bl[wn + fn * 16 + ln][ko];
            #pragma unroll
            for (int fm = 0; fm < 4; ++fm) {
                acc[fm][fn] = MFMA16(a[fm], bh, acc[fm][fn]);
                acc[fm][fn] = MFMA16(a[fm], bl, acc[fm][fn]);
            }
        }
    }

    const int lm = (lane >> 4) * 4;
    #pragma unroll
    for (int fm = 0; fm < 4; ++fm) {
        #pragma unroll
        for (int fn = 0; fn < 4; ++fn) {
            int n = bn + wn + fn * 16 + ln;
            float bias = bgo[n];
            #pragma unroll
            for (int i = 0; i < 4; ++i) {
                int m = bm + wm + fm * 16 + lm + i;
                float t = acc[fm][fn][i] + bias;
                float g = 0.5f * t * (1.0f + erff(t * 0.70710678118654752f));
                yh[(size_t)m * DM + n] = (h16)g;
            }
        }
    }
}

// ---------------------------------------------------------------------------
// GEMM3 (grouped x2, fp16 A x split-fp16 W) + GLU -> fp32 out.
// BM=128, BN=64 per group (x2), BK=32. 4 waves (2x2), each 64m x 32n x 2g.
// ---------------------------------------------------------------------------
__global__ __launch_bounds__(256) void gemm_out_mfma(
    const h16* __restrict__ yh, const h16* __restrict__ Wh, const h16* __restrict__ Wl,
    const float* __restrict__ bout, float* __restrict__ out)
{
    __shared__ __align__(16) h16 As[128][40];
    __shared__ __align__(16) h16 Bh[2][64][40];
    __shared__ __align__(16) h16 Bl[2][64][40];

    const int tid  = threadIdx.x;
    const int lane = tid & 63;
    const int w    = tid >> 6;
    const int wm   = (w & 1) * 64;
    const int wn   = (w >> 1) * 32;
    const int bm   = blockIdx.x * 128;
    const int bn   = blockIdx.y * 64;
    const int ln   = lane & 15;
    const int ko   = (lane >> 4) * 8;

    const h16* asrc[2]; h16* adst[2];
    #pragma unroll
    for (int i = 0; i < 2; ++i) {
        int s = tid + i * 256;
        int row = s >> 2, cc = s & 3;
        asrc[i] = yh + (size_t)(bm + row) * DM + cc * 8;
        adst[i] = &As[row][cc * 8];
    }
    const h16 *bsH[2], *bsL[2]; h16 *bdH[2], *bdL[2];
    #pragma unroll
    for (int i = 0; i < 2; ++i) {
        int s = tid + i * 256;
        int g = s >> 8, rem = s & 255;
        int n = rem >> 2, cc = rem & 3;
        size_t off = (size_t)(g * 512 + bn + n) * DM + cc * 8;
        bsH[i] = Wh + off; bsL[i] = Wl + off;
        bdH[i] = &Bh[g][n][cc * 8]; bdL[i] = &Bl[g][n][cc * 8];
    }

    f32x4 acc[2][4][2];
    #pragma unroll
    for (int g = 0; g < 2; ++g)
        #pragma unroll
        for (int a = 0; a < 4; ++a)
            #pragma unroll
            for (int b = 0; b < 2; ++b) acc[g][a][b] = (f32x4){0.f, 0.f, 0.f, 0.f};

    int4 ra[2], rh[2], rl[2];
    #pragma unroll
    for (int i = 0; i < 2; ++i) {
        ra[i] = *(const int4*)asrc[i];
        rh[i] = *(const int4*)bsH[i];
        rl[i] = *(const int4*)bsL[i];
    }

    for (int k0 = 0; k0 < DM; k0 += 32) {
        __syncthreads();
        #pragma unroll
        for (int i = 0; i < 2; ++i) {
            *(int4*)adst[i] = ra[i];
            *(int4*)bdH[i] = rh[i];
            *(int4*)bdL[i] = rl[i];
        }
        __syncthreads();
        if (k0 + 32 < DM) {
            #pragma unroll
            for (int i = 0; i < 2; ++i) {
                ra[i] = *(const int4*)(asrc[i] + k0 + 32);
                rh[i] = *(const int4*)(bsH[i] + k0 + 32);
                rl[i] = *(const int4*)(bsL[i] + k0 + 32);
            }
        }
        f16x8 a[4];
        #pragma unroll
        for (int fm = 0; fm < 4; ++fm) a[fm] = *(const f16x8*)&As[wm + fm * 16 + ln][ko];
        #pragma unroll
        for (int g = 0; g < 2; ++g) {
            #pragma unroll
            for (int fn = 0; fn < 2; ++fn) {
                f16x8 bh = *(const f16x8*)&Bh[g][wn + fn * 16 + ln][ko];
                f16x8 bl = *(const f16x8*)&Bl[g][wn + fn * 16 + ln][ko];
                #pragma unroll
                for (int fm = 0; fm < 4; ++fm) {
                    acc[g][fm][fn] = MFMA16(a[fm], bh, acc[g][fm][fn]);
                    acc[g][fm][fn] = MFMA16(a[fm], bl, acc[g][fm][fn]);
                }
            }
        }
    }

    const int lm = (lane >> 4) * 4;
    #pragma unroll
    for (int fm = 0; fm < 4; ++fm) {
        #pragma unroll
        for (int fn = 0; fn < 2; ++fn) {
            int n = bn + wn + fn * 16 + ln;
            float bz0 = bout[n], bz1 = bout[n + 512];
            #pragma unroll
            for (int i = 0; i < 4; ++i) {
                int m = bm + wm + fm * 16 + lm + i;
                float z0 = acc[0][fm][fn][i] + bz0;
                float z1 = acc[1][fm][fn][i] + bz1;
                out[(size_t)m * DM + n] = z0 * (1.0f / (1.0f + expf(-z1)));
            }
        }
    }
}

// ---------------------------------------------------------------------------
extern "C" void kernel_launch(void* const* d_in, const int* in_sizes, int n_in,
                              void* d_out, int out_size, void* d_ws, size_t ws_size,
                              hipStream_t stream)
{
    const float* x    = (const float*)d_in[0];
    const float* Wav  = (const float*)d_in[1];
    const float* bav  = (const float*)d_in[2];
    const float* Wgo  = (const float*)d_in[3];
    const float* bgo  = (const float*)d_in[4];
    const float* Wout = (const float*)d_in[5];
    const float* bout = (const float*)d_in[6];
    float* out = (float*)d_out;

    char* ws = (char*)d_ws;
    const size_t MB = 1 << 20;
    float* ms_inp = (float*)ws;                   // 64 MiB region [32764,512] f32
    h16*   yh     = (h16*)ws;                     // aliases ms_inp (used after scan)
    h16*   xh     = (h16*)(ws + 64 * MB);         // 32 MiB
    h16*   msh    = (h16*)(ws + 96 * MB);         // 32 MiB
    float* csum   = (float*)(ws + 128 * MB);      // 0.5 MiB
    h16*   Wavh   = (h16*)(ws + 129 * MB);        // 2 MiB
    h16*   Wavl   = (h16*)(ws + 131 * MB);        // 2 MiB
    h16*   Wgoh   = (h16*)(ws + 133 * MB);        // 1 MiB
    h16*   Wgol   = (h16*)(ws + 134 * MB);        // 1 MiB
    h16*   Wouth  = (h16*)(ws + 135 * MB);        // 1 MiB
    h16*   Woutl  = (h16*)(ws + 136 * MB);        // 1 MiB

    // 0) precompute fp16 forms
    conv_single<<<(M2 * DM / 4 + 255) / 256, 256, 0, stream>>>(x, xh, M2 * DM / 4);
    conv_split<<<(2048 * 512 / 4 + 255) / 256, 256, 0, stream>>>(Wav, Wavh, Wavl, 2048 * 512 / 4);
    conv_split<<<(512 * 1024 / 4 + 255) / 256, 256, 0, stream>>>(Wgo, Wgoh, Wgol, 512 * 1024 / 4);
    conv_split<<<(1024 * 512 / 4 + 255) / 256, 256, 0, stream>>>(Wout, Wouth, Woutl, 1024 * 512 / 4);
    // 1) av GEMM + NRU combine -> ms_inp (f32)
    gemm_av_mfma<<<dim3(256, 8), 256, 0, stream>>>(xh, Wavh, Wavl, bav, ms_inp);
    // 2-4) chunked cumsum -> msh (fp16)
    scan_pass1<<<dim3(64, B_SZ), 256, 0, stream>>>(ms_inp, csum);
    scan_pass2<<<8, 256, 0, stream>>>(csum);
    scan_pass3<<<dim3(64, B_SZ), 256, 0, stream>>>(ms_inp, csum, msh);
    // 5) SSM-in GEMM + GELU -> yh (fp16, reuses ms_inp region)
    gemm_go_mfma<<<dim3(256, 4), 256, 0, stream>>>(xh, msh, Wgoh, Wgol, bgo, yh);
    // 6) output GEMM + GLU -> out (f32)
    gemm_out_mfma<<<dim3(256, 8), 256, 0, stream>>>(yh, Wouth, Woutl, bout, out);
}

// Round 4
// 876.523 us; speedup vs baseline: 1.0927x; 1.0927x over previous
//
#include <hip/hip_runtime.h>
#include <hip/hip_bf16.h>
#include <math.h>

// Problem constants
#define B_SZ 4
#define L_SZ 8192
#define DM 512           // D_MODEL
#define DMEM 512         // D_MEM
#define M1 (B_SZ * (L_SZ - 1))   // 32764 rows for the av GEMM
#define M2 (B_SZ * L_SZ)         // 32768 rows for GEMM2/3

typedef _Float16 h16;
typedef __attribute__((ext_vector_type(2))) _Float16 f16x2;
typedef __attribute__((ext_vector_type(4))) _Float16 f16x4;
typedef __attribute__((ext_vector_type(8))) _Float16 f16x8;
typedef __attribute__((ext_vector_type(4))) float f32x4;

#define MFMA16(a, b, c) __builtin_amdgcn_mfma_f32_16x16x32_f16((a), (b), (c), 0, 0, 0)

// bijective XCD swizzle: group blocks sharing a B-panel onto the same XCD L2
__device__ __forceinline__ void xcd_remap(int gx, int& bx, int& by) {
    int nwg = gx * gridDim.y;
    int lin = blockIdx.y * gx + blockIdx.x;
    int chunk = nwg >> 3;                   // nwg % 8 == 0 for all our grids
    int l = (lin & 7) * chunk + (lin >> 3);
    bx = l % gx;
    by = l / gx;
}

// ---------------------------------------------------------------------------
// Precompute: fp32 -> fp16 single (activations)
// ---------------------------------------------------------------------------
__global__ __launch_bounds__(256) void conv_single(
    const float* __restrict__ src, h16* __restrict__ dst, int n4)
{
    int i = blockIdx.x * 256 + threadIdx.x;
    if (i >= n4) return;
    float4 v = ((const float4*)src)[i];
    f16x4 o = { (h16)v.x, (h16)v.y, (h16)v.z, (h16)v.w };
    ((f16x4*)dst)[i] = o;
}

// Precompute: fp32 -> fp16 hi/lo split (weights)
__global__ __launch_bounds__(256) void conv_split(
    const float* __restrict__ src, h16* __restrict__ h, h16* __restrict__ l, int n4)
{
    int i = blockIdx.x * 256 + threadIdx.x;
    if (i >= n4) return;
    float4 v = ((const float4*)src)[i];
    f16x4 hh, ll;
    hh.x = (h16)v.x; ll.x = (h16)(v.x - (float)hh.x);
    hh.y = (h16)v.y; ll.y = (h16)(v.y - (float)hh.y);
    hh.z = (h16)v.z; ll.z = (h16)(v.z - (float)hh.z);
    hh.w = (h16)v.w; ll.w = (h16)(v.w - (float)hh.w);
    ((f16x4*)h)[i] = hh;
    ((f16x4*)l)[i] = ll;
}

// ---------------------------------------------------------------------------
// GEMM1 (grouped x4, fp16 A x split-fp16 W, 2 MFMA terms) + NRU combine.
// BM=128, BN=64 per group (x4 groups), BK=32. 512 threads, 8 waves (2m x 4n),
// each wave 64m x 16n x 4g -> acc = 16 f32x4 = 64 VGPRs (no spill).
// ---------------------------------------------------------------------------
__global__ __launch_bounds__(512) void gemm_av_mfma(
    const h16* __restrict__ xh, const h16* __restrict__ Wh, const h16* __restrict__ Wl,
    const float* __restrict__ bav, float* __restrict__ ms_inp)
{
    __shared__ __align__(16) h16 As[128][40];
    __shared__ __align__(16) h16 Bh[4][64][40];
    __shared__ __align__(16) h16 Bl[4][64][40];

    int bx, by; xcd_remap(256, bx, by);
    const int tid  = threadIdx.x;
    const int lane = tid & 63;
    const int w    = tid >> 6;          // 0..7
    const int wm   = (w >> 2) * 64;     // 0,64
    const int wn   = (w & 3) * 16;      // 0,16,32,48
    const int bm   = bx * 128;
    const int bn   = by * 64;
    const int ln   = lane & 15;
    const int ko   = (lane >> 4) * 8;

    // staging addresses (fixed per thread; only k0 varies)
    const h16* asrc; h16* adst;
    {
        int row = tid >> 2, cc = tid & 3;
        int m = bm + row;
        int mg = m < M1 ? m : (M1 - 1);
        int xr = mg + mg / (L_SZ - 1);          // skip last l of each batch
        asrc = xh + (size_t)xr * DM + cc * 8;
        adst = &As[row][cc * 8];
    }
    const h16 *bsH[2], *bsL[2]; h16 *bdH[2], *bdL[2];
    #pragma unroll
    for (int i = 0; i < 2; ++i) {
        int s = tid + i * 512;
        int g = s >> 8, rem = s & 255;
        int n = rem >> 2, cc = rem & 3;
        size_t off = (size_t)(g * 512 + bn + n) * DM + cc * 8;
        bsH[i] = Wh + off; bsL[i] = Wl + off;
        bdH[i] = &Bh[g][n][cc * 8]; bdL[i] = &Bl[g][n][cc * 8];
    }

    f32x4 acc[4][4];    // [g][fm]
    #pragma unroll
    for (int g = 0; g < 4; ++g)
        #pragma unroll
        for (int a = 0; a < 4; ++a) acc[g][a] = (f32x4){0.f, 0.f, 0.f, 0.f};

    int4 ra, rh[2], rl[2];
    ra = *(const int4*)asrc;
    #pragma unroll
    for (int i = 0; i < 2; ++i) { rh[i] = *(const int4*)bsH[i]; rl[i] = *(const int4*)bsL[i]; }

    for (int k0 = 0; k0 < DM; k0 += 32) {
        __syncthreads();
        *(int4*)adst = ra;
        #pragma unroll
        for (int i = 0; i < 2; ++i) { *(int4*)bdH[i] = rh[i]; *(int4*)bdL[i] = rl[i]; }
        __syncthreads();
        if (k0 + 32 < DM) {     // issue next-tile loads before compute
            ra = *(const int4*)(asrc + k0 + 32);
            #pragma unroll
            for (int i = 0; i < 2; ++i) {
                rh[i] = *(const int4*)(bsH[i] + k0 + 32);
                rl[i] = *(const int4*)(bsL[i] + k0 + 32);
            }
        }
        f16x8 a[4];
        #pragma unroll
        for (int fm = 0; fm < 4; ++fm) a[fm] = *(const f16x8*)&As[wm + fm * 16 + ln][ko];
        #pragma unroll
        for (int g = 0; g < 4; ++g) {
            f16x8 bh = *(const f16x8*)&Bh[g][wn + ln][ko];
            f16x8 bl = *(const f16x8*)&Bl[g][wn + ln][ko];
            #pragma unroll
            for (int fm = 0; fm < 4; ++fm) {
                acc[g][fm] = MFMA16(a[fm], bh, acc[g][fm]);
                acc[g][fm] = MFMA16(a[fm], bl, acc[g][fm]);
            }
        }
    }

    const int lm = (lane >> 4) * 4;
    const int n = bn + wn + ln;
    const float b0 = bav[n], b1 = bav[n + 512], b2 = bav[n + 1024], b3 = bav[n + 1536];
    #pragma unroll
    for (int fm = 0; fm < 4; ++fm) {
        #pragma unroll
        for (int i = 0; i < 4; ++i) {
            int m = bm + wm + fm * 16 + lm + i;
            if (m < M1) {
                float a0 = acc[0][fm][i] + b0;
                float a1 = acc[1][fm][i] + b1;
                float a2 = acc[2][fm][i] + b2;
                float a3 = acc[3][fm][i] + b3;
                ms_inp[(size_t)m * DMEM + n] = a0 * a1 - a2 * a3;
            }
        }
    }
}

// ---------------------------------------------------------------------------
// Chunked cumsum (fp32), pass3 emits fp16 ms.
// ---------------------------------------------------------------------------
__global__ __launch_bounds__(256) void scan_pass1(
    const float* __restrict__ ms_inp, float* __restrict__ csum)
{
    int c = blockIdx.x, b = blockIdx.y;
    int l0 = c * 128;
    int len = min(128, (L_SZ - 1) - l0);
    int t = threadIdx.x;
    const float2* p = (const float2*)(ms_inp + ((size_t)b * (L_SZ - 1) + l0) * DMEM) + t;
    float2 s = make_float2(0.f, 0.f);
    for (int i = 0; i < len; ++i) {
        float2 v = p[(size_t)i * 256];
        s.x += v.x; s.y += v.y;
    }
    ((float2*)(csum + ((size_t)b * 64 + c) * DMEM))[t] = s;
}

__global__ __launch_bounds__(256) void scan_pass2(float* __restrict__ csum)
{
    int idx = blockIdx.x * 256 + threadIdx.x;
    int b = idx >> 9, d = idx & 511;
    float run = 0.f;
    float* p = csum + (size_t)b * 64 * DMEM + d;
    for (int c = 0; c < 64; ++c) {
        float t = p[(size_t)c * DMEM];
        p[(size_t)c * DMEM] = run;
        run += t;
    }
}

__global__ __launch_bounds__(256) void scan_pass3(
    const float* __restrict__ ms_inp, const float* __restrict__ csum,
    h16* __restrict__ msh)
{
    int c = blockIdx.x, b = blockIdx.y;
    int l0 = c * 128;
    int len = min(128, (L_SZ - 1) - l0);
    int t = threadIdx.x;
    float2 run = ((const float2*)(csum + ((size_t)b * 64 + c) * DMEM))[t];
    const float2* p = (const float2*)(ms_inp + ((size_t)b * (L_SZ - 1) + l0) * DMEM) + t;
    f16x2* q = (f16x2*)(msh + ((size_t)b * L_SZ + l0 + 1) * DMEM) + t;
    if (c == 0) {
        f16x2 z = { (h16)0.f, (h16)0.f };
        ((f16x2*)(msh + (size_t)b * L_SZ * DMEM))[t] = z;
    }
    for (int i = 0; i < len; ++i) {
        float2 v = p[(size_t)i * 256];
        run.x += v.x; run.y += v.y;
        f16x2 o = { (h16)run.x, (h16)run.y };
        q[(size_t)i * 256] = o;
    }
}

// ---------------------------------------------------------------------------
// GEMM2 (fp16 A x split-fp16 W) + exact GELU -> fp16 y. K=1024 (x || ms).
// BM=128, BN=128, BK=32. 4 waves (2x2), each 64m x 64n.
// ---------------------------------------------------------------------------
__global__ __launch_bounds__(256) void gemm_go_mfma(
    const h16* __restrict__ xh, const h16* __restrict__ msh,
    const h16* __restrict__ Wh, const h16* __restrict__ Wl,
    const float* __restrict__ bgo, h16* __restrict__ yh)
{
    __shared__ __align__(16) h16 As[128][40];
    __shared__ __align__(16) h16 Bh[128][40];
    __shared__ __align__(16) h16 Bl[128][40];

    int bx, by; xcd_remap(256, bx, by);
    const int tid  = threadIdx.x;
    const int lane = tid & 63;
    const int w    = tid >> 6;
    const int wm   = (w & 1) * 64;
    const int wn   = (w >> 1) * 64;
    const int bm   = bx * 128;
    const int bn   = by * 128;
    const int ln   = lane & 15;
    const int ko   = (lane >> 4) * 8;

    const h16 *axs[2], *ams[2]; h16* adst[2];
    #pragma unroll
    for (int i = 0; i < 2; ++i) {
        int s = tid + i * 256;
        int row = s >> 2, cc = s & 3;
        size_t off = (size_t)(bm + row) * DM + cc * 8;
        axs[i] = xh + off; ams[i] = msh + off;
        adst[i] = &As[row][cc * 8];
    }
    const h16 *bsH[2], *bsL[2]; h16 *bdH[2], *bdL[2];
    #pragma unroll
    for (int i = 0; i < 2; ++i) {
        int s = tid + i * 256;
        int n = s >> 2, cc = s & 3;
        size_t off = (size_t)(bn + n) * 1024 + cc * 8;
        bsH[i] = Wh + off; bsL[i] = Wl + off;
        bdH[i] = &Bh[n][cc * 8]; bdL[i] = &Bl[n][cc * 8];
    }

    f32x4 acc[4][4];
    #pragma unroll
    for (int a = 0; a < 4; ++a)
        #pragma unroll
        for (int b = 0; b < 4; ++b) acc[a][b] = (f32x4){0.f, 0.f, 0.f, 0.f};

    int4 ra[2], rh[2], rl[2];
    #pragma unroll
    for (int i = 0; i < 2; ++i) {
        ra[i] = *(const int4*)axs[i];
        rh[i] = *(const int4*)bsH[i];
        rl[i] = *(const int4*)bsL[i];
    }

    for (int k0 = 0; k0 < 1024; k0 += 32) {
        __syncthreads();
        #pragma unroll
        for (int i = 0; i < 2; ++i) {
            *(int4*)adst[i] = ra[i];
            *(int4*)bdH[i] = rh[i];
            *(int4*)bdL[i] = rl[i];
        }
        __syncthreads();
        if (k0 + 32 < 1024) {
            int kn = k0 + 32;
            #pragma unroll
            for (int i = 0; i < 2; ++i) {
                ra[i] = (kn < 512) ? *(const int4*)(axs[i] + kn)
                                   : *(const int4*)(ams[i] + (kn - 512));
                rh[i] = *(const int4*)(bsH[i] + kn);
                rl[i] = *(const int4*)(bsL[i] + kn);
            }
        }
        f16x8 a[4];
        #pragma unroll
        for (int fm = 0; fm < 4; ++fm) a[fm] = *(const f16x8*)&As[wm + fm * 16 + ln][ko];
        #pragma unroll
        for (int fn = 0; fn < 4; ++fn) {
            f16x8 bh = *(const f16x8*)&Bh[wn + fn * 16 + ln][ko];
            f16x8 bl = *(const f16x8*)&Bl[wn + fn * 16 + ln][ko];
            #pragma unroll
            for (int fm = 0; fm < 4; ++fm) {
                acc[fm][fn] = MFMA16(a[fm], bh, acc[fm][fn]);
                acc[fm][fn] = MFMA16(a[fm], bl, acc[fm][fn]);
            }
        }
    }

    const int lm = (lane >> 4) * 4;
    #pragma unroll
    for (int fm = 0; fm < 4; ++fm) {
        #pragma unroll
        for (int fn = 0; fn < 4; ++fn) {
            int n = bn + wn + fn * 16 + ln;
            float bias = bgo[n];
            #pragma unroll
            for (int i = 0; i < 4; ++i) {
                int m = bm + wm + fm * 16 + lm + i;
                float t = acc[fm][fn][i] + bias;
                float g = 0.5f * t * (1.0f + erff(t * 0.70710678118654752f));
                yh[(size_t)m * DM + n] = (h16)g;
            }
        }
    }
}

// ---------------------------------------------------------------------------
// GEMM3 (grouped x2, fp16 A x split-fp16 W) + GLU -> fp32 out.
// BM=128, BN=64 per group (x2), BK=32. 4 waves (2x2), each 64m x 32n x 2g.
// ---------------------------------------------------------------------------
__global__ __launch_bounds__(256) void gemm_out_mfma(
    const h16* __restrict__ yh, const h16* __restrict__ Wh, const h16* __restrict__ Wl,
    const float* __restrict__ bout, float* __restrict__ out)
{
    __shared__ __align__(16) h16 As[128][40];
    __shared__ __align__(16) h16 Bh[2][64][40];
    __shared__ __align__(16) h16 Bl[2][64][40];

    int bx, by; xcd_remap(256, bx, by);
    const int tid  = threadIdx.x;
    const int lane = tid & 63;
    const int w    = tid >> 6;
    const int wm   = (w & 1) * 64;
    const int wn   = (w >> 1) * 32;
    const int bm   = bx * 128;
    const int bn   = by * 64;
    const int ln   = lane & 15;
    const int ko   = (lane >> 4) * 8;

    const h16* asrc[2]; h16* adst[2];
    #pragma unroll
    for (int i = 0; i < 2; ++i) {
        int s = tid + i * 256;
        int row = s >> 2, cc = s & 3;
        asrc[i] = yh + (size_t)(bm + row) * DM + cc * 8;
        adst[i] = &As[row][cc * 8];
    }
    const h16 *bsH[2], *bsL[2]; h16 *bdH[2], *bdL[2];
    #pragma unroll
    for (int i = 0; i < 2; ++i) {
        int s = tid + i * 256;
        int g = s >> 8, rem = s & 255;
        int n = rem >> 2, cc = rem & 3;
        size_t off = (size_t)(g * 512 + bn + n) * DM + cc * 8;
        bsH[i] = Wh + off; bsL[i] = Wl + off;
        bdH[i] = &Bh[g][n][cc * 8]; bdL[i] = &Bl[g][n][cc * 8];
    }

    f32x4 acc[2][4][2];
    #pragma unroll
    for (int g = 0; g < 2; ++g)
        #pragma unroll
        for (int a = 0; a < 4; ++a)
            #pragma unroll
            for (int b = 0; b < 2; ++b) acc[g][a][b] = (f32x4){0.f, 0.f, 0.f, 0.f};

    int4 ra[2], rh[2], rl[2];
    #pragma unroll
    for (int i = 0; i < 2; ++i) {
        ra[i] = *(const int4*)asrc[i];
        rh[i] = *(const int4*)bsH[i];
        rl[i] = *(const int4*)bsL[i];
    }

    for (int k0 = 0; k0 < DM; k0 += 32) {
        __syncthreads();
        #pragma unroll
        for (int i = 0; i < 2; ++i) {
            *(int4*)adst[i] = ra[i];
            *(int4*)bdH[i] = rh[i];
            *(int4*)bdL[i] = rl[i];
        }
        __syncthreads();
        if (k0 + 32 < DM) {
            #pragma unroll
            for (int i = 0; i < 2; ++i) {
                ra[i] = *(const int4*)(asrc[i] + k0 + 32);
                rh[i] = *(const int4*)(bsH[i] + k0 + 32);
                rl[i] = *(const int4*)(bsL[i] + k0 + 32);
            }
        }
        f16x8 a[4];
        #pragma unroll
        for (int fm = 0; fm < 4; ++fm) a[fm] = *(const f16x8*)&As[wm + fm * 16 + ln][ko];
        #pragma unroll
        for (int g = 0; g < 2; ++g) {
            #pragma unroll
            for (int fn = 0; fn < 2; ++fn) {
                f16x8 bh = *(const f16x8*)&Bh[g][wn + fn * 16 + ln][ko];
                f16x8 bl = *(const f16x8*)&Bl[g][wn + fn * 16 + ln][ko];
                #pragma unroll
                for (int fm = 0; fm < 4; ++fm) {
                    acc[g][fm][fn] = MFMA16(a[fm], bh, acc[g][fm][fn]);
                    acc[g][fm][fn] = MFMA16(a[fm], bl, acc[g][fm][fn]);
                }
            }
        }
    }

    const int lm = (lane >> 4) * 4;
    #pragma unroll
    for (int fm = 0; fm < 4; ++fm) {
        #pragma unroll
        for (int fn = 0; fn < 2; ++fn) {
            int n = bn + wn + fn * 16 + ln;
            float bz0 = bout[n], bz1 = bout[n + 512];
            #pragma unroll
            for (int i = 0; i < 4; ++i) {
                int m = bm + wm + fm * 16 + lm + i;
                float z0 = acc[0][fm][fn][i] + bz0;
                float z1 = acc[1][fm][fn][i] + bz1;
                out[(size_t)m * DM + n] = z0 * (1.0f / (1.0f + expf(-z1)));
            }
        }
    }
}

// ---------------------------------------------------------------------------
extern "C" void kernel_launch(void* const* d_in, const int* in_sizes, int n_in,
                              void* d_out, int out_size, void* d_ws, size_t ws_size,
                              hipStream_t stream)
{
    const float* x    = (const float*)d_in[0];
    const float* Wav  = (const float*)d_in[1];
    const float* bav  = (const float*)d_in[2];
    const float* Wgo  = (const float*)d_in[3];
    const float* bgo  = (const float*)d_in[4];
    const float* Wout = (const float*)d_in[5];
    const float* bout = (const float*)d_in[6];
    float* out = (float*)d_out;

    char* ws = (char*)d_ws;
    const size_t MB = 1 << 20;
    float* ms_inp = (float*)ws;                   // 64 MiB region [32764,512] f32
    h16*   yh     = (h16*)ws;                     // aliases ms_inp (used after scan)
    h16*   xh     = (h16*)(ws + 64 * MB);         // 32 MiB
    h16*   msh    = (h16*)(ws + 96 * MB);         // 32 MiB
    float* csum   = (float*)(ws + 128 * MB);      // 0.5 MiB
    h16*   Wavh   = (h16*)(ws + 129 * MB);        // 2 MiB
    h16*   Wavl   = (h16*)(ws + 131 * MB);        // 2 MiB
    h16*   Wgoh   = (h16*)(ws + 133 * MB);        // 1 MiB
    h16*   Wgol   = (h16*)(ws + 134 * MB);        // 1 MiB
    h16*   Wouth  = (h16*)(ws + 135 * MB);        // 1 MiB
    h16*   Woutl  = (h16*)(ws + 136 * MB);        // 1 MiB

    // 0) precompute fp16 forms
    conv_single<<<(M2 * DM / 4 + 255) / 256, 256, 0, stream>>>(x, xh, M2 * DM / 4);
    conv_split<<<(2048 * 512 / 4 + 255) / 256, 256, 0, stream>>>(Wav, Wavh, Wavl, 2048 * 512 / 4);
    conv_split<<<(512 * 1024 / 4 + 255) / 256, 256, 0, stream>>>(Wgo, Wgoh, Wgol, 512 * 1024 / 4);
    conv_split<<<(1024 * 512 / 4 + 255) / 256, 256, 0, stream>>>(Wout, Wouth, Woutl, 1024 * 512 / 4);
    // 1) av GEMM + NRU combine -> ms_inp (f32)
    gemm_av_mfma<<<dim3(256, 8), 512, 0, stream>>>(xh, Wavh, Wavl, bav, ms_inp);
    // 2-4) chunked cumsum -> msh (fp16)
    scan_pass1<<<dim3(64, B_SZ), 256, 0, stream>>>(ms_inp, csum);
    scan_pass2<<<8, 256, 0, stream>>>(csum);
    scan_pass3<<<dim3(64, B_SZ), 256, 0, stream>>>(ms_inp, csum, msh);
    // 5) SSM-in GEMM + GELU -> yh (fp16, reuses ms_inp region)
    gemm_go_mfma<<<dim3(256, 4), 256, 0, stream>>>(xh, msh, Wgoh, Wgol, bgo, yh);
    // 6) output GEMM + GLU -> out (f32)
    gemm_out_mfma<<<dim3(256, 8), 256, 0, stream>>>(yh, Wouth, Woutl, bout, out);
}

// Round 5
// 873.801 us; speedup vs baseline: 1.0961x; 1.0031x over previous
//
#include <hip/hip_runtime.h>
#include <hip/hip_bf16.h>
#include <math.h>

// Problem constants
#define B_SZ 4
#define L_SZ 8192
#define DM 512           // D_MODEL
#define DMEM 512         // D_MEM
#define M1 (B_SZ * (L_SZ - 1))   // 32764 rows for the av GEMM
#define M2 (B_SZ * L_SZ)         // 32768 rows for GEMM2/3

typedef _Float16 h16;
typedef __attribute__((ext_vector_type(2))) _Float16 f16x2;
typedef __attribute__((ext_vector_type(4))) _Float16 f16x4;
typedef __attribute__((ext_vector_type(8))) _Float16 f16x8;
typedef __attribute__((ext_vector_type(4))) float f32x4;

#define MFMA16(a, b, c) __builtin_amdgcn_mfma_f32_16x16x32_f16((a), (b), (c), 0, 0, 0)

// bijective XCD swizzle: group blocks sharing a B-panel onto the same XCD L2
__device__ __forceinline__ void xcd_remap(int gx, int& bx, int& by) {
    int nwg = gx * gridDim.y;
    int lin = blockIdx.y * gx + blockIdx.x;
    int chunk = nwg >> 3;                   // nwg % 8 == 0 for all our grids
    int l = (lin & 7) * chunk + (lin >> 3);
    bx = l % gx;
    by = l / gx;
}

// ---------------------------------------------------------------------------
// Precompute: fp32 -> fp16 single (activations)
// ---------------------------------------------------------------------------
__global__ __launch_bounds__(256) void conv_single(
    const float* __restrict__ src, h16* __restrict__ dst, int n4)
{
    int i = blockIdx.x * 256 + threadIdx.x;
    if (i >= n4) return;
    float4 v = ((const float4*)src)[i];
    f16x4 o = { (h16)v.x, (h16)v.y, (h16)v.z, (h16)v.w };
    ((f16x4*)dst)[i] = o;
}

// Precompute: fp32 -> fp16 hi/lo split (weights)
__global__ __launch_bounds__(256) void conv_split(
    const float* __restrict__ src, h16* __restrict__ h, h16* __restrict__ l, int n4)
{
    int i = blockIdx.x * 256 + threadIdx.x;
    if (i >= n4) return;
    float4 v = ((const float4*)src)[i];
    f16x4 hh, ll;
    hh.x = (h16)v.x; ll.x = (h16)(v.x - (float)hh.x);
    hh.y = (h16)v.y; ll.y = (h16)(v.y - (float)hh.y);
    hh.z = (h16)v.z; ll.z = (h16)(v.z - (float)hh.z);
    hh.w = (h16)v.w; ll.w = (h16)(v.w - (float)hh.w);
    ((f16x4*)h)[i] = hh;
    ((f16x4*)l)[i] = ll;
}

// ---------------------------------------------------------------------------
// GEMM1 (grouped x4, fp16 A x split-fp16 W, 2 MFMA terms) + NRU combine.
// BM=128, BN=64 per group (x4 groups), BK=32. 512 threads, 8 waves (2m x 4n),
// each wave 64m x 16n x 4g -> acc = 16 f32x4 = 64 VGPRs.
// __launch_bounds__(512, 2): 2 waves/SIMD -> VGPR cap 256, no spill.
// ---------------------------------------------------------------------------
__global__ __launch_bounds__(512, 2) void gemm_av_mfma(
    const h16* __restrict__ xh, const h16* __restrict__ Wh, const h16* __restrict__ Wl,
    const float* __restrict__ bav, float* __restrict__ ms_inp)
{
    __shared__ __align__(16) h16 As[128][40];
    __shared__ __align__(16) h16 Bh[4][64][40];
    __shared__ __align__(16) h16 Bl[4][64][40];

    int bx, by; xcd_remap(256, bx, by);
    const int tid  = threadIdx.x;
    const int lane = tid & 63;
    const int w    = tid >> 6;          // 0..7
    const int wm   = (w >> 2) * 64;     // 0,64
    const int wn   = (w & 3) * 16;      // 0,16,32,48
    const int bm   = bx * 128;
    const int bn   = by * 64;
    const int ln   = lane & 15;
    const int ko   = (lane >> 4) * 8;

    // staging addresses (fixed per thread; only k0 varies)
    const h16* asrc; h16* adst;
    {
        int row = tid >> 2, cc = tid & 3;
        int m = bm + row;
        int mg = m < M1 ? m : (M1 - 1);
        int xr = mg + mg / (L_SZ - 1);          // skip last l of each batch
        asrc = xh + (size_t)xr * DM + cc * 8;
        adst = &As[row][cc * 8];
    }
    const h16 *bsH[2], *bsL[2]; h16 *bdH[2], *bdL[2];
    #pragma unroll
    for (int i = 0; i < 2; ++i) {
        int s = tid + i * 512;
        int g = s >> 8, rem = s & 255;
        int n = rem >> 2, cc = rem & 3;
        size_t off = (size_t)(g * 512 + bn + n) * DM + cc * 8;
        bsH[i] = Wh + off; bsL[i] = Wl + off;
        bdH[i] = &Bh[g][n][cc * 8]; bdL[i] = &Bl[g][n][cc * 8];
    }

    f32x4 acc[4][4];    // [g][fm]
    #pragma unroll
    for (int g = 0; g < 4; ++g)
        #pragma unroll
        for (int a = 0; a < 4; ++a) acc[g][a] = (f32x4){0.f, 0.f, 0.f, 0.f};

    int4 ra, rh[2], rl[2];
    ra = *(const int4*)asrc;
    #pragma unroll
    for (int i = 0; i < 2; ++i) { rh[i] = *(const int4*)bsH[i]; rl[i] = *(const int4*)bsL[i]; }

    for (int k0 = 0; k0 < DM; k0 += 32) {
        __syncthreads();
        *(int4*)adst = ra;
        #pragma unroll
        for (int i = 0; i < 2; ++i) { *(int4*)bdH[i] = rh[i]; *(int4*)bdL[i] = rl[i]; }
        __syncthreads();
        if (k0 + 32 < DM) {     // issue next-tile loads before compute
            ra = *(const int4*)(asrc + k0 + 32);
            #pragma unroll
            for (int i = 0; i < 2; ++i) {
                rh[i] = *(const int4*)(bsH[i] + k0 + 32);
                rl[i] = *(const int4*)(bsL[i] + k0 + 32);
            }
        }
        f16x8 a[4];
        #pragma unroll
        for (int fm = 0; fm < 4; ++fm) a[fm] = *(const f16x8*)&As[wm + fm * 16 + ln][ko];
        #pragma unroll
        for (int g = 0; g < 4; ++g) {
            f16x8 bh = *(const f16x8*)&Bh[g][wn + ln][ko];
            f16x8 bl = *(const f16x8*)&Bl[g][wn + ln][ko];
            #pragma unroll
            for (int fm = 0; fm < 4; ++fm) {
                acc[g][fm] = MFMA16(a[fm], bh, acc[g][fm]);
                acc[g][fm] = MFMA16(a[fm], bl, acc[g][fm]);
            }
        }
    }

    const int lm = (lane >> 4) * 4;
    const int n = bn + wn + ln;
    const float b0 = bav[n], b1 = bav[n + 512], b2 = bav[n + 1024], b3 = bav[n + 1536];
    #pragma unroll
    for (int fm = 0; fm < 4; ++fm) {
        #pragma unroll
        for (int i = 0; i < 4; ++i) {
            int m = bm + wm + fm * 16 + lm + i;
            if (m < M1) {
                float a0 = acc[0][fm][i] + b0;
                float a1 = acc[1][fm][i] + b1;
                float a2 = acc[2][fm][i] + b2;
                float a3 = acc[3][fm][i] + b3;
                ms_inp[(size_t)m * DMEM + n] = a0 * a1 - a2 * a3;
            }
        }
    }
}

// ---------------------------------------------------------------------------
// Chunked cumsum (fp32), pass3 emits fp16 ms.
// ---------------------------------------------------------------------------
__global__ __launch_bounds__(256) void scan_pass1(
    const float* __restrict__ ms_inp, float* __restrict__ csum)
{
    int c = blockIdx.x, b = blockIdx.y;
    int l0 = c * 128;
    int len = min(128, (L_SZ - 1) - l0);
    int t = threadIdx.x;
    const float2* p = (const float2*)(ms_inp + ((size_t)b * (L_SZ - 1) + l0) * DMEM) + t;
    float2 s = make_float2(0.f, 0.f);
    for (int i = 0; i < len; ++i) {
        float2 v = p[(size_t)i * 256];
        s.x += v.x; s.y += v.y;
    }
    ((float2*)(csum + ((size_t)b * 64 + c) * DMEM))[t] = s;
}

__global__ __launch_bounds__(256) void scan_pass2(float* __restrict__ csum)
{
    int idx = blockIdx.x * 256 + threadIdx.x;
    int b = idx >> 9, d = idx & 511;
    float run = 0.f;
    float* p = csum + (size_t)b * 64 * DMEM + d;
    for (int c = 0; c < 64; ++c) {
        float t = p[(size_t)c * DMEM];
        p[(size_t)c * DMEM] = run;
        run += t;
    }
}

__global__ __launch_bounds__(256) void scan_pass3(
    const float* __restrict__ ms_inp, const float* __restrict__ csum,
    h16* __restrict__ msh)
{
    int c = blockIdx.x, b = blockIdx.y;
    int l0 = c * 128;
    int len = min(128, (L_SZ - 1) - l0);
    int t = threadIdx.x;
    float2 run = ((const float2*)(csum + ((size_t)b * 64 + c) * DMEM))[t];
    const float2* p = (const float2*)(ms_inp + ((size_t)b * (L_SZ - 1) + l0) * DMEM) + t;
    f16x2* q = (f16x2*)(msh + ((size_t)b * L_SZ + l0 + 1) * DMEM) + t;
    if (c == 0) {
        f16x2 z = { (h16)0.f, (h16)0.f };
        ((f16x2*)(msh + (size_t)b * L_SZ * DMEM))[t] = z;
    }
    for (int i = 0; i < len; ++i) {
        float2 v = p[(size_t)i * 256];
        run.x += v.x; run.y += v.y;
        f16x2 o = { (h16)run.x, (h16)run.y };
        q[(size_t)i * 256] = o;
    }
}

// ---------------------------------------------------------------------------
// GEMM2 (fp16 A x split-fp16 W) + exact GELU -> fp16 y. K=1024 (x || ms).
// BM=128, BN=128, BK=32. 4 waves (2x2), each 64m x 64n.
// __launch_bounds__(256, 2): VGPR cap 256, no spill.
// ---------------------------------------------------------------------------
__global__ __launch_bounds__(256, 2) void gemm_go_mfma(
    const h16* __restrict__ xh, const h16* __restrict__ msh,
    const h16* __restrict__ Wh, const h16* __restrict__ Wl,
    const float* __restrict__ bgo, h16* __restrict__ yh)
{
    __shared__ __align__(16) h16 As[128][40];
    __shared__ __align__(16) h16 Bh[128][40];
    __shared__ __align__(16) h16 Bl[128][40];

    int bx, by; xcd_remap(256, bx, by);
    const int tid  = threadIdx.x;
    const int lane = tid & 63;
    const int w    = tid >> 6;
    const int wm   = (w & 1) * 64;
    const int wn   = (w >> 1) * 64;
    const int bm   = bx * 128;
    const int bn   = by * 128;
    const int ln   = lane & 15;
    const int ko   = (lane >> 4) * 8;

    const h16 *axs[2], *ams[2]; h16* adst[2];
    #pragma unroll
    for (int i = 0; i < 2; ++i) {
        int s = tid + i * 256;
        int row = s >> 2, cc = s & 3;
        size_t off = (size_t)(bm + row) * DM + cc * 8;
        axs[i] = xh + off; ams[i] = msh + off;
        adst[i] = &As[row][cc * 8];
    }
    const h16 *bsH[2], *bsL[2]; h16 *bdH[2], *bdL[2];
    #pragma unroll
    for (int i = 0; i < 2; ++i) {
        int s = tid + i * 256;
        int n = s >> 2, cc = s & 3;
        size_t off = (size_t)(bn + n) * 1024 + cc * 8;
        bsH[i] = Wh + off; bsL[i] = Wl + off;
        bdH[i] = &Bh[n][cc * 8]; bdL[i] = &Bl[n][cc * 8];
    }

    f32x4 acc[4][4];
    #pragma unroll
    for (int a = 0; a < 4; ++a)
        #pragma unroll
        for (int b = 0; b < 4; ++b) acc[a][b] = (f32x4){0.f, 0.f, 0.f, 0.f};

    int4 ra[2], rh[2], rl[2];
    #pragma unroll
    for (int i = 0; i < 2; ++i) {
        ra[i] = *(const int4*)axs[i];
        rh[i] = *(const int4*)bsH[i];
        rl[i] = *(const int4*)bsL[i];
    }

    for (int k0 = 0; k0 < 1024; k0 += 32) {
        __syncthreads();
        #pragma unroll
        for (int i = 0; i < 2; ++i) {
            *(int4*)adst[i] = ra[i];
            *(int4*)bdH[i] = rh[i];
            *(int4*)bdL[i] = rl[i];
        }
        __syncthreads();
        if (k0 + 32 < 1024) {
            int kn = k0 + 32;
            #pragma unroll
            for (int i = 0; i < 2; ++i) {
                ra[i] = (kn < 512) ? *(const int4*)(axs[i] + kn)
                                   : *(const int4*)(ams[i] + (kn - 512));
                rh[i] = *(const int4*)(bsH[i] + kn);
                rl[i] = *(const int4*)(bsL[i] + kn);
            }
        }
        f16x8 a[4];
        #pragma unroll
        for (int fm = 0; fm < 4; ++fm) a[fm] = *(const f16x8*)&As[wm + fm * 16 + ln][ko];
        #pragma unroll
        for (int fn = 0; fn < 4; ++fn) {
            f16x8 bh = *(const f16x8*)&Bh[wn + fn * 16 + ln][ko];
            f16x8 bl = *(const f16x8*)&Bl[wn + fn * 16 + ln][ko];
            #pragma unroll
            for (int fm = 0; fm < 4; ++fm) {
                acc[fm][fn] = MFMA16(a[fm], bh, acc[fm][fn]);
                acc[fm][fn] = MFMA16(a[fm], bl, acc[fm][fn]);
            }
        }
    }

    const int lm = (lane >> 4) * 4;
    #pragma unroll
    for (int fm = 0; fm < 4; ++fm) {
        #pragma unroll
        for (int fn = 0; fn < 4; ++fn) {
            int n = bn + wn + fn * 16 + ln;
            float bias = bgo[n];
            #pragma unroll
            for (int i = 0; i < 4; ++i) {
                int m = bm + wm + fm * 16 + lm + i;
                float t = acc[fm][fn][i] + bias;
                float g = 0.5f * t * (1.0f + erff(t * 0.70710678118654752f));
                yh[(size_t)m * DM + n] = (h16)g;
            }
        }
    }
}

// ---------------------------------------------------------------------------
// GEMM3 (grouped x2, fp16 A x split-fp16 W) + GLU -> fp32 out.
// BM=128, BN=64 per group (x2), BK=32. 4 waves (2x2), each 64m x 32n x 2g.
// __launch_bounds__(256, 2): VGPR cap 256, no spill.
// ---------------------------------------------------------------------------
__global__ __launch_bounds__(256, 2) void gemm_out_mfma(
    const h16* __restrict__ yh, const h16* __restrict__ Wh, const h16* __restrict__ Wl,
    const float* __restrict__ bout, float* __restrict__ out)
{
    __shared__ __align__(16) h16 As[128][40];
    __shared__ __align__(16) h16 Bh[2][64][40];
    __shared__ __align__(16) h16 Bl[2][64][40];

    int bx, by; xcd_remap(256, bx, by);
    const int tid  = threadIdx.x;
    const int lane = tid & 63;
    const int w    = tid >> 6;
    const int wm   = (w & 1) * 64;
    const int wn   = (w >> 1) * 32;
    const int bm   = bx * 128;
    const int bn   = by * 64;
    const int ln   = lane & 15;
    const int ko   = (lane >> 4) * 8;

    const h16* asrc[2]; h16* adst[2];
    #pragma unroll
    for (int i = 0; i < 2; ++i) {
        int s = tid + i * 256;
        int row = s >> 2, cc = s & 3;
        asrc[i] = yh + (size_t)(bm + row) * DM + cc * 8;
        adst[i] = &As[row][cc * 8];
    }
    const h16 *bsH[2], *bsL[2]; h16 *bdH[2], *bdL[2];
    #pragma unroll
    for (int i = 0; i < 2; ++i) {
        int s = tid + i * 256;
        int g = s >> 8, rem = s & 255;
        int n = rem >> 2, cc = rem & 3;
        size_t off = (size_t)(g * 512 + bn + n) * DM + cc * 8;
        bsH[i] = Wh + off; bsL[i] = Wl + off;
        bdH[i] = &Bh[g][n][cc * 8]; bdL[i] = &Bl[g][n][cc * 8];
    }

    f32x4 acc[2][4][2];
    #pragma unroll
    for (int g = 0; g < 2; ++g)
        #pragma unroll
        for (int a = 0; a < 4; ++a)
            #pragma unroll
            for (int b = 0; b < 2; ++b) acc[g][a][b] = (f32x4){0.f, 0.f, 0.f, 0.f};

    int4 ra[2], rh[2], rl[2];
    #pragma unroll
    for (int i = 0; i < 2; ++i) {
        ra[i] = *(const int4*)asrc[i];
        rh[i] = *(const int4*)bsH[i];
        rl[i] = *(const int4*)bsL[i];
    }

    for (int k0 = 0; k0 < DM; k0 += 32) {
        __syncthreads();
        #pragma unroll
        for (int i = 0; i < 2; ++i) {
            *(int4*)adst[i] = ra[i];
            *(int4*)bdH[i] = rh[i];
            *(int4*)bdL[i] = rl[i];
        }
        __syncthreads();
        if (k0 + 32 < DM) {
            #pragma unroll
            for (int i = 0; i < 2; ++i) {
                ra[i] = *(const int4*)(asrc[i] + k0 + 32);
                rh[i] = *(const int4*)(bsH[i] + k0 + 32);
                rl[i] = *(const int4*)(bsL[i] + k0 + 32);
            }
        }
        f16x8 a[4];
        #pragma unroll
        for (int fm = 0; fm < 4; ++fm) a[fm] = *(const f16x8*)&As[wm + fm * 16 + ln][ko];
        #pragma unroll
        for (int g = 0; g < 2; ++g) {
            #pragma unroll
            for (int fn = 0; fn < 2; ++fn) {
                f16x8 bh = *(const f16x8*)&Bh[g][wn + fn * 16 + ln][ko];
                f16x8 bl = *(const f16x8*)&Bl[g][wn + fn * 16 + ln][ko];
                #pragma unroll
                for (int fm = 0; fm < 4; ++fm) {
                    acc[g][fm][fn] = MFMA16(a[fm], bh, acc[g][fm][fn]);
                    acc[g][fm][fn] = MFMA16(a[fm], bl, acc[g][fm][fn]);
                }
            }
        }
    }

    const int lm = (lane >> 4) * 4;
    #pragma unroll
    for (int fm = 0; fm < 4; ++fm) {
        #pragma unroll
        for (int fn = 0; fn < 2; ++fn) {
            int n = bn + wn + fn * 16 + ln;
            float bz0 = bout[n], bz1 = bout[n + 512];
            #pragma unroll
            for (int i = 0; i < 4; ++i) {
                int m = bm + wm + fm * 16 + lm + i;
                float z0 = acc[0][fm][fn][i] + bz0;
                float z1 = acc[1][fm][fn][i] + bz1;
                out[(size_t)m * DM + n] = z0 * (1.0f / (1.0f + expf(-z1)));
            }
        }
    }
}

// ---------------------------------------------------------------------------
extern "C" void kernel_launch(void* const* d_in, const int* in_sizes, int n_in,
                              void* d_out, int out_size, void* d_ws, size_t ws_size,
                              hipStream_t stream)
{
    const float* x    = (const float*)d_in[0];
    const float* Wav  = (const float*)d_in[1];
    const float* bav  = (const float*)d_in[2];
    const float* Wgo  = (const float*)d_in[3];
    const float* bgo  = (const float*)d_in[4];
    const float* Wout = (const float*)d_in[5];
    const float* bout = (const float*)d_in[6];
    float* out = (float*)d_out;

    char* ws = (char*)d_ws;
    const size_t MB = 1 << 20;
    float* ms_inp = (float*)ws;                   // 64 MiB region [32764,512] f32
    h16*   yh     = (h16*)ws;                     // aliases ms_inp (used after scan)
    h16*   xh     = (h16*)(ws + 64 * MB);         // 32 MiB
    h16*   msh    = (h16*)(ws + 96 * MB);         // 32 MiB
    float* csum   = (float*)(ws + 128 * MB);      // 0.5 MiB
    h16*   Wavh   = (h16*)(ws + 129 * MB);        // 2 MiB
    h16*   Wavl   = (h16*)(ws + 131 * MB);        // 2 MiB
    h16*   Wgoh   = (h16*)(ws + 133 * MB);        // 1 MiB
    h16*   Wgol   = (h16*)(ws + 134 * MB);        // 1 MiB
    h16*   Wouth  = (h16*)(ws + 135 * MB);        // 1 MiB
    h16*   Woutl  = (h16*)(ws + 136 * MB);        // 1 MiB

    // 0) precompute fp16 forms
    conv_single<<<(M2 * DM / 4 + 255) / 256, 256, 0, stream>>>(x, xh, M2 * DM / 4);
    conv_split<<<(2048 * 512 / 4 + 255) / 256, 256, 0, stream>>>(Wav, Wavh, Wavl, 2048 * 512 / 4);
    conv_split<<<(512 * 1024 / 4 + 255) / 256, 256, 0, stream>>>(Wgo, Wgoh, Wgol, 512 * 1024 / 4);
    conv_split<<<(1024 * 512 / 4 + 255) / 256, 256, 0, stream>>>(Wout, Wouth, Woutl, 1024 * 512 / 4);
    // 1) av GEMM + NRU combine -> ms_inp (f32)
    gemm_av_mfma<<<dim3(256, 8), 512, 0, stream>>>(xh, Wavh, Wavl, bav, ms_inp);
    // 2-4) chunked cumsum -> msh (fp16)
    scan_pass1<<<dim3(64, B_SZ), 256, 0, stream>>>(ms_inp, csum);
    scan_pass2<<<8, 256, 0, stream>>>(csum);
    scan_pass3<<<dim3(64, B_SZ), 256, 0, stream>>>(ms_inp, csum, msh);
    // 5) SSM-in GEMM + GELU -> yh (fp16, reuses ms_inp region)
    gemm_go_mfma<<<dim3(256, 4), 256, 0, stream>>>(xh, msh, Wgoh, Wgol, bgo, yh);
    // 6) output GEMM + GLU -> out (f32)
    gemm_out_mfma<<<dim3(256, 8), 256, 0, stream>>>(yh, Wouth, Woutl, bout, out);
}

// Round 6
// 607.983 us; speedup vs baseline: 1.5753x; 1.4372x over previous
//
#include <hip/hip_runtime.h>
#include <hip/hip_bf16.h>
#include <math.h>

// Problem constants
#define B_SZ 4
#define L_SZ 8192
#define DM 512           // D_MODEL
#define DMEM 512         // D_MEM
#define M1 (B_SZ * (L_SZ - 1))   // 32764 rows for the av GEMM
#define M2 (B_SZ * L_SZ)         // 32768 rows for GEMM2/3

typedef _Float16 h16;
typedef __attribute__((ext_vector_type(2))) _Float16 f16x2;
typedef __attribute__((ext_vector_type(4))) _Float16 f16x4;
typedef __attribute__((ext_vector_type(8))) _Float16 f16x8;
typedef __attribute__((ext_vector_type(4))) float f32x4;

#define MFMA16(a, b, c) __builtin_amdgcn_mfma_f32_16x16x32_f16((a), (b), (c), 0, 0, 0)

// Force the register allocator's occupancy TARGET (min,max waves per EU).
// __launch_bounds__'s 2nd arg is only a minimum -> raises the cap but the
// allocator still targets high occupancy and spills. max=2 -> 256-VGPR budget.
#define WAVES_EU(mn, mx) __attribute__((amdgpu_waves_per_eu(mn, mx)))

// bijective XCD swizzle: group blocks sharing a B-panel onto the same XCD L2
__device__ __forceinline__ void xcd_remap(int gx, int& bx, int& by) {
    int nwg = gx * gridDim.y;
    int lin = blockIdx.y * gx + blockIdx.x;
    int chunk = nwg >> 3;                   // nwg % 8 == 0 for all our grids
    int l = (lin & 7) * chunk + (lin >> 3);
    bx = l % gx;
    by = l / gx;
}

// ---------------------------------------------------------------------------
// Precompute: fp32 -> fp16 single (activations)
// ---------------------------------------------------------------------------
__global__ __launch_bounds__(256) void conv_single(
    const float* __restrict__ src, h16* __restrict__ dst, int n4)
{
    int i = blockIdx.x * 256 + threadIdx.x;
    if (i >= n4) return;
    float4 v = ((const float4*)src)[i];
    f16x4 o = { (h16)v.x, (h16)v.y, (h16)v.z, (h16)v.w };
    ((f16x4*)dst)[i] = o;
}

// Precompute: fp32 -> fp16 hi/lo split (weights)
__global__ __launch_bounds__(256) void conv_split(
    const float* __restrict__ src, h16* __restrict__ h, h16* __restrict__ l, int n4)
{
    int i = blockIdx.x * 256 + threadIdx.x;
    if (i >= n4) return;
    float4 v = ((const float4*)src)[i];
    f16x4 hh, ll;
    hh.x = (h16)v.x; ll.x = (h16)(v.x - (float)hh.x);
    hh.y = (h16)v.y; ll.y = (h16)(v.y - (float)hh.y);
    hh.z = (h16)v.z; ll.z = (h16)(v.z - (float)hh.z);
    hh.w = (h16)v.w; ll.w = (h16)(v.w - (float)hh.w);
    ((f16x4*)h)[i] = hh;
    ((f16x4*)l)[i] = ll;
}

// ---------------------------------------------------------------------------
// GEMM1 (grouped x4, fp16 A x split-fp16 W, 2 MFMA terms) + NRU combine.
// BM=128, BN=64 per group (x4 groups), BK=32. 512 threads, 8 waves (2m x 4n),
// each wave 64m x 16n x 4g -> acc = 16 f32x4 = 64 VGPRs.
// waves_per_eu(2,2): allocator targets 2 waves/EU -> 256-VGPR budget, no spill.
// ---------------------------------------------------------------------------
__global__ __launch_bounds__(512) WAVES_EU(2, 2) void gemm_av_mfma(
    const h16* __restrict__ xh, const h16* __restrict__ Wh, const h16* __restrict__ Wl,
    const float* __restrict__ bav, float* __restrict__ ms_inp)
{
    __shared__ __align__(16) h16 As[128][40];
    __shared__ __align__(16) h16 Bh[4][64][40];
    __shared__ __align__(16) h16 Bl[4][64][40];

    int bx, by; xcd_remap(256, bx, by);
    const int tid  = threadIdx.x;
    const int lane = tid & 63;
    const int w    = tid >> 6;          // 0..7
    const int wm   = (w >> 2) * 64;     // 0,64
    const int wn   = (w & 3) * 16;      // 0,16,32,48
    const int bm   = bx * 128;
    const int bn   = by * 64;
    const int ln   = lane & 15;
    const int ko   = (lane >> 4) * 8;

    // staging addresses (fixed per thread; only k0 varies)
    const h16* asrc; h16* adst;
    {
        int row = tid >> 2, cc = tid & 3;
        int m = bm + row;
        int mg = m < M1 ? m : (M1 - 1);
        int xr = mg + mg / (L_SZ - 1);          // skip last l of each batch
        asrc = xh + (size_t)xr * DM + cc * 8;
        adst = &As[row][cc * 8];
    }
    const h16 *bsH[2], *bsL[2]; h16 *bdH[2], *bdL[2];
    #pragma unroll
    for (int i = 0; i < 2; ++i) {
        int s = tid + i * 512;
        int g = s >> 8, rem = s & 255;
        int n = rem >> 2, cc = rem & 3;
        size_t off = (size_t)(g * 512 + bn + n) * DM + cc * 8;
        bsH[i] = Wh + off; bsL[i] = Wl + off;
        bdH[i] = &Bh[g][n][cc * 8]; bdL[i] = &Bl[g][n][cc * 8];
    }

    f32x4 acc[4][4];    // [g][fm]
    #pragma unroll
    for (int g = 0; g < 4; ++g)
        #pragma unroll
        for (int a = 0; a < 4; ++a) acc[g][a] = (f32x4){0.f, 0.f, 0.f, 0.f};

    int4 ra, rh[2], rl[2];
    ra = *(const int4*)asrc;
    #pragma unroll
    for (int i = 0; i < 2; ++i) { rh[i] = *(const int4*)bsH[i]; rl[i] = *(const int4*)bsL[i]; }

    for (int k0 = 0; k0 < DM; k0 += 32) {
        __syncthreads();
        *(int4*)adst = ra;
        #pragma unroll
        for (int i = 0; i < 2; ++i) { *(int4*)bdH[i] = rh[i]; *(int4*)bdL[i] = rl[i]; }
        __syncthreads();
        if (k0 + 32 < DM) {     // issue next-tile loads before compute
            ra = *(const int4*)(asrc + k0 + 32);
            #pragma unroll
            for (int i = 0; i < 2; ++i) {
                rh[i] = *(const int4*)(bsH[i] + k0 + 32);
                rl[i] = *(const int4*)(bsL[i] + k0 + 32);
            }
        }
        f16x8 a[4];
        #pragma unroll
        for (int fm = 0; fm < 4; ++fm) a[fm] = *(const f16x8*)&As[wm + fm * 16 + ln][ko];
        #pragma unroll
        for (int g = 0; g < 4; ++g) {
            f16x8 bh = *(const f16x8*)&Bh[g][wn + ln][ko];
            f16x8 bl = *(const f16x8*)&Bl[g][wn + ln][ko];
            #pragma unroll
            for (int fm = 0; fm < 4; ++fm) {
                acc[g][fm] = MFMA16(a[fm], bh, acc[g][fm]);
                acc[g][fm] = MFMA16(a[fm], bl, acc[g][fm]);
            }
        }
    }

    const int lm = (lane >> 4) * 4;
    const int n = bn + wn + ln;
    const float b0 = bav[n], b1 = bav[n + 512], b2 = bav[n + 1024], b3 = bav[n + 1536];
    #pragma unroll
    for (int fm = 0; fm < 4; ++fm) {
        #pragma unroll
        for (int i = 0; i < 4; ++i) {
            int m = bm + wm + fm * 16 + lm + i;
            if (m < M1) {
                float a0 = acc[0][fm][i] + b0;
                float a1 = acc[1][fm][i] + b1;
                float a2 = acc[2][fm][i] + b2;
                float a3 = acc[3][fm][i] + b3;
                ms_inp[(size_t)m * DMEM + n] = a0 * a1 - a2 * a3;
            }
        }
    }
}

// ---------------------------------------------------------------------------
// Chunked cumsum (fp32), pass3 emits fp16 ms.
// ---------------------------------------------------------------------------
__global__ __launch_bounds__(256) void scan_pass1(
    const float* __restrict__ ms_inp, float* __restrict__ csum)
{
    int c = blockIdx.x, b = blockIdx.y;
    int l0 = c * 128;
    int len = min(128, (L_SZ - 1) - l0);
    int t = threadIdx.x;
    const float2* p = (const float2*)(ms_inp + ((size_t)b * (L_SZ - 1) + l0) * DMEM) + t;
    float2 s = make_float2(0.f, 0.f);
    for (int i = 0; i < len; ++i) {
        float2 v = p[(size_t)i * 256];
        s.x += v.x; s.y += v.y;
    }
    ((float2*)(csum + ((size_t)b * 64 + c) * DMEM))[t] = s;
}

__global__ __launch_bounds__(256) void scan_pass2(float* __restrict__ csum)
{
    int idx = blockIdx.x * 256 + threadIdx.x;
    int b = idx >> 9, d = idx & 511;
    float run = 0.f;
    float* p = csum + (size_t)b * 64 * DMEM + d;
    for (int c = 0; c < 64; ++c) {
        float t = p[(size_t)c * DMEM];
        p[(size_t)c * DMEM] = run;
        run += t;
    }
}

__global__ __launch_bounds__(256) void scan_pass3(
    const float* __restrict__ ms_inp, const float* __restrict__ csum,
    h16* __restrict__ msh)
{
    int c = blockIdx.x, b = blockIdx.y;
    int l0 = c * 128;
    int len = min(128, (L_SZ - 1) - l0);
    int t = threadIdx.x;
    float2 run = ((const float2*)(csum + ((size_t)b * 64 + c) * DMEM))[t];
    const float2* p = (const float2*)(ms_inp + ((size_t)b * (L_SZ - 1) + l0) * DMEM) + t;
    f16x2* q = (f16x2*)(msh + ((size_t)b * L_SZ + l0 + 1) * DMEM) + t;
    if (c == 0) {
        f16x2 z = { (h16)0.f, (h16)0.f };
        ((f16x2*)(msh + (size_t)b * L_SZ * DMEM))[t] = z;
    }
    for (int i = 0; i < len; ++i) {
        float2 v = p[(size_t)i * 256];
        run.x += v.x; run.y += v.y;
        f16x2 o = { (h16)run.x, (h16)run.y };
        q[(size_t)i * 256] = o;
    }
}

// ---------------------------------------------------------------------------
// GEMM2 (fp16 A x split-fp16 W) + exact GELU -> fp16 y. K=1024 (x || ms).
// BM=128, BN=128, BK=32. 4 waves (2x2), each 64m x 64n.
// waves_per_eu(2,2): 256-VGPR budget, 2 blocks/CU.
// ---------------------------------------------------------------------------
__global__ __launch_bounds__(256) WAVES_EU(2, 2) void gemm_go_mfma(
    const h16* __restrict__ xh, const h16* __restrict__ msh,
    const h16* __restrict__ Wh, const h16* __restrict__ Wl,
    const float* __restrict__ bgo, h16* __restrict__ yh)
{
    __shared__ __align__(16) h16 As[128][40];
    __shared__ __align__(16) h16 Bh[128][40];
    __shared__ __align__(16) h16 Bl[128][40];

    int bx, by; xcd_remap(256, bx, by);
    const int tid  = threadIdx.x;
    const int lane = tid & 63;
    const int w    = tid >> 6;
    const int wm   = (w & 1) * 64;
    const int wn   = (w >> 1) * 64;
    const int bm   = bx * 128;
    const int bn   = by * 128;
    const int ln   = lane & 15;
    const int ko   = (lane >> 4) * 8;

    const h16 *axs[2], *ams[2]; h16* adst[2];
    #pragma unroll
    for (int i = 0; i < 2; ++i) {
        int s = tid + i * 256;
        int row = s >> 2, cc = s & 3;
        size_t off = (size_t)(bm + row) * DM + cc * 8;
        axs[i] = xh + off; ams[i] = msh + off;
        adst[i] = &As[row][cc * 8];
    }
    const h16 *bsH[2], *bsL[2]; h16 *bdH[2], *bdL[2];
    #pragma unroll
    for (int i = 0; i < 2; ++i) {
        int s = tid + i * 256;
        int n = s >> 2, cc = s & 3;
        size_t off = (size_t)(bn + n) * 1024 + cc * 8;
        bsH[i] = Wh + off; bsL[i] = Wl + off;
        bdH[i] = &Bh[n][cc * 8]; bdL[i] = &Bl[n][cc * 8];
    }

    f32x4 acc[4][4];
    #pragma unroll
    for (int a = 0; a < 4; ++a)
        #pragma unroll
        for (int b = 0; b < 4; ++b) acc[a][b] = (f32x4){0.f, 0.f, 0.f, 0.f};

    int4 ra[2], rh[2], rl[2];
    #pragma unroll
    for (int i = 0; i < 2; ++i) {
        ra[i] = *(const int4*)axs[i];
        rh[i] = *(const int4*)bsH[i];
        rl[i] = *(const int4*)bsL[i];
    }

    for (int k0 = 0; k0 < 1024; k0 += 32) {
        __syncthreads();
        #pragma unroll
        for (int i = 0; i < 2; ++i) {
            *(int4*)adst[i] = ra[i];
            *(int4*)bdH[i] = rh[i];
            *(int4*)bdL[i] = rl[i];
        }
        __syncthreads();
        if (k0 + 32 < 1024) {
            int kn = k0 + 32;
            #pragma unroll
            for (int i = 0; i < 2; ++i) {
                ra[i] = (kn < 512) ? *(const int4*)(axs[i] + kn)
                                   : *(const int4*)(ams[i] + (kn - 512));
                rh[i] = *(const int4*)(bsH[i] + kn);
                rl[i] = *(const int4*)(bsL[i] + kn);
            }
        }
        f16x8 a[4];
        #pragma unroll
        for (int fm = 0; fm < 4; ++fm) a[fm] = *(const f16x8*)&As[wm + fm * 16 + ln][ko];
        #pragma unroll
        for (int fn = 0; fn < 4; ++fn) {
            f16x8 bh = *(const f16x8*)&Bh[wn + fn * 16 + ln][ko];
            f16x8 bl = *(const f16x8*)&Bl[wn + fn * 16 + ln][ko];
            #pragma unroll
            for (int fm = 0; fm < 4; ++fm) {
                acc[fm][fn] = MFMA16(a[fm], bh, acc[fm][fn]);
                acc[fm][fn] = MFMA16(a[fm], bl, acc[fm][fn]);
            }
        }
    }

    const int lm = (lane >> 4) * 4;
    #pragma unroll
    for (int fm = 0; fm < 4; ++fm) {
        #pragma unroll
        for (int fn = 0; fn < 4; ++fn) {
            int n = bn + wn + fn * 16 + ln;
            float bias = bgo[n];
            #pragma unroll
            for (int i = 0; i < 4; ++i) {
                int m = bm + wm + fm * 16 + lm + i;
                float t = acc[fm][fn][i] + bias;
                float g = 0.5f * t * (1.0f + erff(t * 0.70710678118654752f));
                yh[(size_t)m * DM + n] = (h16)g;
            }
        }
    }
}

// ---------------------------------------------------------------------------
// GEMM3 (grouped x2, fp16 A x split-fp16 W) + GLU -> fp32 out.
// BM=128, BN=64 per group (x2), BK=32. 4 waves (2x2), each 64m x 32n x 2g.
// waves_per_eu(2,2): 256-VGPR budget, 2 blocks/CU.
// ---------------------------------------------------------------------------
__global__ __launch_bounds__(256) WAVES_EU(2, 2) void gemm_out_mfma(
    const h16* __restrict__ yh, const h16* __restrict__ Wh, const h16* __restrict__ Wl,
    const float* __restrict__ bout, float* __restrict__ out)
{
    __shared__ __align__(16) h16 As[128][40];
    __shared__ __align__(16) h16 Bh[2][64][40];
    __shared__ __align__(16) h16 Bl[2][64][40];

    int bx, by; xcd_remap(256, bx, by);
    const int tid  = threadIdx.x;
    const int lane = tid & 63;
    const int w    = tid >> 6;
    const int wm   = (w & 1) * 64;
    const int wn   = (w >> 1) * 32;
    const int bm   = bx * 128;
    const int bn   = by * 64;
    const int ln   = lane & 15;
    const int ko   = (lane >> 4) * 8;

    const h16* asrc[2]; h16* adst[2];
    #pragma unroll
    for (int i = 0; i < 2; ++i) {
        int s = tid + i * 256;
        int row = s >> 2, cc = s & 3;
        asrc[i] = yh + (size_t)(bm + row) * DM + cc * 8;
        adst[i] = &As[row][cc * 8];
    }
    const h16 *bsH[2], *bsL[2]; h16 *bdH[2], *bdL[2];
    #pragma unroll
    for (int i = 0; i < 2; ++i) {
        int s = tid + i * 256;
        int g = s >> 8, rem = s & 255;
        int n = rem >> 2, cc = rem & 3;
        size_t off = (size_t)(g * 512 + bn + n) * DM + cc * 8;
        bsH[i] = Wh + off; bsL[i] = Wl + off;
        bdH[i] = &Bh[g][n][cc * 8]; bdL[i] = &Bl[g][n][cc * 8];
    }

    f32x4 acc[2][4][2];
    #pragma unroll
    for (int g = 0; g < 2; ++g)
        #pragma unroll
        for (int a = 0; a < 4; ++a)
            #pragma unroll
            for (int b = 0; b < 2; ++b) acc[g][a][b] = (f32x4){0.f, 0.f, 0.f, 0.f};

    int4 ra[2], rh[2], rl[2];
    #pragma unroll
    for (int i = 0; i < 2; ++i) {
        ra[i] = *(const int4*)asrc[i];
        rh[i] = *(const int4*)bsH[i];
        rl[i] = *(const int4*)bsL[i];
    }

    for (int k0 = 0; k0 < DM; k0 += 32) {
        __syncthreads();
        #pragma unroll
        for (int i = 0; i < 2; ++i) {
            *(int4*)adst[i] = ra[i];
            *(int4*)bdH[i] = rh[i];
            *(int4*)bdL[i] = rl[i];
        }
        __syncthreads();
        if (k0 + 32 < DM) {
            #pragma unroll
            for (int i = 0; i < 2; ++i) {
                ra[i] = *(const int4*)(asrc[i] + k0 + 32);
                rh[i] = *(const int4*)(bsH[i] + k0 + 32);
                rl[i] = *(const int4*)(bsL[i] + k0 + 32);
            }
        }
        f16x8 a[4];
        #pragma unroll
        for (int fm = 0; fm < 4; ++fm) a[fm] = *(const f16x8*)&As[wm + fm * 16 + ln][ko];
        #pragma unroll
        for (int g = 0; g < 2; ++g) {
            #pragma unroll
            for (int fn = 0; fn < 2; ++fn) {
                f16x8 bh = *(const f16x8*)&Bh[g][wn + fn * 16 + ln][ko];
                f16x8 bl = *(const f16x8*)&Bl[g][wn + fn * 16 + ln][ko];
                #pragma unroll
                for (int fm = 0; fm < 4; ++fm) {
                    acc[g][fm][fn] = MFMA16(a[fm], bh, acc[g][fm][fn]);
                    acc[g][fm][fn] = MFMA16(a[fm], bl, acc[g][fm][fn]);
                }
            }
        }
    }

    const int lm = (lane >> 4) * 4;
    #pragma unroll
    for (int fm = 0; fm < 4; ++fm) {
        #pragma unroll
        for (int fn = 0; fn < 2; ++fn) {
            int n = bn + wn + fn * 16 + ln;
            float bz0 = bout[n], bz1 = bout[n + 512];
            #pragma unroll
            for (int i = 0; i < 4; ++i) {
                int m = bm + wm + fm * 16 + lm + i;
                float z0 = acc[0][fm][fn][i] + bz0;
                float z1 = acc[1][fm][fn][i] + bz1;
                out[(size_t)m * DM + n] = z0 * (1.0f / (1.0f + expf(-z1)));
            }
        }
    }
}

// ---------------------------------------------------------------------------
extern "C" void kernel_launch(void* const* d_in, const int* in_sizes, int n_in,
                              void* d_out, int out_size, void* d_ws, size_t ws_size,
                              hipStream_t stream)
{
    const float* x    = (const float*)d_in[0];
    const float* Wav  = (const float*)d_in[1];
    const float* bav  = (const float*)d_in[2];
    const float* Wgo  = (const float*)d_in[3];
    const float* bgo  = (const float*)d_in[4];
    const float* Wout = (const float*)d_in[5];
    const float* bout = (const float*)d_in[6];
    float* out = (float*)d_out;

    char* ws = (char*)d_ws;
    const size_t MB = 1 << 20;
    float* ms_inp = (float*)ws;                   // 64 MiB region [32764,512] f32
    h16*   yh     = (h16*)ws;                     // aliases ms_inp (used after scan)
    h16*   xh     = (h16*)(ws + 64 * MB);         // 32 MiB
    h16*   msh    = (h16*)(ws + 96 * MB);         // 32 MiB
    float* csum   = (float*)(ws + 128 * MB);      // 0.5 MiB
    h16*   Wavh   = (h16*)(ws + 129 * MB);        // 2 MiB
    h16*   Wavl   = (h16*)(ws + 131 * MB);        // 2 MiB
    h16*   Wgoh   = (h16*)(ws + 133 * MB);        // 1 MiB
    h16*   Wgol   = (h16*)(ws + 134 * MB);        // 1 MiB
    h16*   Wouth  = (h16*)(ws + 135 * MB);        // 1 MiB
    h16*   Woutl  = (h16*)(ws + 136 * MB);        // 1 MiB

    // 0) precompute fp16 forms
    conv_single<<<(M2 * DM / 4 + 255) / 256, 256, 0, stream>>>(x, xh, M2 * DM / 4);
    conv_split<<<(2048 * 512 / 4 + 255) / 256, 256, 0, stream>>>(Wav, Wavh, Wavl, 2048 * 512 / 4);
    conv_split<<<(512 * 1024 / 4 + 255) / 256, 256, 0, stream>>>(Wgo, Wgoh, Wgol, 512 * 1024 / 4);
    conv_split<<<(1024 * 512 / 4 + 255) / 256, 256, 0, stream>>>(Wout, Wouth, Woutl, 1024 * 512 / 4);
    // 1) av GEMM + NRU combine -> ms_inp (f32)
    gemm_av_mfma<<<dim3(256, 8), 512, 0, stream>>>(xh, Wavh, Wavl, bav, ms_inp);
    // 2-4) chunked cumsum -> msh (fp16)
    scan_pass1<<<dim3(64, B_SZ), 256, 0, stream>>>(ms_inp, csum);
    scan_pass2<<<8, 256, 0, stream>>>(csum);
    scan_pass3<<<dim3(64, B_SZ), 256, 0, stream>>>(ms_inp, csum, msh);
    // 5) SSM-in GEMM + GELU -> yh (fp16, reuses ms_inp region)
    gemm_go_mfma<<<dim3(256, 4), 256, 0, stream>>>(xh, msh, Wgoh, Wgol, bgo, yh);
    // 6) output GEMM + GLU -> out (f32)
    gemm_out_mfma<<<dim3(256, 8), 256, 0, stream>>>(yh, Wouth, Woutl, bout, out);
}

// Round 7
// 365.136 us; speedup vs baseline: 2.6230x; 1.6651x over previous
//
#include <hip/hip_runtime.h>
#include <hip/hip_bf16.h>
#include <math.h>

// Problem constants
#define B_SZ 4
#define L_SZ 8192
#define DM 512           // D_MODEL
#define DMEM 512         // D_MEM
#define M1 (B_SZ * (L_SZ - 1))   // 32764 rows for the av GEMM
#define M2 (B_SZ * L_SZ)         // 32768 rows for GEMM2/3

typedef _Float16 h16;
typedef __attribute__((ext_vector_type(2))) _Float16 f16x2;
typedef __attribute__((ext_vector_type(8))) _Float16 f16x8;
typedef __attribute__((ext_vector_type(4))) float f32x4;

#define MFMA16(a, b, c) __builtin_amdgcn_mfma_f32_16x16x32_f16((a), (b), (c), 0, 0, 0)
#define WAVES_EU(mn, mx) __attribute__((amdgpu_waves_per_eu(mn, mx)))

// async global->LDS, 16B per lane: LDS dst = wave-uniform base + lane*16,
// global src = per-lane address.
__device__ __forceinline__ void gl16(const void* g, void* l) {
    __builtin_amdgcn_global_load_lds(
        (const __attribute__((address_space(1))) void*)g,
        (__attribute__((address_space(3))) void*)l, 16, 0, 0);
}

// Swizzled LDS fragment read from a [128 rows][64 cols] fp16 tile (128 B rows).
// Memory (and hence LDS, staged linearly) has 16B-block index XOR'd with the
// source-row key; 'key' must equal (memory_row & 7).
__device__ __forceinline__ f16x8 lds_frag(const h16* base, int row, int col, int key) {
    return *(const f16x8*)((const char*)base + row * 128 + ((col * 2) ^ (key << 4)));
}

// fp32[8] -> fp16 hi/lo split
__device__ __forceinline__ void split8(const float* v, f16x8& hh, f16x8& ll) {
    #pragma unroll
    for (int j = 0; j < 8; ++j) {
        h16 h = (h16)v[j];
        hh[j] = h;
        ll[j] = (h16)(v[j] - (float)h);
    }
}

// bijective XCD swizzle: group blocks sharing a B-panel onto the same XCD L2
__device__ __forceinline__ void xcd_remap(int gx, int& bx, int& by) {
    int nwg = gx * gridDim.y;
    int lin = blockIdx.y * gx + blockIdx.x;
    int chunk = nwg >> 3;                   // nwg % 8 == 0 for all our grids
    int l = (lin & 7) * chunk + (lin >> 3);
    bx = l % gx;
    by = l / gx;
}

// ---------------------------------------------------------------------------
// Precompute: x (fp32) -> xh (fp16, row-swizzled). One thread per 8 elems.
// ---------------------------------------------------------------------------
__global__ __launch_bounds__(256) void conv_x(
    const float* __restrict__ src, h16* __restrict__ dst)
{
    int i = blockIdx.x * 256 + threadIdx.x;     // 32768*512/8 = 2097152 threads
    int m = i >> 6, bb = i & 63;
    const float4* s = (const float4*)(src + (size_t)m * 512 + bb * 8);
    float4 v0 = s[0], v1 = s[1];
    float vv[8] = {v0.x, v0.y, v0.z, v0.w, v1.x, v1.y, v1.z, v1.w};
    f16x8 o;
    #pragma unroll
    for (int j = 0; j < 8; ++j) o[j] = (h16)vv[j];
    int db = bb ^ (m & 7);
    *(f16x8*)(dst + (size_t)m * 512 + db * 8) = o;
}

// Wgo [512][1024] -> hi/lo fp16, row-swizzled (no row permutation).
__global__ __launch_bounds__(256) void conv_wgo(
    const float* __restrict__ src, h16* __restrict__ h, h16* __restrict__ l)
{
    int i = blockIdx.x * 256 + threadIdx.x;     // 512*128 = 65536
    int r = i >> 7, bb = i & 127;
    const float4* s = (const float4*)(src + (size_t)r * 1024 + bb * 8);
    float4 v0 = s[0], v1 = s[1];
    float vv[8] = {v0.x, v0.y, v0.z, v0.w, v1.x, v1.y, v1.z, v1.w};
    f16x8 hh, ll; split8(vv, hh, ll);
    int db = bb ^ (r & 7);
    *(f16x8*)(h + (size_t)r * 1024 + db * 8) = hh;
    *(f16x8*)(l + (size_t)r * 1024 + db * 8) = ll;
}

// Wav [2048][512] -> packed rows P = by*128 + (half*64 + g*16 + nlow), where
// orig row = g*512 + by*32 + half*16 + nlow. hi/lo split + row swizzle.
__global__ __launch_bounds__(256) void pack_wav(
    const float* __restrict__ src, h16* __restrict__ h, h16* __restrict__ l)
{
    int i = blockIdx.x * 256 + threadIdx.x;     // 2048*64 = 131072
    int P = i >> 6, bb = i & 63;
    int by = P >> 7, lo = P & 127;
    int half = lo >> 6, g = (lo >> 4) & 3, nl = lo & 15;
    int orig = g * 512 + by * 32 + half * 16 + nl;
    const float4* s = (const float4*)(src + (size_t)orig * 512 + bb * 8);
    float4 v0 = s[0], v1 = s[1];
    float vv[8] = {v0.x, v0.y, v0.z, v0.w, v1.x, v1.y, v1.z, v1.w};
    f16x8 hh, ll; split8(vv, hh, ll);
    int db = bb ^ (P & 7);
    *(f16x8*)(h + (size_t)P * 512 + db * 8) = hh;
    *(f16x8*)(l + (size_t)P * 512 + db * 8) = ll;
}

// Wout [1024][512] -> packed rows P = by*128 + (chunk*32 + g*16 + nlow), where
// orig row = g*512 + by*64 + chunk*16 + nlow.
__global__ __launch_bounds__(256) void pack_wout(
    const float* __restrict__ src, h16* __restrict__ h, h16* __restrict__ l)
{
    int i = blockIdx.x * 256 + threadIdx.x;     // 1024*64 = 65536
    int P = i >> 6, bb = i & 63;
    int by = P >> 7, lo = P & 127;
    int chunk = lo >> 5, g = (lo >> 4) & 1, nl = lo & 15;
    int orig = g * 512 + by * 64 + chunk * 16 + nl;
    const float4* s = (const float4*)(src + (size_t)orig * 512 + bb * 8);
    float4 v0 = s[0], v1 = s[1];
    float vv[8] = {v0.x, v0.y, v0.z, v0.w, v1.x, v1.y, v1.z, v1.w};
    f16x8 hh, ll; split8(vv, hh, ll);
    int db = bb ^ (P & 7);
    *(f16x8*)(h + (size_t)P * 512 + db * 8) = hh;
    *(f16x8*)(l + (size_t)P * 512 + db * 8) = ll;
}

// ---------------------------------------------------------------------------
// GEMM1: [M1 x 512] x [512 x 2048(packed 4 groups)] + NRU combine -> ms_inp.
// 128x128 tile, BK=64, global_load_lds staging, swizzled LDS. 4 waves (2x2),
// each 64m x 64n; fragment fn = group g -> combine in-register.
// ---------------------------------------------------------------------------
__global__ __launch_bounds__(256) WAVES_EU(3, 3) void gemm_av_mfma(
    const h16* __restrict__ xh, const h16* __restrict__ Wh, const h16* __restrict__ Wl,
    const float* __restrict__ bav, float* __restrict__ ms_inp)
{
    __shared__ __align__(16) h16 As[128 * 64];   // 16 KB each
    __shared__ __align__(16) h16 Bh[128 * 64];
    __shared__ __align__(16) h16 Bl[128 * 64];

    int bx, by; xcd_remap(256, bx, by);
    const int tid = threadIdx.x, lane = tid & 63, w = tid >> 6;
    const int wm = (w & 1) * 64, wn = (w >> 1) * 64;
    const int bm = bx * 128;
    const int ln = lane & 15, ko = (lane >> 4) * 8;
    const int kb = ln & 7;                       // B-side swizzle key
    char* lA = (char*)As; char* lH = (char*)Bh; char* lL = (char*)Bl;
    const int wb = w * 1024;

    const char *aP[4], *hP[4], *lP[4];
    {
        const int r8 = lane >> 3, c16 = (lane & 7) * 16;
        #pragma unroll
        for (int i = 0; i < 4; ++i) {
            int row = i * 32 + w * 8 + r8;
            int mg = bm + row; if (mg > M1 - 1) mg = M1 - 1;
            size_t xr = (size_t)mg + (unsigned)mg / (L_SZ - 1);   // skip last l per batch
            aP[i] = (const char*)xh + xr * (DM * 2) + c16;
            size_t br = (size_t)(by * 128 + row) * (DM * 2) + c16;
            hP[i] = (const char*)Wh + br;
            lP[i] = (const char*)Wl + br;
        }
    }
    // A-side swizzle keys: key = (memory row of xh) & 7 = (m + batch) & 7
    int ka[4];
    #pragma unroll
    for (int fm = 0; fm < 4; ++fm) {
        int m = bm + wm + fm * 16 + ln;
        int mg = m > M1 - 1 ? M1 - 1 : m;
        ka[fm] = (int)((mg + (unsigned)mg / (L_SZ - 1)) & 7);
    }

    f32x4 acc[4][4];
    #pragma unroll
    for (int i = 0; i < 4; ++i)
        #pragma unroll
        for (int j = 0; j < 4; ++j) acc[i][j] = (f32x4){0.f, 0.f, 0.f, 0.f};

#define STAGE_AV(aoff, boff) do { \
    gl16(aP[0] + (aoff), lA + 0 * 4096 + wb); gl16(hP[0] + (boff), lH + 0 * 4096 + wb); gl16(lP[0] + (boff), lL + 0 * 4096 + wb); \
    gl16(aP[1] + (aoff), lA + 1 * 4096 + wb); gl16(hP[1] + (boff), lH + 1 * 4096 + wb); gl16(lP[1] + (boff), lL + 1 * 4096 + wb); \
    gl16(aP[2] + (aoff), lA + 2 * 4096 + wb); gl16(hP[2] + (boff), lH + 2 * 4096 + wb); gl16(lP[2] + (boff), lL + 2 * 4096 + wb); \
    gl16(aP[3] + (aoff), lA + 3 * 4096 + wb); gl16(hP[3] + (boff), lH + 3 * 4096 + wb); gl16(lP[3] + (boff), lL + 3 * 4096 + wb); \
} while (0)

    STAGE_AV(0, 0);
    for (int kt = 0; kt < 8; ++kt) {
        asm volatile("s_waitcnt vmcnt(0)" ::: "memory");
        __syncthreads();
        #pragma unroll
        for (int s = 0; s < 2; ++s) {
            const int c = s * 32 + ko;
            f16x8 a[4];
            #pragma unroll
            for (int fm = 0; fm < 4; ++fm)
                a[fm] = lds_frag(As, wm + fm * 16 + ln, c, ka[fm]);
            #pragma unroll
            for (int fn = 0; fn < 4; ++fn) {
                f16x8 vh = lds_frag(Bh, wn + fn * 16 + ln, c, kb);
                f16x8 vl = lds_frag(Bl, wn + fn * 16 + ln, c, kb);
                #pragma unroll
                for (int fm = 0; fm < 4; ++fm) {
                    acc[fm][fn] = MFMA16(a[fm], vh, acc[fm][fn]);
                    acc[fm][fn] = MFMA16(a[fm], vl, acc[fm][fn]);
                }
            }
        }
        __syncthreads();
        if (kt < 7) { int off = (kt + 1) * 128; STAGE_AV(off, off); }
    }
#undef STAGE_AV

    // epilogue: fn = group; combine in-register
    const int lm = (lane >> 4) * 4;
    const int nn = by * 32 + (wn >> 6) * 16 + ln;
    const float b0 = bav[nn], b1 = bav[nn + 512], b2 = bav[nn + 1024], b3 = bav[nn + 1536];
    #pragma unroll
    for (int fm = 0; fm < 4; ++fm) {
        #pragma unroll
        for (int i = 0; i < 4; ++i) {
            int m = bm + wm + fm * 16 + lm + i;
            if (m < M1) {
                float a0 = acc[fm][0][i] + b0;
                float a1 = acc[fm][1][i] + b1;
                float a2 = acc[fm][2][i] + b2;
                float a3 = acc[fm][3][i] + b3;
                ms_inp[(size_t)m * DMEM + nn] = a0 * a1 - a2 * a3;
            }
        }
    }
}

// ---------------------------------------------------------------------------
// Chunked cumsum (fp32); pass3 emits fp16 msh in the swizzled layout.
// ---------------------------------------------------------------------------
__global__ __launch_bounds__(256) void scan_pass1(
    const float* __restrict__ ms_inp, float* __restrict__ csum)
{
    int c = blockIdx.x, b = blockIdx.y;
    int l0 = c * 128;
    int len = min(128, (L_SZ - 1) - l0);
    int t = threadIdx.x;
    const float2* p = (const float2*)(ms_inp + ((size_t)b * (L_SZ - 1) + l0) * DMEM) + t;
    float2 s = make_float2(0.f, 0.f);
    for (int i = 0; i < len; ++i) {
        float2 v = p[(size_t)i * 256];
        s.x += v.x; s.y += v.y;
    }
    ((float2*)(csum + ((size_t)b * 64 + c) * DMEM))[t] = s;
}

__global__ __launch_bounds__(256) void scan_pass2(float* __restrict__ csum)
{
    int idx = blockIdx.x * 256 + threadIdx.x;
    int b = idx >> 9, d = idx & 511;
    float run = 0.f;
    float* p = csum + (size_t)b * 64 * DMEM + d;
    for (int c = 0; c < 64; ++c) {
        float t = p[(size_t)c * DMEM];
        p[(size_t)c * DMEM] = run;
        run += t;
    }
}

__global__ __launch_bounds__(256) void scan_pass3(
    const float* __restrict__ ms_inp, const float* __restrict__ csum,
    h16* __restrict__ msh)
{
    int c = blockIdx.x, b = blockIdx.y;
    int l0 = c * 128;
    int len = min(128, (L_SZ - 1) - l0);
    int t = threadIdx.x;
    float2 run = ((const float2*)(csum + ((size_t)b * 64 + c) * DMEM))[t];
    const float2* p = (const float2*)(ms_inp + ((size_t)b * (L_SZ - 1) + l0) * DMEM) + t;
    const int bb = t >> 2;              // 16B block index of this thread's 4B slot
    const int sub = (t & 3) * 4;        // byte within block
    if (c == 0) {                       // row l=0: m&7==0 -> identity swizzle
        f16x2 z = {(h16)0.f, (h16)0.f};
        *(f16x2*)((char*)(msh + (size_t)b * L_SZ * DMEM) + bb * 16 + sub) = z;
    }
    for (int i = 0; i < len; ++i) {
        float2 v = p[(size_t)i * 256];
        run.x += v.x; run.y += v.y;
        int m = b * L_SZ + l0 + 1 + i;
        int db = bb ^ (m & 7);
        f16x2 o = {(h16)run.x, (h16)run.y};
        *(f16x2*)((char*)(msh + (size_t)m * DMEM) + db * 16 + sub) = o;
    }
}

// ---------------------------------------------------------------------------
// GEMM2: [M2 x 1024 (x||ms)] x [1024 x 512] + GELU -> yh (fp16, swizzled).
// ---------------------------------------------------------------------------
__global__ __launch_bounds__(256) WAVES_EU(3, 3) void gemm_go_mfma(
    const h16* __restrict__ xh, const h16* __restrict__ msh,
    const h16* __restrict__ Wh, const h16* __restrict__ Wl,
    const float* __restrict__ bgo, h16* __restrict__ yh)
{
    __shared__ __align__(16) h16 As[128 * 64];
    __shared__ __align__(16) h16 Bh[128 * 64];
    __shared__ __align__(16) h16 Bl[128 * 64];

    int bx, by; xcd_remap(256, bx, by);
    const int tid = threadIdx.x, lane = tid & 63, w = tid >> 6;
    const int wm = (w & 1) * 64, wn = (w >> 1) * 64;
    const int bm = bx * 128, bn = by * 128;
    const int ln = lane & 15, ko = (lane >> 4) * 8;
    const int kk = ln & 7;
    char* lA = (char*)As; char* lH = (char*)Bh; char* lL = (char*)Bl;
    const int wb = w * 1024;

    const char *xP[4], *mP[4], *hP[4], *lP[4];
    {
        const int r8 = lane >> 3, c16 = (lane & 7) * 16;
        #pragma unroll
        for (int i = 0; i < 4; ++i) {
            int row = i * 32 + w * 8 + r8;
            size_t ar = (size_t)(bm + row) * (DM * 2) + c16;
            xP[i] = (const char*)xh + ar;
            mP[i] = (const char*)msh + ar;
            size_t br = (size_t)(bn + row) * (2 * DM * 2) + c16;   // 1024-col rows
            hP[i] = (const char*)Wh + br;
            lP[i] = (const char*)Wl + br;
        }
    }

    f32x4 acc[4][4];
    #pragma unroll
    for (int i = 0; i < 4; ++i)
        #pragma unroll
        for (int j = 0; j < 4; ++j) acc[i][j] = (f32x4){0.f, 0.f, 0.f, 0.f};

#define STAGE_GO(AP, aoff, boff) do { \
    gl16(AP[0] + (aoff), lA + 0 * 4096 + wb); gl16(hP[0] + (boff), lH + 0 * 4096 + wb); gl16(lP[0] + (boff), lL + 0 * 4096 + wb); \
    gl16(AP[1] + (aoff), lA + 1 * 4096 + wb); gl16(hP[1] + (boff), lH + 1 * 4096 + wb); gl16(lP[1] + (boff), lL + 1 * 4096 + wb); \
    gl16(AP[2] + (aoff), lA + 2 * 4096 + wb); gl16(hP[2] + (boff), lH + 2 * 4096 + wb); gl16(lP[2] + (boff), lL + 2 * 4096 + wb); \
    gl16(AP[3] + (aoff), lA + 3 * 4096 + wb); gl16(hP[3] + (boff), lH + 3 * 4096 + wb); gl16(lP[3] + (boff), lL + 3 * 4096 + wb); \
} while (0)

    STAGE_GO(xP, 0, 0);
    for (int kt = 0; kt < 16; ++kt) {
        asm volatile("s_waitcnt vmcnt(0)" ::: "memory");
        __syncthreads();
        #pragma unroll
        for (int s = 0; s < 2; ++s) {
            const int c = s * 32 + ko;
            f16x8 a[4];
            #pragma unroll
            for (int fm = 0; fm < 4; ++fm)
                a[fm] = lds_frag(As, wm + fm * 16 + ln, c, kk);
            #pragma unroll
            for (int fn = 0; fn < 4; ++fn) {
                f16x8 vh = lds_frag(Bh, wn + fn * 16 + ln, c, kk);
                f16x8 vl = lds_frag(Bl, wn + fn * 16 + ln, c, kk);
                #pragma unroll
                for (int fm = 0; fm < 4; ++fm) {
                    acc[fm][fn] = MFMA16(a[fm], vh, acc[fm][fn]);
                    acc[fm][fn] = MFMA16(a[fm], vl, acc[fm][fn]);
                }
            }
        }
        __syncthreads();
        int nx = kt + 1;
        if (nx < 8)       { STAGE_GO(xP, nx * 128, nx * 128); }
        else if (nx < 16) { STAGE_GO(mP, (nx - 8) * 128, nx * 128); }
    }
#undef STAGE_GO

    // epilogue: GELU -> yh, swizzled write
    const int lm = (lane >> 4) * 4;
    #pragma unroll
    for (int fm = 0; fm < 4; ++fm) {
        #pragma unroll
        for (int fn = 0; fn < 4; ++fn) {
            int n = bn + wn + fn * 16 + ln;
            float bias = bgo[n];
            #pragma unroll
            for (int i = 0; i < 4; ++i) {
                int m = bm + wm + fm * 16 + lm + i;
                float t = acc[fm][fn][i] + bias;
                float g = 0.5f * t * (1.0f + erff(t * 0.70710678118654752f));
                int nsw = (((n >> 3) ^ (m & 7)) << 3) | (n & 7);
                yh[(size_t)m * DM + nsw] = (h16)g;
            }
        }
    }
}

// ---------------------------------------------------------------------------
// GEMM3: [M2 x 512] x [512 x 1024(packed 2 groups)] + GLU -> out (fp32).
// fn parity = GLU half; combine in-register.
// ---------------------------------------------------------------------------
__global__ __launch_bounds__(256) WAVES_EU(3, 3) void gemm_out_mfma(
    const h16* __restrict__ yh, const h16* __restrict__ Wh, const h16* __restrict__ Wl,
    const float* __restrict__ bout, float* __restrict__ out)
{
    __shared__ __align__(16) h16 As[128 * 64];
    __shared__ __align__(16) h16 Bh[128 * 64];
    __shared__ __align__(16) h16 Bl[128 * 64];

    int bx, by; xcd_remap(256, bx, by);
    const int tid = threadIdx.x, lane = tid & 63, w = tid >> 6;
    const int wm = (w & 1) * 64, wn = (w >> 1) * 64;
    const int bm = bx * 128;
    const int ln = lane & 15, ko = (lane >> 4) * 8;
    const int kk = ln & 7;
    char* lA = (char*)As; char* lH = (char*)Bh; char* lL = (char*)Bl;
    const int wb = w * 1024;

    const char *aP[4], *hP[4], *lP[4];
    {
        const int r8 = lane >> 3, c16 = (lane & 7) * 16;
        #pragma unroll
        for (int i = 0; i < 4; ++i) {
            int row = i * 32 + w * 8 + r8;
            aP[i] = (const char*)yh + (size_t)(bm + row) * (DM * 2) + c16;
            size_t br = (size_t)(by * 128 + row) * (DM * 2) + c16;
            hP[i] = (const char*)Wh + br;
            lP[i] = (const char*)Wl + br;
        }
    }

    f32x4 acc[4][4];
    #pragma unroll
    for (int i = 0; i < 4; ++i)
        #pragma unroll
        for (int j = 0; j < 4; ++j) acc[i][j] = (f32x4){0.f, 0.f, 0.f, 0.f};

#define STAGE_OUT(aoff, boff) do { \
    gl16(aP[0] + (aoff), lA + 0 * 4096 + wb); gl16(hP[0] + (boff), lH + 0 * 4096 + wb); gl16(lP[0] + (boff), lL + 0 * 4096 + wb); \
    gl16(aP[1] + (aoff), lA + 1 * 4096 + wb); gl16(hP[1] + (boff), lH + 1 * 4096 + wb); gl16(lP[1] + (boff), lL + 1 * 4096 + wb); \
    gl16(aP[2] + (aoff), lA + 2 * 4096 + wb); gl16(hP[2] + (boff), lH + 2 * 4096 + wb); gl16(lP[2] + (boff), lL + 2 * 4096 + wb); \
    gl16(aP[3] + (aoff), lA + 3 * 4096 + wb); gl16(hP[3] + (boff), lH + 3 * 4096 + wb); gl16(lP[3] + (boff), lL + 3 * 4096 + wb); \
} while (0)

    STAGE_OUT(0, 0);
    for (int kt = 0; kt < 8; ++kt) {
        asm volatile("s_waitcnt vmcnt(0)" ::: "memory");
        __syncthreads();
        #pragma unroll
        for (int s = 0; s < 2; ++s) {
            const int c = s * 32 + ko;
            f16x8 a[4];
            #pragma unroll
            for (int fm = 0; fm < 4; ++fm)
                a[fm] = lds_frag(As, wm + fm * 16 + ln, c, kk);
            #pragma unroll
            for (int fn = 0; fn < 4; ++fn) {
                f16x8 vh = lds_frag(Bh, wn + fn * 16 + ln, c, kk);
                f16x8 vl = lds_frag(Bl, wn + fn * 16 + ln, c, kk);
                #pragma unroll
                for (int fm = 0; fm < 4; ++fm) {
                    acc[fm][fn] = MFMA16(a[fm], vh, acc[fm][fn]);
                    acc[fm][fn] = MFMA16(a[fm], vl, acc[fm][fn]);
                }
            }
        }
        __syncthreads();
        if (kt < 7) { int off = (kt + 1) * 128; STAGE_OUT(off, off); }
    }
#undef STAGE_OUT

    // epilogue: GLU (fn pairs: even = z0-half, odd = z1-half)
    const int lm = (lane >> 4) * 4;
    #pragma unroll
    for (int fm = 0; fm < 4; ++fm) {
        #pragma unroll
        for (int cp = 0; cp < 2; ++cp) {
            int ncol = by * 64 + ((wn >> 5) + cp) * 16 + ln;
            float bz0 = bout[ncol], bz1 = bout[ncol + 512];
            #pragma unroll
            for (int i = 0; i < 4; ++i) {
                int m = bm + wm + fm * 16 + lm + i;
                float z0 = acc[fm][cp * 2 + 0][i] + bz0;
                float z1 = acc[fm][cp * 2 + 1][i] + bz1;
                out[(size_t)m * DM + ncol] = z0 * (1.0f / (1.0f + expf(-z1)));
            }
        }
    }
}

// ---------------------------------------------------------------------------
extern "C" void kernel_launch(void* const* d_in, const int* in_sizes, int n_in,
                              void* d_out, int out_size, void* d_ws, size_t ws_size,
                              hipStream_t stream)
{
    const float* x    = (const float*)d_in[0];
    const float* Wav  = (const float*)d_in[1];
    const float* bav  = (const float*)d_in[2];
    const float* Wgo  = (const float*)d_in[3];
    const float* bgo  = (const float*)d_in[4];
    const float* Wout = (const float*)d_in[5];
    const float* bout = (const float*)d_in[6];
    float* out = (float*)d_out;

    char* ws = (char*)d_ws;
    const size_t MB = 1 << 20;
    float* ms_inp = (float*)ws;                   // 64 MiB [32764,512] f32
    h16*   yh     = (h16*)ws;                     // aliases ms_inp (after scan)
    h16*   xh     = (h16*)(ws + 64 * MB);         // 32 MiB (swizzled fp16)
    h16*   msh    = (h16*)(ws + 96 * MB);         // 32 MiB (swizzled fp16)
    float* csum   = (float*)(ws + 128 * MB);      // 0.5 MiB
    h16*   Wavh   = (h16*)(ws + 129 * MB);        // 2 MiB (packed+swizzled)
    h16*   Wavl   = (h16*)(ws + 131 * MB);        // 2 MiB
    h16*   Wgoh   = (h16*)(ws + 133 * MB);        // 1 MiB
    h16*   Wgol   = (h16*)(ws + 134 * MB);        // 1 MiB
    h16*   Wouth  = (h16*)(ws + 135 * MB);        // 1 MiB
    h16*   Woutl  = (h16*)(ws + 136 * MB);        // 1 MiB

    // 0) precompute fp16 forms (swizzled / packed)
    conv_x   <<<8192, 256, 0, stream>>>(x, xh);
    conv_wgo <<<256,  256, 0, stream>>>(Wgo, Wgoh, Wgol);
    pack_wav <<<512,  256, 0, stream>>>(Wav, Wavh, Wavl);
    pack_wout<<<256,  256, 0, stream>>>(Wout, Wouth, Woutl);
    // 1) av GEMM + NRU combine -> ms_inp (f32)
    gemm_av_mfma<<<dim3(256, 16), 256, 0, stream>>>(xh, Wavh, Wavl, bav, ms_inp);
    // 2-4) chunked cumsum -> msh (fp16, swizzled)
    scan_pass1<<<dim3(64, B_SZ), 256, 0, stream>>>(ms_inp, csum);
    scan_pass2<<<8, 256, 0, stream>>>(csum);
    scan_pass3<<<dim3(64, B_SZ), 256, 0, stream>>>(ms_inp, csum, msh);
    // 5) SSM-in GEMM + GELU -> yh (fp16 swizzled, reuses ms_inp region)
    gemm_go_mfma<<<dim3(256, 4), 256, 0, stream>>>(xh, msh, Wgoh, Wgol, bgo, yh);
    // 6) output GEMM + GLU -> out (f32)
    gemm_out_mfma<<<dim3(256, 8), 256, 0, stream>>>(yh, Wouth, Woutl, bout, out);
}

// Round 8
// 318.936 us; speedup vs baseline: 3.0029x; 1.1449x over previous
//
#include <hip/hip_runtime.h>
#include <hip/hip_bf16.h>
#include <math.h>

// Problem constants
#define B_SZ 4
#define L_SZ 8192
#define DM 512           // D_MODEL
#define DMEM 512         // D_MEM
#define M1 (B_SZ * (L_SZ - 1))   // 32764 rows for the av GEMM
#define M2 (B_SZ * L_SZ)         // 32768 rows for GEMM2/3

typedef _Float16 h16;
typedef __attribute__((ext_vector_type(2))) _Float16 f16x2;
typedef __attribute__((ext_vector_type(8))) _Float16 f16x8;
typedef __attribute__((ext_vector_type(4))) float f32x4;

#define MFMA16(a, b, c) __builtin_amdgcn_mfma_f32_16x16x32_f16((a), (b), (c), 0, 0, 0)
#define WAVES_EU(mn, mx) __attribute__((amdgpu_waves_per_eu(mn, mx)))

// async global->LDS, 16B per lane: LDS dst = wave-uniform base + lane*16,
// global src = per-lane address.
__device__ __forceinline__ void gl16(const void* g, void* l) {
    __builtin_amdgcn_global_load_lds(
        (const __attribute__((address_space(1))) void*)g,
        (__attribute__((address_space(3))) void*)l, 16, 0, 0);
}

// Swizzled LDS fragment read from a [128 rows][64 cols] fp16 tile (128 B rows).
// Memory (and hence LDS, staged linearly) has 16B-block index XOR'd with the
// source-row key; 'key' must equal (memory_row & 7).
__device__ __forceinline__ f16x8 lds_frag(const h16* base, int row, int col, int key) {
    return *(const f16x8*)((const char*)base + row * 128 + ((col * 2) ^ (key << 4)));
}

// bijective XCD swizzle: group blocks sharing a B-panel onto the same XCD L2
__device__ __forceinline__ void xcd_remap(int gx, int& bx, int& by) {
    int nwg = gx * gridDim.y;
    int lin = blockIdx.y * gx + blockIdx.x;
    int chunk = nwg >> 3;                   // nwg % 8 == 0 for all our grids
    int l = (lin & 7) * chunk + (lin >> 3);
    bx = l % gx;
    by = l / gx;
}

// ---------------------------------------------------------------------------
// Precompute: x (fp32) -> xh (fp16, row-swizzled). One thread per 8 elems.
// ---------------------------------------------------------------------------
__global__ __launch_bounds__(256) void conv_x(
    const float* __restrict__ src, h16* __restrict__ dst)
{
    int i = blockIdx.x * 256 + threadIdx.x;     // 32768*512/8 = 2097152 threads
    int m = i >> 6, bb = i & 63;
    const float4* s = (const float4*)(src + (size_t)m * 512 + bb * 8);
    float4 v0 = s[0], v1 = s[1];
    float vv[8] = {v0.x, v0.y, v0.z, v0.w, v1.x, v1.y, v1.z, v1.w};
    f16x8 o;
    #pragma unroll
    for (int j = 0; j < 8; ++j) o[j] = (h16)vv[j];
    int db = bb ^ (m & 7);
    *(f16x8*)(dst + (size_t)m * 512 + db * 8) = o;
}

// Wgo [512][1024] -> fp16, row-swizzled (no row permutation).
__global__ __launch_bounds__(256) void conv_wgo(
    const float* __restrict__ src, h16* __restrict__ h)
{
    int i = blockIdx.x * 256 + threadIdx.x;     // 512*128 = 65536
    int r = i >> 7, bb = i & 127;
    const float4* s = (const float4*)(src + (size_t)r * 1024 + bb * 8);
    float4 v0 = s[0], v1 = s[1];
    float vv[8] = {v0.x, v0.y, v0.z, v0.w, v1.x, v1.y, v1.z, v1.w};
    f16x8 hh;
    #pragma unroll
    for (int j = 0; j < 8; ++j) hh[j] = (h16)vv[j];
    int db = bb ^ (r & 7);
    *(f16x8*)(h + (size_t)r * 1024 + db * 8) = hh;
}

// Wav [2048][512] -> packed rows P = by*128 + (half*64 + g*16 + nlow), where
// orig row = g*512 + by*32 + half*16 + nlow. fp16 + row swizzle.
__global__ __launch_bounds__(256) void pack_wav(
    const float* __restrict__ src, h16* __restrict__ h)
{
    int i = blockIdx.x * 256 + threadIdx.x;     // 2048*64 = 131072
    int P = i >> 6, bb = i & 63;
    int by = P >> 7, lo = P & 127;
    int half = lo >> 6, g = (lo >> 4) & 3, nl = lo & 15;
    int orig = g * 512 + by * 32 + half * 16 + nl;
    const float4* s = (const float4*)(src + (size_t)orig * 512 + bb * 8);
    float4 v0 = s[0], v1 = s[1];
    float vv[8] = {v0.x, v0.y, v0.z, v0.w, v1.x, v1.y, v1.z, v1.w};
    f16x8 hh;
    #pragma unroll
    for (int j = 0; j < 8; ++j) hh[j] = (h16)vv[j];
    int db = bb ^ (P & 7);
    *(f16x8*)(h + (size_t)P * 512 + db * 8) = hh;
}

// Wout [1024][512] -> packed rows P = by*128 + (chunk*32 + g*16 + nlow), where
// orig row = g*512 + by*64 + chunk*16 + nlow.
__global__ __launch_bounds__(256) void pack_wout(
    const float* __restrict__ src, h16* __restrict__ h)
{
    int i = blockIdx.x * 256 + threadIdx.x;     // 1024*64 = 65536
    int P = i >> 6, bb = i & 63;
    int by = P >> 7, lo = P & 127;
    int chunk = lo >> 5, g = (lo >> 4) & 1, nl = lo & 15;
    int orig = g * 512 + by * 64 + chunk * 16 + nl;
    const float4* s = (const float4*)(src + (size_t)orig * 512 + bb * 8);
    float4 v0 = s[0], v1 = s[1];
    float vv[8] = {v0.x, v0.y, v0.z, v0.w, v1.x, v1.y, v1.z, v1.w};
    f16x8 hh;
    #pragma unroll
    for (int j = 0; j < 8; ++j) hh[j] = (h16)vv[j];
    int db = bb ^ (P & 7);
    *(f16x8*)(h + (size_t)P * 512 + db * 8) = hh;
}

// ---------------------------------------------------------------------------
// GEMM1: [M1 x 512] x [512 x 2048(packed 4 groups)] + NRU combine -> ms_inp.
// 128x128 tile, BK=64, global_load_lds staging, swizzled LDS. 4 waves (2x2),
// each 64m x 64n; fragment fn = group g -> combine in-register.
// ---------------------------------------------------------------------------
__global__ __launch_bounds__(256) WAVES_EU(3, 3) void gemm_av_mfma(
    const h16* __restrict__ xh, const h16* __restrict__ Wh,
    const float* __restrict__ bav, float* __restrict__ ms_inp)
{
    __shared__ __align__(16) h16 As[128 * 64];   // 16 KB each
    __shared__ __align__(16) h16 Bh[128 * 64];

    int bx, by; xcd_remap(256, bx, by);
    const int tid = threadIdx.x, lane = tid & 63, w = tid >> 6;
    const int wm = (w & 1) * 64, wn = (w >> 1) * 64;
    const int bm = bx * 128;
    const int ln = lane & 15, ko = (lane >> 4) * 8;
    const int kb = ln & 7;                       // B-side swizzle key
    char* lA = (char*)As; char* lH = (char*)Bh;
    const int wb = w * 1024;

    const char *aP[4], *hP[4];
    {
        const int r8 = lane >> 3, c16 = (lane & 7) * 16;
        #pragma unroll
        for (int i = 0; i < 4; ++i) {
            int row = i * 32 + w * 8 + r8;
            int mg = bm + row; if (mg > M1 - 1) mg = M1 - 1;
            size_t xr = (size_t)mg + (unsigned)mg / (L_SZ - 1);   // skip last l per batch
            aP[i] = (const char*)xh + xr * (DM * 2) + c16;
            size_t br = (size_t)(by * 128 + row) * (DM * 2) + c16;
            hP[i] = (const char*)Wh + br;
        }
    }
    // A-side swizzle keys: key = (memory row of xh) & 7 = (m + batch) & 7
    int ka[4];
    #pragma unroll
    for (int fm = 0; fm < 4; ++fm) {
        int m = bm + wm + fm * 16 + ln;
        int mg = m > M1 - 1 ? M1 - 1 : m;
        ka[fm] = (int)((mg + (unsigned)mg / (L_SZ - 1)) & 7);
    }

    f32x4 acc[4][4];
    #pragma unroll
    for (int i = 0; i < 4; ++i)
        #pragma unroll
        for (int j = 0; j < 4; ++j) acc[i][j] = (f32x4){0.f, 0.f, 0.f, 0.f};

#define STAGE_AV(aoff, boff) do { \
    gl16(aP[0] + (aoff), lA + 0 * 4096 + wb); gl16(hP[0] + (boff), lH + 0 * 4096 + wb); \
    gl16(aP[1] + (aoff), lA + 1 * 4096 + wb); gl16(hP[1] + (boff), lH + 1 * 4096 + wb); \
    gl16(aP[2] + (aoff), lA + 2 * 4096 + wb); gl16(hP[2] + (boff), lH + 2 * 4096 + wb); \
    gl16(aP[3] + (aoff), lA + 3 * 4096 + wb); gl16(hP[3] + (boff), lH + 3 * 4096 + wb); \
} while (0)

    STAGE_AV(0, 0);
    for (int kt = 0; kt < 8; ++kt) {
        asm volatile("s_waitcnt vmcnt(0)" ::: "memory");
        __syncthreads();
        #pragma unroll
        for (int s = 0; s < 2; ++s) {
            const int c = s * 32 + ko;
            f16x8 a[4];
            #pragma unroll
            for (int fm = 0; fm < 4; ++fm)
                a[fm] = lds_frag(As, wm + fm * 16 + ln, c, ka[fm]);
            #pragma unroll
            for (int fn = 0; fn < 4; ++fn) {
                f16x8 vh = lds_frag(Bh, wn + fn * 16 + ln, c, kb);
                #pragma unroll
                for (int fm = 0; fm < 4; ++fm)
                    acc[fm][fn] = MFMA16(a[fm], vh, acc[fm][fn]);
            }
        }
        __syncthreads();
        if (kt < 7) { int off = (kt + 1) * 128; STAGE_AV(off, off); }
    }
#undef STAGE_AV

    // epilogue: fn = group; combine in-register
    const int lm = (lane >> 4) * 4;
    const int nn = by * 32 + (wn >> 6) * 16 + ln;
    const float b0 = bav[nn], b1 = bav[nn + 512], b2 = bav[nn + 1024], b3 = bav[nn + 1536];
    #pragma unroll
    for (int fm = 0; fm < 4; ++fm) {
        #pragma unroll
        for (int i = 0; i < 4; ++i) {
            int m = bm + wm + fm * 16 + lm + i;
            if (m < M1) {
                float a0 = acc[fm][0][i] + b0;
                float a1 = acc[fm][1][i] + b1;
                float a2 = acc[fm][2][i] + b2;
                float a3 = acc[fm][3][i] + b3;
                ms_inp[(size_t)m * DMEM + nn] = a0 * a1 - a2 * a3;
            }
        }
    }
}

// ---------------------------------------------------------------------------
// Chunked cumsum (fp32); pass3 emits fp16 msh in the swizzled layout.
// ---------------------------------------------------------------------------
__global__ __launch_bounds__(256) void scan_pass1(
    const float* __restrict__ ms_inp, float* __restrict__ csum)
{
    int c = blockIdx.x, b = blockIdx.y;
    int l0 = c * 128;
    int len = min(128, (L_SZ - 1) - l0);
    int t = threadIdx.x;
    const float2* p = (const float2*)(ms_inp + ((size_t)b * (L_SZ - 1) + l0) * DMEM) + t;
    float2 s = make_float2(0.f, 0.f);
    for (int i = 0; i < len; ++i) {
        float2 v = p[(size_t)i * 256];
        s.x += v.x; s.y += v.y;
    }
    ((float2*)(csum + ((size_t)b * 64 + c) * DMEM))[t] = s;
}

__global__ __launch_bounds__(256) void scan_pass2(float* __restrict__ csum)
{
    int idx = blockIdx.x * 256 + threadIdx.x;
    int b = idx >> 9, d = idx & 511;
    float run = 0.f;
    float* p = csum + (size_t)b * 64 * DMEM + d;
    for (int c = 0; c < 64; ++c) {
        float t = p[(size_t)c * DMEM];
        p[(size_t)c * DMEM] = run;
        run += t;
    }
}

__global__ __launch_bounds__(256) void scan_pass3(
    const float* __restrict__ ms_inp, const float* __restrict__ csum,
    h16* __restrict__ msh)
{
    int c = blockIdx.x, b = blockIdx.y;
    int l0 = c * 128;
    int len = min(128, (L_SZ - 1) - l0);
    int t = threadIdx.x;
    float2 run = ((const float2*)(csum + ((size_t)b * 64 + c) * DMEM))[t];
    const float2* p = (const float2*)(ms_inp + ((size_t)b * (L_SZ - 1) + l0) * DMEM) + t;
    const int bb = t >> 2;              // 16B block index of this thread's 4B slot
    const int sub = (t & 3) * 4;        // byte within block
    if (c == 0) {                       // row l=0: m&7==0 -> identity swizzle
        f16x2 z = {(h16)0.f, (h16)0.f};
        *(f16x2*)((char*)(msh + (size_t)b * L_SZ * DMEM) + bb * 16 + sub) = z;
    }
    for (int i = 0; i < len; ++i) {
        float2 v = p[(size_t)i * 256];
        run.x += v.x; run.y += v.y;
        int m = b * L_SZ + l0 + 1 + i;
        int db = bb ^ (m & 7);
        f16x2 o = {(h16)run.x, (h16)run.y};
        *(f16x2*)((char*)(msh + (size_t)m * DMEM) + db * 16 + sub) = o;
    }
}

// ---------------------------------------------------------------------------
// GEMM2: [M2 x 1024 (x||ms)] x [1024 x 512] + GELU -> yh (fp16, swizzled).
// ---------------------------------------------------------------------------
__global__ __launch_bounds__(256) WAVES_EU(3, 3) void gemm_go_mfma(
    const h16* __restrict__ xh, const h16* __restrict__ msh,
    const h16* __restrict__ Wh,
    const float* __restrict__ bgo, h16* __restrict__ yh)
{
    __shared__ __align__(16) h16 As[128 * 64];
    __shared__ __align__(16) h16 Bh[128 * 64];

    int bx, by; xcd_remap(256, bx, by);
    const int tid = threadIdx.x, lane = tid & 63, w = tid >> 6;
    const int wm = (w & 1) * 64, wn = (w >> 1) * 64;
    const int bm = bx * 128, bn = by * 128;
    const int ln = lane & 15, ko = (lane >> 4) * 8;
    const int kk = ln & 7;
    char* lA = (char*)As; char* lH = (char*)Bh;
    const int wb = w * 1024;

    const char *xP[4], *mP[4], *hP[4];
    {
        const int r8 = lane >> 3, c16 = (lane & 7) * 16;
        #pragma unroll
        for (int i = 0; i < 4; ++i) {
            int row = i * 32 + w * 8 + r8;
            size_t ar = (size_t)(bm + row) * (DM * 2) + c16;
            xP[i] = (const char*)xh + ar;
            mP[i] = (const char*)msh + ar;
            size_t br = (size_t)(bn + row) * (2 * DM * 2) + c16;   // 1024-col rows
            hP[i] = (const char*)Wh + br;
        }
    }

    f32x4 acc[4][4];
    #pragma unroll
    for (int i = 0; i < 4; ++i)
        #pragma unroll
        for (int j = 0; j < 4; ++j) acc[i][j] = (f32x4){0.f, 0.f, 0.f, 0.f};

#define STAGE_GO(AP, aoff, boff) do { \
    gl16(AP[0] + (aoff), lA + 0 * 4096 + wb); gl16(hP[0] + (boff), lH + 0 * 4096 + wb); \
    gl16(AP[1] + (aoff), lA + 1 * 4096 + wb); gl16(hP[1] + (boff), lH + 1 * 4096 + wb); \
    gl16(AP[2] + (aoff), lA + 2 * 4096 + wb); gl16(hP[2] + (boff), lH + 2 * 4096 + wb); \
    gl16(AP[3] + (aoff), lA + 3 * 4096 + wb); gl16(hP[3] + (boff), lH + 3 * 4096 + wb); \
} while (0)

    STAGE_GO(xP, 0, 0);
    for (int kt = 0; kt < 16; ++kt) {
        asm volatile("s_waitcnt vmcnt(0)" ::: "memory");
        __syncthreads();
        #pragma unroll
        for (int s = 0; s < 2; ++s) {
            const int c = s * 32 + ko;
            f16x8 a[4];
            #pragma unroll
            for (int fm = 0; fm < 4; ++fm)
                a[fm] = lds_frag(As, wm + fm * 16 + ln, c, kk);
            #pragma unroll
            for (int fn = 0; fn < 4; ++fn) {
                f16x8 vh = lds_frag(Bh, wn + fn * 16 + ln, c, kk);
                #pragma unroll
                for (int fm = 0; fm < 4; ++fm)
                    acc[fm][fn] = MFMA16(a[fm], vh, acc[fm][fn]);
            }
        }
        __syncthreads();
        int nx = kt + 1;
        if (nx < 8)       { STAGE_GO(xP, nx * 128, nx * 128); }
        else if (nx < 16) { STAGE_GO(mP, (nx - 8) * 128, nx * 128); }
    }
#undef STAGE_GO

    // epilogue: GELU -> yh, swizzled write
    const int lm = (lane >> 4) * 4;
    #pragma unroll
    for (int fm = 0; fm < 4; ++fm) {
        #pragma unroll
        for (int fn = 0; fn < 4; ++fn) {
            int n = bn + wn + fn * 16 + ln;
            float bias = bgo[n];
            #pragma unroll
            for (int i = 0; i < 4; ++i) {
                int m = bm + wm + fm * 16 + lm + i;
                float t = acc[fm][fn][i] + bias;
                float g = 0.5f * t * (1.0f + erff(t * 0.70710678118654752f));
                int nsw = (((n >> 3) ^ (m & 7)) << 3) | (n & 7);
                yh[(size_t)m * DM + nsw] = (h16)g;
            }
        }
    }
}

// ---------------------------------------------------------------------------
// GEMM3: [M2 x 512] x [512 x 1024(packed 2 groups)] + GLU -> out (fp32).
// fn parity = GLU half; combine in-register.
// ---------------------------------------------------------------------------
__global__ __launch_bounds__(256) WAVES_EU(3, 3) void gemm_out_mfma(
    const h16* __restrict__ yh, const h16* __restrict__ Wh,
    const float* __restrict__ bout, float* __restrict__ out)
{
    __shared__ __align__(16) h16 As[128 * 64];
    __shared__ __align__(16) h16 Bh[128 * 64];

    int bx, by; xcd_remap(256, bx, by);
    const int tid = threadIdx.x, lane = tid & 63, w = tid >> 6;
    const int wm = (w & 1) * 64, wn = (w >> 1) * 64;
    const int bm = bx * 128;
    const int ln = lane & 15, ko = (lane >> 4) * 8;
    const int kk = ln & 7;
    char* lA = (char*)As; char* lH = (char*)Bh;
    const int wb = w * 1024;

    const char *aP[4], *hP[4];
    {
        const int r8 = lane >> 3, c16 = (lane & 7) * 16;
        #pragma unroll
        for (int i = 0; i < 4; ++i) {
            int row = i * 32 + w * 8 + r8;
            aP[i] = (const char*)yh + (size_t)(bm + row) * (DM * 2) + c16;
            size_t br = (size_t)(by * 128 + row) * (DM * 2) + c16;
            hP[i] = (const char*)Wh + br;
        }
    }

    f32x4 acc[4][4];
    #pragma unroll
    for (int i = 0; i < 4; ++i)
        #pragma unroll
        for (int j = 0; j < 4; ++j) acc[i][j] = (f32x4){0.f, 0.f, 0.f, 0.f};

#define STAGE_OUT(aoff, boff) do { \
    gl16(aP[0] + (aoff), lA + 0 * 4096 + wb); gl16(hP[0] + (boff), lH + 0 * 4096 + wb); \
    gl16(aP[1] + (aoff), lA + 1 * 4096 + wb); gl16(hP[1] + (boff), lH + 1 * 4096 + wb); \
    gl16(aP[2] + (aoff), lA + 2 * 4096 + wb); gl16(hP[2] + (boff), lH + 2 * 4096 + wb); \
    gl16(aP[3] + (aoff), lA + 3 * 4096 + wb); gl16(hP[3] + (boff), lH + 3 * 4096 + wb); \
} while (0)

    STAGE_OUT(0, 0);
    for (int kt = 0; kt < 8; ++kt) {
        asm volatile("s_waitcnt vmcnt(0)" ::: "memory");
        __syncthreads();
        #pragma unroll
        for (int s = 0; s < 2; ++s) {
            const int c = s * 32 + ko;
            f16x8 a[4];
            #pragma unroll
            for (int fm = 0; fm < 4; ++fm)
                a[fm] = lds_frag(As, wm + fm * 16 + ln, c, kk);
            #pragma unroll
            for (int fn = 0; fn < 4; ++fn) {
                f16x8 vh = lds_frag(Bh, wn + fn * 16 + ln, c, kk);
                #pragma unroll
                for (int fm = 0; fm < 4; ++fm)
                    acc[fm][fn] = MFMA16(a[fm], vh, acc[fm][fn]);
            }
        }
        __syncthreads();
        if (kt < 7) { int off = (kt + 1) * 128; STAGE_OUT(off, off); }
    }
#undef STAGE_OUT

    // epilogue: GLU (fn pairs: even = z0-half, odd = z1-half)
    const int lm = (lane >> 4) * 4;
    #pragma unroll
    for (int fm = 0; fm < 4; ++fm) {
        #pragma unroll
        for (int cp = 0; cp < 2; ++cp) {
            int ncol = by * 64 + ((wn >> 5) + cp) * 16 + ln;
            float bz0 = bout[ncol], bz1 = bout[ncol + 512];
            #pragma unroll
            for (int i = 0; i < 4; ++i) {
                int m = bm + wm + fm * 16 + lm + i;
                float z0 = acc[fm][cp * 2 + 0][i] + bz0;
                float z1 = acc[fm][cp * 2 + 1][i] + bz1;
                out[(size_t)m * DM + ncol] = z0 * (1.0f / (1.0f + expf(-z1)));
            }
        }
    }
}

// ---------------------------------------------------------------------------
extern "C" void kernel_launch(void* const* d_in, const int* in_sizes, int n_in,
                              void* d_out, int out_size, void* d_ws, size_t ws_size,
                              hipStream_t stream)
{
    const float* x    = (const float*)d_in[0];
    const float* Wav  = (const float*)d_in[1];
    const float* bav  = (const float*)d_in[2];
    const float* Wgo  = (const float*)d_in[3];
    const float* bgo  = (const float*)d_in[4];
    const float* Wout = (const float*)d_in[5];
    const float* bout = (const float*)d_in[6];
    float* out = (float*)d_out;

    char* ws = (char*)d_ws;
    const size_t MB = 1 << 20;
    float* ms_inp = (float*)ws;                   // 64 MiB [32764,512] f32
    h16*   yh     = (h16*)ws;                     // aliases ms_inp (after scan)
    h16*   xh     = (h16*)(ws + 64 * MB);         // 32 MiB (swizzled fp16)
    h16*   msh    = (h16*)(ws + 96 * MB);         // 32 MiB (swizzled fp16)
    float* csum   = (float*)(ws + 128 * MB);      // 0.5 MiB
    h16*   Wavh   = (h16*)(ws + 129 * MB);        // 2 MiB (packed+swizzled)
    h16*   Wgoh   = (h16*)(ws + 131 * MB);        // 1 MiB
    h16*   Wouth  = (h16*)(ws + 132 * MB);        // 1 MiB

    // 0) precompute fp16 forms (swizzled / packed)
    conv_x   <<<8192, 256, 0, stream>>>(x, xh);
    conv_wgo <<<256,  256, 0, stream>>>(Wgo, Wgoh);
    pack_wav <<<512,  256, 0, stream>>>(Wav, Wavh);
    pack_wout<<<256,  256, 0, stream>>>(Wout, Wouth);
    // 1) av GEMM + NRU combine -> ms_inp (f32)
    gemm_av_mfma<<<dim3(256, 16), 256, 0, stream>>>(xh, Wavh, bav, ms_inp);
    // 2-4) chunked cumsum -> msh (fp16, swizzled)
    scan_pass1<<<dim3(64, B_SZ), 256, 0, stream>>>(ms_inp, csum);
    scan_pass2<<<8, 256, 0, stream>>>(csum);
    scan_pass3<<<dim3(64, B_SZ), 256, 0, stream>>>(ms_inp, csum, msh);
    // 5) SSM-in GEMM + GELU -> yh (fp16 swizzled, reuses ms_inp region)
    gemm_go_mfma<<<dim3(256, 4), 256, 0, stream>>>(xh, msh, Wgoh, bgo, yh);
    // 6) output GEMM + GLU -> out (f32)
    gemm_out_mfma<<<dim3(256, 8), 256, 0, stream>>>(yh, Wouth, bout, out);
}

// Round 9
// 287.983 us; speedup vs baseline: 3.3257x; 1.1075x over previous
//
#include <hip/hip_runtime.h>
#include <hip/hip_bf16.h>
#include <math.h>

// Problem constants
#define B_SZ 4
#define L_SZ 8192
#define DM 512           // D_MODEL
#define DMEM 512         // D_MEM
#define M1 (B_SZ * (L_SZ - 1))   // 32764 rows for the av GEMM
#define M2 (B_SZ * L_SZ)         // 32768 rows for GEMM2/3

typedef _Float16 h16;
typedef __attribute__((ext_vector_type(2))) _Float16 f16x2;
typedef __attribute__((ext_vector_type(8))) _Float16 f16x8;
typedef __attribute__((ext_vector_type(4))) float f32x4;

#define MFMA16(a, b, c) __builtin_amdgcn_mfma_f32_16x16x32_f16((a), (b), (c), 0, 0, 0)
#define WAVES_EU(mn, mx) __attribute__((amdgpu_waves_per_eu(mn, mx)))

// async global->LDS, 16B per lane: LDS dst = wave-uniform base + lane*16,
// global src = per-lane address.
__device__ __forceinline__ void gl16(const void* g, void* l) {
    __builtin_amdgcn_global_load_lds(
        (const __attribute__((address_space(1))) void*)g,
        (__attribute__((address_space(3))) void*)l, 16, 0, 0);
}

// Swizzled LDS fragment read from a [128 rows][64 cols] fp16 tile (128 B rows).
// Memory (and hence LDS, staged linearly) has 16B-block index XOR'd with the
// source-row key; 'key' must equal (memory_row & 7).
__device__ __forceinline__ f16x8 lds_frag(const h16* base, int row, int col, int key) {
    return *(const f16x8*)((const char*)base + row * 128 + ((col * 2) ^ (key << 4)));
}

// XCD swizzle, A-reuse-friendly decode: blocks on one XCD get a contiguous
// chunk of l; decoding by-FAST means the gy consecutive blocks share one
// A-tile (L2-hit) while the small weight panels become L2-resident.
__device__ __forceinline__ void xcd_remap(int& bx, int& by) {
    int gx = gridDim.x, gy = gridDim.y;
    int nwg = gx * gy;                      // divisible by 8 for all our grids
    int lin = blockIdx.y * gx + blockIdx.x;
    int chunk = nwg >> 3;
    int l = (lin & 7) * chunk + (lin >> 3);
    by = l % gy;                            // fast: weight panel
    bx = l / gy;                            // slow: activation tile (reused gy times)
}

// ---------------------------------------------------------------------------
// Precompute: x (fp32) -> xh (fp16, row-swizzled). One thread per 8 elems.
// ---------------------------------------------------------------------------
__global__ __launch_bounds__(256) void conv_x(
    const float* __restrict__ src, h16* __restrict__ dst)
{
    int i = blockIdx.x * 256 + threadIdx.x;     // 32768*512/8 = 2097152 threads
    int m = i >> 6, bb = i & 63;
    const float4* s = (const float4*)(src + (size_t)m * 512 + bb * 8);
    float4 v0 = s[0], v1 = s[1];
    float vv[8] = {v0.x, v0.y, v0.z, v0.w, v1.x, v1.y, v1.z, v1.w};
    f16x8 o;
    #pragma unroll
    for (int j = 0; j < 8; ++j) o[j] = (h16)vv[j];
    int db = bb ^ (m & 7);
    *(f16x8*)(dst + (size_t)m * 512 + db * 8) = o;
}

// Wgo [512][1024] -> fp16, row-swizzled (no row permutation).
__global__ __launch_bounds__(256) void conv_wgo(
    const float* __restrict__ src, h16* __restrict__ h)
{
    int i = blockIdx.x * 256 + threadIdx.x;     // 512*128 = 65536
    int r = i >> 7, bb = i & 127;
    const float4* s = (const float4*)(src + (size_t)r * 1024 + bb * 8);
    float4 v0 = s[0], v1 = s[1];
    float vv[8] = {v0.x, v0.y, v0.z, v0.w, v1.x, v1.y, v1.z, v1.w};
    f16x8 hh;
    #pragma unroll
    for (int j = 0; j < 8; ++j) hh[j] = (h16)vv[j];
    int db = bb ^ (r & 7);
    *(f16x8*)(h + (size_t)r * 1024 + db * 8) = hh;
}

// Wav [2048][512] -> packed rows P = by*128 + (half*64 + g*16 + nlow), where
// orig row = g*512 + by*32 + half*16 + nlow. fp16 + row swizzle.
__global__ __launch_bounds__(256) void pack_wav(
    const float* __restrict__ src, h16* __restrict__ h)
{
    int i = blockIdx.x * 256 + threadIdx.x;     // 2048*64 = 131072
    int P = i >> 6, bb = i & 63;
    int by = P >> 7, lo = P & 127;
    int half = lo >> 6, g = (lo >> 4) & 3, nl = lo & 15;
    int orig = g * 512 + by * 32 + half * 16 + nl;
    const float4* s = (const float4*)(src + (size_t)orig * 512 + bb * 8);
    float4 v0 = s[0], v1 = s[1];
    float vv[8] = {v0.x, v0.y, v0.z, v0.w, v1.x, v1.y, v1.z, v1.w};
    f16x8 hh;
    #pragma unroll
    for (int j = 0; j < 8; ++j) hh[j] = (h16)vv[j];
    int db = bb ^ (P & 7);
    *(f16x8*)(h + (size_t)P * 512 + db * 8) = hh;
}

// Wout [1024][512] -> packed rows P = by*128 + (chunk*32 + g*16 + nlow), where
// orig row = g*512 + by*64 + chunk*16 + nlow.
__global__ __launch_bounds__(256) void pack_wout(
    const float* __restrict__ src, h16* __restrict__ h)
{
    int i = blockIdx.x * 256 + threadIdx.x;     // 1024*64 = 65536
    int P = i >> 6, bb = i & 63;
    int by = P >> 7, lo = P & 127;
    int chunk = lo >> 5, g = (lo >> 4) & 1, nl = lo & 15;
    int orig = g * 512 + by * 64 + chunk * 16 + nl;
    const float4* s = (const float4*)(src + (size_t)orig * 512 + bb * 8);
    float4 v0 = s[0], v1 = s[1];
    float vv[8] = {v0.x, v0.y, v0.z, v0.w, v1.x, v1.y, v1.z, v1.w};
    f16x8 hh;
    #pragma unroll
    for (int j = 0; j < 8; ++j) hh[j] = (h16)vv[j];
    int db = bb ^ (P & 7);
    *(f16x8*)(h + (size_t)P * 512 + db * 8) = hh;
}

// ---------------------------------------------------------------------------
// GEMM1: [M1 x 512] x [512 x 2048(packed 4 groups)] + NRU combine -> ms_inp.
// 128x128 tile, BK=64, global_load_lds staging, swizzled LDS. 4 waves (2x2),
// each 64m x 64n; fragment fn = group g -> combine in-register.
// ---------------------------------------------------------------------------
__global__ __launch_bounds__(256) WAVES_EU(3, 3) void gemm_av_mfma(
    const h16* __restrict__ xh, const h16* __restrict__ Wh,
    const float* __restrict__ bav, float* __restrict__ ms_inp)
{
    __shared__ __align__(16) h16 As[128 * 64];   // 16 KB each
    __shared__ __align__(16) h16 Bh[128 * 64];

    int bx, by; xcd_remap(bx, by);
    const int tid = threadIdx.x, lane = tid & 63, w = tid >> 6;
    const int wm = (w & 1) * 64, wn = (w >> 1) * 64;
    const int bm = bx * 128;
    const int ln = lane & 15, ko = (lane >> 4) * 8;
    const int kb = ln & 7;                       // B-side swizzle key
    char* lA = (char*)As; char* lH = (char*)Bh;
    const int wb = w * 1024;

    const char *aP[4], *hP[4];
    {
        const int r8 = lane >> 3, c16 = (lane & 7) * 16;
        #pragma unroll
        for (int i = 0; i < 4; ++i) {
            int row = i * 32 + w * 8 + r8;
            int mg = bm + row; if (mg > M1 - 1) mg = M1 - 1;
            size_t xr = (size_t)mg + (unsigned)mg / (L_SZ - 1);   // skip last l per batch
            aP[i] = (const char*)xh + xr * (DM * 2) + c16;
            size_t br = (size_t)(by * 128 + row) * (DM * 2) + c16;
            hP[i] = (const char*)Wh + br;
        }
    }
    // A-side swizzle keys: key = (memory row of xh) & 7 = (m + batch) & 7
    int ka[4];
    #pragma unroll
    for (int fm = 0; fm < 4; ++fm) {
        int m = bm + wm + fm * 16 + ln;
        int mg = m > M1 - 1 ? M1 - 1 : m;
        ka[fm] = (int)((mg + (unsigned)mg / (L_SZ - 1)) & 7);
    }

    f32x4 acc[4][4];
    #pragma unroll
    for (int i = 0; i < 4; ++i)
        #pragma unroll
        for (int j = 0; j < 4; ++j) acc[i][j] = (f32x4){0.f, 0.f, 0.f, 0.f};

#define STAGE_AV(aoff, boff) do { \
    gl16(aP[0] + (aoff), lA + 0 * 4096 + wb); gl16(hP[0] + (boff), lH + 0 * 4096 + wb); \
    gl16(aP[1] + (aoff), lA + 1 * 4096 + wb); gl16(hP[1] + (boff), lH + 1 * 4096 + wb); \
    gl16(aP[2] + (aoff), lA + 2 * 4096 + wb); gl16(hP[2] + (boff), lH + 2 * 4096 + wb); \
    gl16(aP[3] + (aoff), lA + 3 * 4096 + wb); gl16(hP[3] + (boff), lH + 3 * 4096 + wb); \
} while (0)

    STAGE_AV(0, 0);
    for (int kt = 0; kt < 8; ++kt) {
        asm volatile("s_waitcnt vmcnt(0)" ::: "memory");
        __syncthreads();
        #pragma unroll
        for (int s = 0; s < 2; ++s) {
            const int c = s * 32 + ko;
            f16x8 a[4];
            #pragma unroll
            for (int fm = 0; fm < 4; ++fm)
                a[fm] = lds_frag(As, wm + fm * 16 + ln, c, ka[fm]);
            #pragma unroll
            for (int fn = 0; fn < 4; ++fn) {
                f16x8 vh = lds_frag(Bh, wn + fn * 16 + ln, c, kb);
                #pragma unroll
                for (int fm = 0; fm < 4; ++fm)
                    acc[fm][fn] = MFMA16(a[fm], vh, acc[fm][fn]);
            }
        }
        __syncthreads();
        if (kt < 7) { int off = (kt + 1) * 128; STAGE_AV(off, off); }
    }
#undef STAGE_AV

    // epilogue: fn = group; combine in-register
    const int lm = (lane >> 4) * 4;
    const int nn = by * 32 + (wn >> 6) * 16 + ln;
    const float b0 = bav[nn], b1 = bav[nn + 512], b2 = bav[nn + 1024], b3 = bav[nn + 1536];
    #pragma unroll
    for (int fm = 0; fm < 4; ++fm) {
        #pragma unroll
        for (int i = 0; i < 4; ++i) {
            int m = bm + wm + fm * 16 + lm + i;
            if (m < M1) {
                float a0 = acc[fm][0][i] + b0;
                float a1 = acc[fm][1][i] + b1;
                float a2 = acc[fm][2][i] + b2;
                float a3 = acc[fm][3][i] + b3;
                ms_inp[(size_t)m * DMEM + nn] = a0 * a1 - a2 * a3;
            }
        }
    }
}

// ---------------------------------------------------------------------------
// Chunked cumsum (fp32); pass3 emits fp16 msh in the swizzled layout.
// ---------------------------------------------------------------------------
__global__ __launch_bounds__(256) void scan_pass1(
    const float* __restrict__ ms_inp, float* __restrict__ csum)
{
    int c = blockIdx.x, b = blockIdx.y;
    int l0 = c * 128;
    int len = min(128, (L_SZ - 1) - l0);
    int t = threadIdx.x;
    const float2* p = (const float2*)(ms_inp + ((size_t)b * (L_SZ - 1) + l0) * DMEM) + t;
    float2 s = make_float2(0.f, 0.f);
    for (int i = 0; i < len; ++i) {
        float2 v = p[(size_t)i * 256];
        s.x += v.x; s.y += v.y;
    }
    ((float2*)(csum + ((size_t)b * 64 + c) * DMEM))[t] = s;
}

// Wave-parallel exclusive scan of the 64 chunk sums per (b,d):
// one 64-lane wave per (b,d); shuffle prefix scan.
__global__ __launch_bounds__(256) void scan_pass2(float* __restrict__ csum)
{
    int sid = blockIdx.x * 4 + (threadIdx.x >> 6);  // 0..2047
    int lane = threadIdx.x & 63;
    int b = sid >> 9, d = sid & 511;
    float* p = csum + (size_t)b * 64 * DMEM + d;
    float v = p[(size_t)lane * DMEM];
    #pragma unroll
    for (int off = 1; off < 64; off <<= 1) {
        float t = __shfl_up(v, off, 64);
        if (lane >= off) v += t;
    }
    float ex = __shfl_up(v, 1, 64);          // inclusive -> exclusive
    if (lane == 0) ex = 0.f;
    p[(size_t)lane * DMEM] = ex;
}

__global__ __launch_bounds__(256) void scan_pass3(
    const float* __restrict__ ms_inp, const float* __restrict__ csum,
    h16* __restrict__ msh)
{
    int c = blockIdx.x, b = blockIdx.y;
    int l0 = c * 128;
    int len = min(128, (L_SZ - 1) - l0);
    int t = threadIdx.x;
    float2 run = ((const float2*)(csum + ((size_t)b * 64 + c) * DMEM))[t];
    const float2* p = (const float2*)(ms_inp + ((size_t)b * (L_SZ - 1) + l0) * DMEM) + t;
    const int bb = t >> 2;              // 16B block index of this thread's 4B slot
    const int sub = (t & 3) * 4;        // byte within block
    if (c == 0) {                       // row l=0: m&7==0 -> identity swizzle
        f16x2 z = {(h16)0.f, (h16)0.f};
        *(f16x2*)((char*)(msh + (size_t)b * L_SZ * DMEM) + bb * 16 + sub) = z;
    }
    for (int i = 0; i < len; ++i) {
        float2 v = p[(size_t)i * 256];
        run.x += v.x; run.y += v.y;
        int m = b * L_SZ + l0 + 1 + i;
        int db = bb ^ (m & 7);
        f16x2 o = {(h16)run.x, (h16)run.y};
        *(f16x2*)((char*)(msh + (size_t)m * DMEM) + db * 16 + sub) = o;
    }
}

// ---------------------------------------------------------------------------
// GEMM2: [M2 x 1024 (x||ms)] x [1024 x 512] + GELU -> yh (fp16, swizzled).
// ---------------------------------------------------------------------------
__global__ __launch_bounds__(256) WAVES_EU(3, 3) void gemm_go_mfma(
    const h16* __restrict__ xh, const h16* __restrict__ msh,
    const h16* __restrict__ Wh,
    const float* __restrict__ bgo, h16* __restrict__ yh)
{
    __shared__ __align__(16) h16 As[128 * 64];
    __shared__ __align__(16) h16 Bh[128 * 64];

    int bx, by; xcd_remap(bx, by);
    const int tid = threadIdx.x, lane = tid & 63, w = tid >> 6;
    const int wm = (w & 1) * 64, wn = (w >> 1) * 64;
    const int bm = bx * 128, bn = by * 128;
    const int ln = lane & 15, ko = (lane >> 4) * 8;
    const int kk = ln & 7;
    char* lA = (char*)As; char* lH = (char*)Bh;
    const int wb = w * 1024;

    const char *xP[4], *mP[4], *hP[4];
    {
        const int r8 = lane >> 3, c16 = (lane & 7) * 16;
        #pragma unroll
        for (int i = 0; i < 4; ++i) {
            int row = i * 32 + w * 8 + r8;
            size_t ar = (size_t)(bm + row) * (DM * 2) + c16;
            xP[i] = (const char*)xh + ar;
            mP[i] = (const char*)msh + ar;
            size_t br = (size_t)(bn + row) * (2 * DM * 2) + c16;   // 1024-col rows
            hP[i] = (const char*)Wh + br;
        }
    }

    f32x4 acc[4][4];
    #pragma unroll
    for (int i = 0; i < 4; ++i)
        #pragma unroll
        for (int j = 0; j < 4; ++j) acc[i][j] = (f32x4){0.f, 0.f, 0.f, 0.f};

#define STAGE_GO(AP, aoff, boff) do { \
    gl16(AP[0] + (aoff), lA + 0 * 4096 + wb); gl16(hP[0] + (boff), lH + 0 * 4096 + wb); \
    gl16(AP[1] + (aoff), lA + 1 * 4096 + wb); gl16(hP[1] + (boff), lH + 1 * 4096 + wb); \
    gl16(AP[2] + (aoff), lA + 2 * 4096 + wb); gl16(hP[2] + (boff), lH + 2 * 4096 + wb); \
    gl16(AP[3] + (aoff), lA + 3 * 4096 + wb); gl16(hP[3] + (boff), lH + 3 * 4096 + wb); \
} while (0)

    STAGE_GO(xP, 0, 0);
    for (int kt = 0; kt < 16; ++kt) {
        asm volatile("s_waitcnt vmcnt(0)" ::: "memory");
        __syncthreads();
        #pragma unroll
        for (int s = 0; s < 2; ++s) {
            const int c = s * 32 + ko;
            f16x8 a[4];
            #pragma unroll
            for (int fm = 0; fm < 4; ++fm)
                a[fm] = lds_frag(As, wm + fm * 16 + ln, c, kk);
            #pragma unroll
            for (int fn = 0; fn < 4; ++fn) {
                f16x8 vh = lds_frag(Bh, wn + fn * 16 + ln, c, kk);
                #pragma unroll
                for (int fm = 0; fm < 4; ++fm)
                    acc[fm][fn] = MFMA16(a[fm], vh, acc[fm][fn]);
            }
        }
        __syncthreads();
        int nx = kt + 1;
        if (nx < 8)       { STAGE_GO(xP, nx * 128, nx * 128); }
        else if (nx < 16) { STAGE_GO(mP, (nx - 8) * 128, nx * 128); }
    }
#undef STAGE_GO

    // epilogue: GELU -> yh, swizzled write
    const int lm = (lane >> 4) * 4;
    #pragma unroll
    for (int fm = 0; fm < 4; ++fm) {
        #pragma unroll
        for (int fn = 0; fn < 4; ++fn) {
            int n = bn + wn + fn * 16 + ln;
            float bias = bgo[n];
            #pragma unroll
            for (int i = 0; i < 4; ++i) {
                int m = bm + wm + fm * 16 + lm + i;
                float t = acc[fm][fn][i] + bias;
                float g = 0.5f * t * (1.0f + erff(t * 0.70710678118654752f));
                int nsw = (((n >> 3) ^ (m & 7)) << 3) | (n & 7);
                yh[(size_t)m * DM + nsw] = (h16)g;
            }
        }
    }
}

// ---------------------------------------------------------------------------
// GEMM3: [M2 x 512] x [512 x 1024(packed 2 groups)] + GLU -> out (fp32).
// fn parity = GLU half; combine in-register.
// ---------------------------------------------------------------------------
__global__ __launch_bounds__(256) WAVES_EU(3, 3) void gemm_out_mfma(
    const h16* __restrict__ yh, const h16* __restrict__ Wh,
    const float* __restrict__ bout, float* __restrict__ out)
{
    __shared__ __align__(16) h16 As[128 * 64];
    __shared__ __align__(16) h16 Bh[128 * 64];

    int bx, by; xcd_remap(bx, by);
    const int tid = threadIdx.x, lane = tid & 63, w = tid >> 6;
    const int wm = (w & 1) * 64, wn = (w >> 1) * 64;
    const int bm = bx * 128;
    const int ln = lane & 15, ko = (lane >> 4) * 8;
    const int kk = ln & 7;
    char* lA = (char*)As; char* lH = (char*)Bh;
    const int wb = w * 1024;

    const char *aP[4], *hP[4];
    {
        const int r8 = lane >> 3, c16 = (lane & 7) * 16;
        #pragma unroll
        for (int i = 0; i < 4; ++i) {
            int row = i * 32 + w * 8 + r8;
            aP[i] = (const char*)yh + (size_t)(bm + row) * (DM * 2) + c16;
            size_t br = (size_t)(by * 128 + row) * (DM * 2) + c16;
            hP[i] = (const char*)Wh + br;
        }
    }

    f32x4 acc[4][4];
    #pragma unroll
    for (int i = 0; i < 4; ++i)
        #pragma unroll
        for (int j = 0; j < 4; ++j) acc[i][j] = (f32x4){0.f, 0.f, 0.f, 0.f};

#define STAGE_OUT(aoff, boff) do { \
    gl16(aP[0] + (aoff), lA + 0 * 4096 + wb); gl16(hP[0] + (boff), lH + 0 * 4096 + wb); \
    gl16(aP[1] + (aoff), lA + 1 * 4096 + wb); gl16(hP[1] + (boff), lH + 1 * 4096 + wb); \
    gl16(aP[2] + (aoff), lA + 2 * 4096 + wb); gl16(hP[2] + (boff), lH + 2 * 4096 + wb); \
    gl16(aP[3] + (aoff), lA + 3 * 4096 + wb); gl16(hP[3] + (boff), lH + 3 * 4096 + wb); \
} while (0)

    STAGE_OUT(0, 0);
    for (int kt = 0; kt < 8; ++kt) {
        asm volatile("s_waitcnt vmcnt(0)" ::: "memory");
        __syncthreads();
        #pragma unroll
        for (int s = 0; s < 2; ++s) {
            const int c = s * 32 + ko;
            f16x8 a[4];
            #pragma unroll
            for (int fm = 0; fm < 4; ++fm)
                a[fm] = lds_frag(As, wm + fm * 16 + ln, c, kk);
            #pragma unroll
            for (int fn = 0; fn < 4; ++fn) {
                f16x8 vh = lds_frag(Bh, wn + fn * 16 + ln, c, kk);
                #pragma unroll
                for (int fm = 0; fm < 4; ++fm)
                    acc[fm][fn] = MFMA16(a[fm], vh, acc[fm][fn]);
            }
        }
        __syncthreads();
        if (kt < 7) { int off = (kt + 1) * 128; STAGE_OUT(off, off); }
    }
#undef STAGE_OUT

    // epilogue: GLU (fn pairs: even = z0-half, odd = z1-half)
    const int lm = (lane >> 4) * 4;
    #pragma unroll
    for (int fm = 0; fm < 4; ++fm) {
        #pragma unroll
        for (int cp = 0; cp < 2; ++cp) {
            int ncol = by * 64 + ((wn >> 5) + cp) * 16 + ln;
            float bz0 = bout[ncol], bz1 = bout[ncol + 512];
            #pragma unroll
            for (int i = 0; i < 4; ++i) {
                int m = bm + wm + fm * 16 + lm + i;
                float z0 = acc[fm][cp * 2 + 0][i] + bz0;
                float z1 = acc[fm][cp * 2 + 1][i] + bz1;
                out[(size_t)m * DM + ncol] = z0 * (1.0f / (1.0f + expf(-z1)));
            }
        }
    }
}

// ---------------------------------------------------------------------------
extern "C" void kernel_launch(void* const* d_in, const int* in_sizes, int n_in,
                              void* d_out, int out_size, void* d_ws, size_t ws_size,
                              hipStream_t stream)
{
    const float* x    = (const float*)d_in[0];
    const float* Wav  = (const float*)d_in[1];
    const float* bav  = (const float*)d_in[2];
    const float* Wgo  = (const float*)d_in[3];
    const float* bgo  = (const float*)d_in[4];
    const float* Wout = (const float*)d_in[5];
    const float* bout = (const float*)d_in[6];
    float* out = (float*)d_out;

    char* ws = (char*)d_ws;
    const size_t MB = 1 << 20;
    float* ms_inp = (float*)ws;                   // 64 MiB [32764,512] f32
    h16*   yh     = (h16*)ws;                     // aliases ms_inp (after scan)
    h16*   xh     = (h16*)(ws + 64 * MB);         // 32 MiB (swizzled fp16)
    h16*   msh    = (h16*)(ws + 96 * MB);         // 32 MiB (swizzled fp16)
    float* csum   = (float*)(ws + 128 * MB);      // 0.5 MiB
    h16*   Wavh   = (h16*)(ws + 129 * MB);        // 2 MiB (packed+swizzled)
    h16*   Wgoh   = (h16*)(ws + 131 * MB);        // 1 MiB
    h16*   Wouth  = (h16*)(ws + 132 * MB);        // 1 MiB

    // 0) precompute fp16 forms (swizzled / packed)
    conv_x   <<<8192, 256, 0, stream>>>(x, xh);
    conv_wgo <<<256,  256, 0, stream>>>(Wgo, Wgoh);
    pack_wav <<<512,  256, 0, stream>>>(Wav, Wavh);
    pack_wout<<<256,  256, 0, stream>>>(Wout, Wouth);
    // 1) av GEMM + NRU combine -> ms_inp (f32)
    gemm_av_mfma<<<dim3(256, 16), 256, 0, stream>>>(xh, Wavh, bav, ms_inp);
    // 2-4) chunked cumsum -> msh (fp16, swizzled)
    scan_pass1<<<dim3(64, B_SZ), 256, 0, stream>>>(ms_inp, csum);
    scan_pass2<<<512, 256, 0, stream>>>(csum);
    scan_pass3<<<dim3(64, B_SZ), 256, 0, stream>>>(ms_inp, csum, msh);
    // 5) SSM-in GEMM + GELU -> yh (fp16 swizzled, reuses ms_inp region)
    gemm_go_mfma<<<dim3(256, 4), 256, 0, stream>>>(xh, msh, Wgoh, bgo, yh);
    // 6) output GEMM + GLU -> out (f32)
    gemm_out_mfma<<<dim3(256, 8), 256, 0, stream>>>(yh, Wouth, bout, out);
}

// Round 10
// 277.175 us; speedup vs baseline: 3.4553x; 1.0390x over previous
//
#include <hip/hip_runtime.h>
#include <hip/hip_bf16.h>
#include <math.h>

// Problem constants
#define B_SZ 4
#define L_SZ 8192
#define DM 512           // D_MODEL
#define DMEM 512         // D_MEM
#define M1 (B_SZ * (L_SZ - 1))   // 32764 rows for the av GEMM
#define M2 (B_SZ * L_SZ)         // 32768 rows for GEMM2/3

typedef _Float16 h16;
typedef __attribute__((ext_vector_type(2))) _Float16 f16x2;
typedef __attribute__((ext_vector_type(8))) _Float16 f16x8;
typedef __attribute__((ext_vector_type(4))) float f32x4;

#define MFMA16(a, b, c) __builtin_amdgcn_mfma_f32_16x16x32_f16((a), (b), (c), 0, 0, 0)
#define WAVES_EU(mn, mx) __attribute__((amdgpu_waves_per_eu(mn, mx)))

// async global->LDS, 16B per lane: LDS dst = wave-uniform base + lane*16,
// global src = per-lane address.
__device__ __forceinline__ void gl16(const void* g, void* l) {
    __builtin_amdgcn_global_load_lds(
        (const __attribute__((address_space(1))) void*)g,
        (__attribute__((address_space(3))) void*)l, 16, 0, 0);
}

// Swizzled LDS fragment read from a [128 rows][64 cols] fp16 tile (128 B rows).
__device__ __forceinline__ f16x8 lds_frag(const h16* base, int row, int col, int key) {
    return *(const f16x8*)((const char*)base + row * 128 + ((col * 2) ^ (key << 4)));
}

// XCD swizzle, A-reuse-friendly decode (by fast -> weight panel L2-resident,
// A-tile reused by consecutive blocks on the same XCD).
__device__ __forceinline__ void xcd_remap(int& bx, int& by) {
    int gx = gridDim.x, gy = gridDim.y;
    int nwg = gx * gy;
    int lin = blockIdx.y * gx + blockIdx.x;
    int chunk = nwg >> 3;
    int l = (lin & 7) * chunk + (lin >> 3);
    by = l % gy;
    bx = l / gy;
}

// ---------------------------------------------------------------------------
// Precompute: x (fp32) -> xh (fp16, row-swizzled). One thread per 8 elems.
// ---------------------------------------------------------------------------
__global__ __launch_bounds__(256) void conv_x(
    const float* __restrict__ src, h16* __restrict__ dst)
{
    int i = blockIdx.x * 256 + threadIdx.x;     // 2097152 threads
    int m = i >> 6, bb = i & 63;
    const float4* s = (const float4*)(src + (size_t)m * 512 + bb * 8);
    float4 v0 = s[0], v1 = s[1];
    float vv[8] = {v0.x, v0.y, v0.z, v0.w, v1.x, v1.y, v1.z, v1.w};
    f16x8 o;
    #pragma unroll
    for (int j = 0; j < 8; ++j) o[j] = (h16)vv[j];
    int db = bb ^ (m & 7);
    *(f16x8*)(dst + (size_t)m * 512 + db * 8) = o;
}

// ---------------------------------------------------------------------------
// Merged weight prep: Wgo conv + Wav pack + Wout pack (one launch).
//   i in [0, 65536):        Wgo [512][1024] row-swizzle
//   i in [65536, 196608):   Wav pack P = by*128 + (half*64 + g*16 + nl)
//   i in [196608, 262144):  Wout pack P = by*128 + (chunk*32 + g*16 + nl)
// ---------------------------------------------------------------------------
__global__ __launch_bounds__(256) void pack_weights(
    const float* __restrict__ Wgo, const float* __restrict__ Wav,
    const float* __restrict__ Wout, h16* __restrict__ Wgoh,
    h16* __restrict__ Wavh, h16* __restrict__ Wouth)
{
    int i = blockIdx.x * 256 + threadIdx.x;
    const float* s;
    h16* d;
    if (i < 65536) {                 // Wgo: row r, 128 blocks of 8
        int r = i >> 7, bb = i & 127;
        s = Wgo + (size_t)r * 1024 + bb * 8;
        d = Wgoh + (size_t)r * 1024 + (bb ^ (r & 7)) * 8;
    } else if (i < 196608) {         // Wav
        int j = i - 65536;
        int P = j >> 6, bb = j & 63;
        int by = P >> 7, lo = P & 127;
        int half = lo >> 6, g = (lo >> 4) & 3, nl = lo & 15;
        int orig = g * 512 + by * 32 + half * 16 + nl;
        s = Wav + (size_t)orig * 512 + bb * 8;
        d = Wavh + (size_t)P * 512 + (bb ^ (P & 7)) * 8;
    } else {                         // Wout
        int j = i - 196608;
        int P = j >> 6, bb = j & 63;
        int by = P >> 7, lo = P & 127;
        int chunk = lo >> 5, g = (lo >> 4) & 1, nl = lo & 15;
        int orig = g * 512 + by * 64 + chunk * 16 + nl;
        s = Wout + (size_t)orig * 512 + bb * 8;
        d = Wouth + (size_t)P * 512 + (bb ^ (P & 7)) * 8;
    }
    const float4* sv = (const float4*)s;
    float4 v0 = sv[0], v1 = sv[1];
    float vv[8] = {v0.x, v0.y, v0.z, v0.w, v1.x, v1.y, v1.z, v1.w};
    f16x8 hh;
    #pragma unroll
    for (int j = 0; j < 8; ++j) hh[j] = (h16)vv[j];
    *(f16x8*)d = hh;
}

// Pipeline sync helpers (raw barrier: __syncthreads would drain vmcnt(0) and
// kill the in-flight prefetch).
#define PIPE_WAIT(N) do { \
    asm volatile("s_waitcnt vmcnt(" #N ")" ::: "memory"); \
    __builtin_amdgcn_s_barrier(); \
    asm volatile("" ::: "memory"); \
} while (0)
#define PIPE_POST() do { \
    __builtin_amdgcn_s_barrier(); \
    asm volatile("" ::: "memory"); \
} while (0)

// ---------------------------------------------------------------------------
// GEMM1: [M1 x 512] x [512 x 2048(packed 4 groups)] + NRU combine -> ms_inp.
// 128x128 tile, BK=64, double-buffered issue-early global_load_lds pipeline.
// ---------------------------------------------------------------------------
__global__ __launch_bounds__(256) WAVES_EU(2, 2) void gemm_av_mfma(
    const h16* __restrict__ xh, const h16* __restrict__ Wh,
    const float* __restrict__ bav, float* __restrict__ ms_inp)
{
    __shared__ __align__(16) h16 As[2][128 * 64];   // 16 KB each buf
    __shared__ __align__(16) h16 Bh[2][128 * 64];

    int bx, by; xcd_remap(bx, by);
    const int tid = threadIdx.x, lane = tid & 63, w = tid >> 6;
    const int wm = (w & 1) * 64, wn = (w >> 1) * 64;
    const int bm = bx * 128;
    const int ln = lane & 15, ko = (lane >> 4) * 8;
    const int kb = ln & 7;
    const int wb = w * 1024;

    const char *aP[4], *hP[4];
    {
        const int r8 = lane >> 3, c16 = (lane & 7) * 16;
        #pragma unroll
        for (int i = 0; i < 4; ++i) {
            int row = i * 32 + w * 8 + r8;
            int mg = bm + row; if (mg > M1 - 1) mg = M1 - 1;
            size_t xr = (size_t)mg + (unsigned)mg / (L_SZ - 1);
            aP[i] = (const char*)xh + xr * (DM * 2) + c16;
            size_t br = (size_t)(by * 128 + row) * (DM * 2) + c16;
            hP[i] = (const char*)Wh + br;
        }
    }
    int ka[4];
    #pragma unroll
    for (int fm = 0; fm < 4; ++fm) {
        int m = bm + wm + fm * 16 + ln;
        int mg = m > M1 - 1 ? M1 - 1 : m;
        ka[fm] = (int)((mg + (unsigned)mg / (L_SZ - 1)) & 7);
    }

    f32x4 acc[4][4];
    #pragma unroll
    for (int i = 0; i < 4; ++i)
        #pragma unroll
        for (int j = 0; j < 4; ++j) acc[i][j] = (f32x4){0.f, 0.f, 0.f, 0.f};

#define STAGE_AV(koff, sel) do { \
    char* dA = (char*)As[sel]; char* dB = (char*)Bh[sel]; \
    gl16(aP[0] + (koff), dA + 0 * 4096 + wb); gl16(hP[0] + (koff), dB + 0 * 4096 + wb); \
    gl16(aP[1] + (koff), dA + 1 * 4096 + wb); gl16(hP[1] + (koff), dB + 1 * 4096 + wb); \
    gl16(aP[2] + (koff), dA + 2 * 4096 + wb); gl16(hP[2] + (koff), dB + 2 * 4096 + wb); \
    gl16(aP[3] + (koff), dA + 3 * 4096 + wb); gl16(hP[3] + (koff), dB + 3 * 4096 + wb); \
} while (0)

    STAGE_AV(0, 0);
    STAGE_AV(128, 1);
    for (int kt = 0; kt < 8; ++kt) {
        if (kt < 7) PIPE_WAIT(8); else PIPE_WAIT(0);
        const h16* A = As[kt & 1];
        const h16* B = Bh[kt & 1];
        #pragma unroll
        for (int s = 0; s < 2; ++s) {
            const int c = s * 32 + ko;
            f16x8 a[4];
            #pragma unroll
            for (int fm = 0; fm < 4; ++fm)
                a[fm] = lds_frag(A, wm + fm * 16 + ln, c, ka[fm]);
            #pragma unroll
            for (int fn = 0; fn < 4; ++fn) {
                f16x8 vh = lds_frag(B, wn + fn * 16 + ln, c, kb);
                #pragma unroll
                for (int fm = 0; fm < 4; ++fm)
                    acc[fm][fn] = MFMA16(a[fm], vh, acc[fm][fn]);
            }
        }
        PIPE_POST();
        if (kt + 2 < 8) STAGE_AV((kt + 2) * 128, kt & 1);
    }
#undef STAGE_AV

    const int lm = (lane >> 4) * 4;
    const int nn = by * 32 + (wn >> 6) * 16 + ln;
    const float b0 = bav[nn], b1 = bav[nn + 512], b2 = bav[nn + 1024], b3 = bav[nn + 1536];
    #pragma unroll
    for (int fm = 0; fm < 4; ++fm) {
        #pragma unroll
        for (int i = 0; i < 4; ++i) {
            int m = bm + wm + fm * 16 + lm + i;
            if (m < M1) {
                float a0 = acc[fm][0][i] + b0;
                float a1 = acc[fm][1][i] + b1;
                float a2 = acc[fm][2][i] + b2;
                float a3 = acc[fm][3][i] + b3;
                ms_inp[(size_t)m * DMEM + nn] = a0 * a1 - a2 * a3;
            }
        }
    }
}

// ---------------------------------------------------------------------------
// Chunked cumsum (fp32); pass3 emits fp16 msh in the swizzled layout.
// ---------------------------------------------------------------------------
__global__ __launch_bounds__(256) void scan_pass1(
    const float* __restrict__ ms_inp, float* __restrict__ csum)
{
    int c = blockIdx.x, b = blockIdx.y;
    int l0 = c * 128;
    int len = min(128, (L_SZ - 1) - l0);
    int t = threadIdx.x;
    const float2* p = (const float2*)(ms_inp + ((size_t)b * (L_SZ - 1) + l0) * DMEM) + t;
    float2 s = make_float2(0.f, 0.f);
    for (int i = 0; i < len; ++i) {
        float2 v = p[(size_t)i * 256];
        s.x += v.x; s.y += v.y;
    }
    ((float2*)(csum + ((size_t)b * 64 + c) * DMEM))[t] = s;
}

// Wave-parallel exclusive scan of the 64 chunk sums per (b,d).
__global__ __launch_bounds__(256) void scan_pass2(float* __restrict__ csum)
{
    int sid = blockIdx.x * 4 + (threadIdx.x >> 6);
    int lane = threadIdx.x & 63;
    int b = sid >> 9, d = sid & 511;
    float* p = csum + (size_t)b * 64 * DMEM + d;
    float v = p[(size_t)lane * DMEM];
    #pragma unroll
    for (int off = 1; off < 64; off <<= 1) {
        float t = __shfl_up(v, off, 64);
        if (lane >= off) v += t;
    }
    float ex = __shfl_up(v, 1, 64);
    if (lane == 0) ex = 0.f;
    p[(size_t)lane * DMEM] = ex;
}

__global__ __launch_bounds__(256) void scan_pass3(
    const float* __restrict__ ms_inp, const float* __restrict__ csum,
    h16* __restrict__ msh)
{
    int c = blockIdx.x, b = blockIdx.y;
    int l0 = c * 128;
    int len = min(128, (L_SZ - 1) - l0);
    int t = threadIdx.x;
    float2 run = ((const float2*)(csum + ((size_t)b * 64 + c) * DMEM))[t];
    const float2* p = (const float2*)(ms_inp + ((size_t)b * (L_SZ - 1) + l0) * DMEM) + t;
    const int bb = t >> 2;
    const int sub = (t & 3) * 4;
    if (c == 0) {
        f16x2 z = {(h16)0.f, (h16)0.f};
        *(f16x2*)((char*)(msh + (size_t)b * L_SZ * DMEM) + bb * 16 + sub) = z;
    }
    for (int i = 0; i < len; ++i) {
        float2 v = p[(size_t)i * 256];
        run.x += v.x; run.y += v.y;
        int m = b * L_SZ + l0 + 1 + i;
        int db = bb ^ (m & 7);
        f16x2 o = {(h16)run.x, (h16)run.y};
        *(f16x2*)((char*)(msh + (size_t)m * DMEM) + db * 16 + sub) = o;
    }
}

// ---------------------------------------------------------------------------
// GEMM2: [M2 x 1024 (x||ms)] x [1024 x 512] + GELU -> yh (fp16, swizzled).
// ---------------------------------------------------------------------------
__global__ __launch_bounds__(256) WAVES_EU(2, 2) void gemm_go_mfma(
    const h16* __restrict__ xh, const h16* __restrict__ msh,
    const h16* __restrict__ Wh,
    const float* __restrict__ bgo, h16* __restrict__ yh)
{
    __shared__ __align__(16) h16 As[2][128 * 64];
    __shared__ __align__(16) h16 Bh[2][128 * 64];

    int bx, by; xcd_remap(bx, by);
    const int tid = threadIdx.x, lane = tid & 63, w = tid >> 6;
    const int wm = (w & 1) * 64, wn = (w >> 1) * 64;
    const int bm = bx * 128, bn = by * 128;
    const int ln = lane & 15, ko = (lane >> 4) * 8;
    const int kk = ln & 7;
    const int wb = w * 1024;

    const char *xP[4], *mP[4], *hP[4];
    {
        const int r8 = lane >> 3, c16 = (lane & 7) * 16;
        #pragma unroll
        for (int i = 0; i < 4; ++i) {
            int row = i * 32 + w * 8 + r8;
            size_t ar = (size_t)(bm + row) * (DM * 2) + c16;
            xP[i] = (const char*)xh + ar;
            mP[i] = (const char*)msh + ar;
            size_t br = (size_t)(bn + row) * (2 * DM * 2) + c16;
            hP[i] = (const char*)Wh + br;
        }
    }

    f32x4 acc[4][4];
    #pragma unroll
    for (int i = 0; i < 4; ++i)
        #pragma unroll
        for (int j = 0; j < 4; ++j) acc[i][j] = (f32x4){0.f, 0.f, 0.f, 0.f};

#define STAGE_GO(tt, sel) do { \
    char* dA = (char*)As[sel]; char* dB = (char*)Bh[sel]; \
    const int bo = (tt) * 128; \
    if ((tt) < 8) { \
        const int ao = (tt) * 128; \
        gl16(xP[0] + ao, dA + 0 * 4096 + wb); gl16(hP[0] + bo, dB + 0 * 4096 + wb); \
        gl16(xP[1] + ao, dA + 1 * 4096 + wb); gl16(hP[1] + bo, dB + 1 * 4096 + wb); \
        gl16(xP[2] + ao, dA + 2 * 4096 + wb); gl16(hP[2] + bo, dB + 2 * 4096 + wb); \
        gl16(xP[3] + ao, dA + 3 * 4096 + wb); gl16(hP[3] + bo, dB + 3 * 4096 + wb); \
    } else { \
        const int ao = ((tt) - 8) * 128; \
        gl16(mP[0] + ao, dA + 0 * 4096 + wb); gl16(hP[0] + bo, dB + 0 * 4096 + wb); \
        gl16(mP[1] + ao, dA + 1 * 4096 + wb); gl16(hP[1] + bo, dB + 1 * 4096 + wb); \
        gl16(mP[2] + ao, dA + 2 * 4096 + wb); gl16(hP[2] + bo, dB + 2 * 4096 + wb); \
        gl16(mP[3] + ao, dA + 3 * 4096 + wb); gl16(hP[3] + bo, dB + 3 * 4096 + wb); \
    } \
} while (0)

    STAGE_GO(0, 0);
    STAGE_GO(1, 1);
    for (int kt = 0; kt < 16; ++kt) {
        if (kt < 15) PIPE_WAIT(8); else PIPE_WAIT(0);
        const h16* A = As[kt & 1];
        const h16* B = Bh[kt & 1];
        #pragma unroll
        for (int s = 0; s < 2; ++s) {
            const int c = s * 32 + ko;
            f16x8 a[4];
            #pragma unroll
            for (int fm = 0; fm < 4; ++fm)
                a[fm] = lds_frag(A, wm + fm * 16 + ln, c, kk);
            #pragma unroll
            for (int fn = 0; fn < 4; ++fn) {
                f16x8 vh = lds_frag(B, wn + fn * 16 + ln, c, kk);
                #pragma unroll
                for (int fm = 0; fm < 4; ++fm)
                    acc[fm][fn] = MFMA16(a[fm], vh, acc[fm][fn]);
            }
        }
        PIPE_POST();
        if (kt + 2 < 16) STAGE_GO(kt + 2, kt & 1);
    }
#undef STAGE_GO

    const int lm = (lane >> 4) * 4;
    #pragma unroll
    for (int fm = 0; fm < 4; ++fm) {
        #pragma unroll
        for (int fn = 0; fn < 4; ++fn) {
            int n = bn + wn + fn * 16 + ln;
            float bias = bgo[n];
            #pragma unroll
            for (int i = 0; i < 4; ++i) {
                int m = bm + wm + fm * 16 + lm + i;
                float t = acc[fm][fn][i] + bias;
                float g = 0.5f * t * (1.0f + erff(t * 0.70710678118654752f));
                int nsw = (((n >> 3) ^ (m & 7)) << 3) | (n & 7);
                yh[(size_t)m * DM + nsw] = (h16)g;
            }
        }
    }
}

// ---------------------------------------------------------------------------
// GEMM3: [M2 x 512] x [512 x 1024(packed 2 groups)] + GLU -> out (fp32).
// ---------------------------------------------------------------------------
__global__ __launch_bounds__(256) WAVES_EU(2, 2) void gemm_out_mfma(
    const h16* __restrict__ yh, const h16* __restrict__ Wh,
    const float* __restrict__ bout, float* __restrict__ out)
{
    __shared__ __align__(16) h16 As[2][128 * 64];
    __shared__ __align__(16) h16 Bh[2][128 * 64];

    int bx, by; xcd_remap(bx, by);
    const int tid = threadIdx.x, lane = tid & 63, w = tid >> 6;
    const int wm = (w & 1) * 64, wn = (w >> 1) * 64;
    const int bm = bx * 128;
    const int ln = lane & 15, ko = (lane >> 4) * 8;
    const int kk = ln & 7;
    const int wb = w * 1024;

    const char *aP[4], *hP[4];
    {
        const int r8 = lane >> 3, c16 = (lane & 7) * 16;
        #pragma unroll
        for (int i = 0; i < 4; ++i) {
            int row = i * 32 + w * 8 + r8;
            aP[i] = (const char*)yh + (size_t)(bm + row) * (DM * 2) + c16;
            size_t br = (size_t)(by * 128 + row) * (DM * 2) + c16;
            hP[i] = (const char*)Wh + br;
        }
    }

    f32x4 acc[4][4];
    #pragma unroll
    for (int i = 0; i < 4; ++i)
        #pragma unroll
        for (int j = 0; j < 4; ++j) acc[i][j] = (f32x4){0.f, 0.f, 0.f, 0.f};

#define STAGE_OUT(koff, sel) do { \
    char* dA = (char*)As[sel]; char* dB = (char*)Bh[sel]; \
    gl16(aP[0] + (koff), dA + 0 * 4096 + wb); gl16(hP[0] + (koff), dB + 0 * 4096 + wb); \
    gl16(aP[1] + (koff), dA + 1 * 4096 + wb); gl16(hP[1] + (koff), dB + 1 * 4096 + wb); \
    gl16(aP[2] + (koff), dA + 2 * 4096 + wb); gl16(hP[2] + (koff), dB + 2 * 4096 + wb); \
    gl16(aP[3] + (koff), dA + 3 * 4096 + wb); gl16(hP[3] + (koff), dB + 3 * 4096 + wb); \
} while (0)

    STAGE_OUT(0, 0);
    STAGE_OUT(128, 1);
    for (int kt = 0; kt < 8; ++kt) {
        if (kt < 7) PIPE_WAIT(8); else PIPE_WAIT(0);
        const h16* A = As[kt & 1];
        const h16* B = Bh[kt & 1];
        #pragma unroll
        for (int s = 0; s < 2; ++s) {
            const int c = s * 32 + ko;
            f16x8 a[4];
            #pragma unroll
            for (int fm = 0; fm < 4; ++fm)
                a[fm] = lds_frag(A, wm + fm * 16 + ln, c, kk);
            #pragma unroll
            for (int fn = 0; fn < 4; ++fn) {
                f16x8 vh = lds_frag(B, wn + fn * 16 + ln, c, kk);
                #pragma unroll
                for (int fm = 0; fm < 4; ++fm)
                    acc[fm][fn] = MFMA16(a[fm], vh, acc[fm][fn]);
            }
        }
        PIPE_POST();
        if (kt + 2 < 8) STAGE_OUT((kt + 2) * 128, kt & 1);
    }
#undef STAGE_OUT

    const int lm = (lane >> 4) * 4;
    #pragma unroll
    for (int fm = 0; fm < 4; ++fm) {
        #pragma unroll
        for (int cp = 0; cp < 2; ++cp) {
            int ncol = by * 64 + ((wn >> 5) + cp) * 16 + ln;
            float bz0 = bout[ncol], bz1 = bout[ncol + 512];
            #pragma unroll
            for (int i = 0; i < 4; ++i) {
                int m = bm + wm + fm * 16 + lm + i;
                float z0 = acc[fm][cp * 2 + 0][i] + bz0;
                float z1 = acc[fm][cp * 2 + 1][i] + bz1;
                out[(size_t)m * DM + ncol] = z0 * (1.0f / (1.0f + expf(-z1)));
            }
        }
    }
}

// ---------------------------------------------------------------------------
extern "C" void kernel_launch(void* const* d_in, const int* in_sizes, int n_in,
                              void* d_out, int out_size, void* d_ws, size_t ws_size,
                              hipStream_t stream)
{
    const float* x    = (const float*)d_in[0];
    const float* Wav  = (const float*)d_in[1];
    const float* bav  = (const float*)d_in[2];
    const float* Wgo  = (const float*)d_in[3];
    const float* bgo  = (const float*)d_in[4];
    const float* Wout = (const float*)d_in[5];
    const float* bout = (const float*)d_in[6];
    float* out = (float*)d_out;

    char* ws = (char*)d_ws;
    const size_t MB = 1 << 20;
    float* ms_inp = (float*)ws;                   // 64 MiB [32764,512] f32
    h16*   yh     = (h16*)ws;                     // aliases ms_inp (after scan)
    h16*   xh     = (h16*)(ws + 64 * MB);         // 32 MiB (swizzled fp16)
    h16*   msh    = (h16*)(ws + 96 * MB);         // 32 MiB (swizzled fp16)
    float* csum   = (float*)(ws + 128 * MB);      // 0.5 MiB
    h16*   Wavh   = (h16*)(ws + 129 * MB);        // 2 MiB (packed+swizzled)
    h16*   Wgoh   = (h16*)(ws + 131 * MB);        // 1 MiB
    h16*   Wouth  = (h16*)(ws + 132 * MB);        // 1 MiB

    // 0) precompute fp16 forms (swizzled / packed)
    conv_x      <<<8192, 256, 0, stream>>>(x, xh);
    pack_weights<<<1024, 256, 0, stream>>>(Wgo, Wav, Wout, Wgoh, Wavh, Wouth);
    // 1) av GEMM + NRU combine -> ms_inp (f32)
    gemm_av_mfma<<<dim3(256, 16), 256, 0, stream>>>(xh, Wavh, bav, ms_inp);
    // 2-4) chunked cumsum -> msh (fp16, swizzled)
    scan_pass1<<<dim3(64, B_SZ), 256, 0, stream>>>(ms_inp, csum);
    scan_pass2<<<512, 256, 0, stream>>>(csum);
    scan_pass3<<<dim3(64, B_SZ), 256, 0, stream>>>(ms_inp, csum, msh);
    // 5) SSM-in GEMM + GELU -> yh (fp16 swizzled, reuses ms_inp region)
    gemm_go_mfma<<<dim3(256, 4), 256, 0, stream>>>(xh, msh, Wgoh, bgo, yh);
    // 6) output GEMM + GLU -> out (f32)
    gemm_out_mfma<<<dim3(256, 8), 256, 0, stream>>>(yh, Wouth, bout, out);
}

// Round 11
// 275.793 us; speedup vs baseline: 3.4727x; 1.0050x over previous
//
#include <hip/hip_runtime.h>
#include <hip/hip_bf16.h>
#include <math.h>

// Problem constants
#define B_SZ 4
#define L_SZ 8192
#define DM 512           // D_MODEL
#define DMEM 512         // D_MEM
#define M1 (B_SZ * (L_SZ - 1))   // 32764 rows for the av GEMM
#define M2 (B_SZ * L_SZ)         // 32768 rows for GEMM2/3

typedef _Float16 h16;
typedef __attribute__((ext_vector_type(2))) _Float16 f16x2;
typedef __attribute__((ext_vector_type(8))) _Float16 f16x8;
typedef __attribute__((ext_vector_type(4))) float f32x4;

#define MFMA16(a, b, c) __builtin_amdgcn_mfma_f32_16x16x32_f16((a), (b), (c), 0, 0, 0)
#define WAVES_EU(mn, mx) __attribute__((amdgpu_waves_per_eu(mn, mx)))

// async global->LDS, 16B per lane
__device__ __forceinline__ void gl16(const void* g, void* l) {
    __builtin_amdgcn_global_load_lds(
        (const __attribute__((address_space(1))) void*)g,
        (__attribute__((address_space(3))) void*)l, 16, 0, 0);
}

// Swizzled LDS fragment read from a [128 rows][64 cols] fp16 tile (128 B rows).
__device__ __forceinline__ f16x8 lds_frag(const h16* base, int row, int col, int key) {
    return *(const f16x8*)((const char*)base + row * 128 + ((col * 2) ^ (key << 4)));
}

// XCD swizzle, A-reuse-friendly decode (by fast -> weight panel L2-resident).
__device__ __forceinline__ void xcd_remap(int& bx, int& by) {
    int gx = gridDim.x, gy = gridDim.y;
    int nwg = gx * gy;
    int lin = blockIdx.y * gx + blockIdx.x;
    int chunk = nwg >> 3;
    int l = (lin & 7) * chunk + (lin >> 3);
    by = l % gy;
    bx = l / gy;
}

// ---------------------------------------------------------------------------
// Merged precompute: x conv + all weight packs in ONE launch.
//   i in [0, 2097152):            x [32768][512] -> xh (fp16, row-swizzled)
//   j = i - 2097152:
//     j in [0, 65536):            Wgo [512][1024] row-swizzle
//     j in [65536, 196608):       Wav pack P = by*128 + (half*64 + g*16 + nl)
//     j in [196608, 262144):      Wout pack P = by*128 + (chunk*32 + g*16 + nl)
// ---------------------------------------------------------------------------
__global__ __launch_bounds__(256) void prep_all(
    const float* __restrict__ x, const float* __restrict__ Wgo,
    const float* __restrict__ Wav, const float* __restrict__ Wout,
    h16* __restrict__ xh, h16* __restrict__ Wgoh,
    h16* __restrict__ Wavh, h16* __restrict__ Wouth)
{
    int i = blockIdx.x * 256 + threadIdx.x;
    const float* s;
    h16* d;
    if (i < 2097152) {               // x
        int m = i >> 6, bb = i & 63;
        s = x + (size_t)m * 512 + bb * 8;
        d = xh + (size_t)m * 512 + (bb ^ (m & 7)) * 8;
    } else {
        int j = i - 2097152;
        if (j < 65536) {             // Wgo
            int r = j >> 7, bb = j & 127;
            s = Wgo + (size_t)r * 1024 + bb * 8;
            d = Wgoh + (size_t)r * 1024 + (bb ^ (r & 7)) * 8;
        } else if (j < 196608) {     // Wav
            int k = j - 65536;
            int P = k >> 6, bb = k & 63;
            int by = P >> 7, lo = P & 127;
            int half = lo >> 6, g = (lo >> 4) & 3, nl = lo & 15;
            int orig = g * 512 + by * 32 + half * 16 + nl;
            s = Wav + (size_t)orig * 512 + bb * 8;
            d = Wavh + (size_t)P * 512 + (bb ^ (P & 7)) * 8;
        } else {                     // Wout
            int k = j - 196608;
            int P = k >> 6, bb = k & 63;
            int by = P >> 7, lo = P & 127;
            int chunk = lo >> 5, g = (lo >> 4) & 1, nl = lo & 15;
            int orig = g * 512 + by * 64 + chunk * 16 + nl;
            s = Wout + (size_t)orig * 512 + bb * 8;
            d = Wouth + (size_t)P * 512 + (bb ^ (P & 7)) * 8;
        }
    }
    const float4* sv = (const float4*)s;
    float4 v0 = sv[0], v1 = sv[1];
    float vv[8] = {v0.x, v0.y, v0.z, v0.w, v1.x, v1.y, v1.z, v1.w};
    f16x8 hh;
    #pragma unroll
    for (int j = 0; j < 8; ++j) hh[j] = (h16)vv[j];
    *(f16x8*)d = hh;
}

// Pipeline sync helpers for the dbuf kernels (raw barrier keeps prefetch alive)
#define PIPE_WAIT(N) do { \
    asm volatile("s_waitcnt vmcnt(" #N ")" ::: "memory"); \
    __builtin_amdgcn_s_barrier(); \
    asm volatile("" ::: "memory"); \
} while (0)
#define PIPE_POST() do { \
    __builtin_amdgcn_s_barrier(); \
    asm volatile("" ::: "memory"); \
} while (0)

// ---------------------------------------------------------------------------
// GEMM1: [M1 x 512] x [512 x 2048(packed 4 groups)] + NRU combine -> ms_inp
// (fp16). Single-buffer 32KB, 3 blocks/CU (r9-proven structure).
// ---------------------------------------------------------------------------
__global__ __launch_bounds__(256) WAVES_EU(3, 3) void gemm_av_mfma(
    const h16* __restrict__ xh, const h16* __restrict__ Wh,
    const float* __restrict__ bav, h16* __restrict__ ms_inp)
{
    __shared__ __align__(16) h16 As[128 * 64];   // 16 KB each
    __shared__ __align__(16) h16 Bh[128 * 64];

    int bx, by; xcd_remap(bx, by);
    const int tid = threadIdx.x, lane = tid & 63, w = tid >> 6;
    const int wm = (w & 1) * 64, wn = (w >> 1) * 64;
    const int bm = bx * 128;
    const int ln = lane & 15, ko = (lane >> 4) * 8;
    const int kb = ln & 7;
    char* lA = (char*)As; char* lH = (char*)Bh;
    const int wb = w * 1024;

    const char *aP[4], *hP[4];
    {
        const int r8 = lane >> 3, c16 = (lane & 7) * 16;
        #pragma unroll
        for (int i = 0; i < 4; ++i) {
            int row = i * 32 + w * 8 + r8;
            int mg = bm + row; if (mg > M1 - 1) mg = M1 - 1;
            size_t xr = (size_t)mg + (unsigned)mg / (L_SZ - 1);
            aP[i] = (const char*)xh + xr * (DM * 2) + c16;
            size_t br = (size_t)(by * 128 + row) * (DM * 2) + c16;
            hP[i] = (const char*)Wh + br;
        }
    }
    int ka[4];
    #pragma unroll
    for (int fm = 0; fm < 4; ++fm) {
        int m = bm + wm + fm * 16 + ln;
        int mg = m > M1 - 1 ? M1 - 1 : m;
        ka[fm] = (int)((mg + (unsigned)mg / (L_SZ - 1)) & 7);
    }

    f32x4 acc[4][4];
    #pragma unroll
    for (int i = 0; i < 4; ++i)
        #pragma unroll
        for (int j = 0; j < 4; ++j) acc[i][j] = (f32x4){0.f, 0.f, 0.f, 0.f};

#define STAGE_AV(koff) do { \
    gl16(aP[0] + (koff), lA + 0 * 4096 + wb); gl16(hP[0] + (koff), lH + 0 * 4096 + wb); \
    gl16(aP[1] + (koff), lA + 1 * 4096 + wb); gl16(hP[1] + (koff), lH + 1 * 4096 + wb); \
    gl16(aP[2] + (koff), lA + 2 * 4096 + wb); gl16(hP[2] + (koff), lH + 2 * 4096 + wb); \
    gl16(aP[3] + (koff), lA + 3 * 4096 + wb); gl16(hP[3] + (koff), lH + 3 * 4096 + wb); \
} while (0)

    STAGE_AV(0);
    for (int kt = 0; kt < 8; ++kt) {
        asm volatile("s_waitcnt vmcnt(0)" ::: "memory");
        __syncthreads();
        #pragma unroll
        for (int s = 0; s < 2; ++s) {
            const int c = s * 32 + ko;
            f16x8 a[4];
            #pragma unroll
            for (int fm = 0; fm < 4; ++fm)
                a[fm] = lds_frag(As, wm + fm * 16 + ln, c, ka[fm]);
            #pragma unroll
            for (int fn = 0; fn < 4; ++fn) {
                f16x8 vh = lds_frag(Bh, wn + fn * 16 + ln, c, kb);
                #pragma unroll
                for (int fm = 0; fm < 4; ++fm)
                    acc[fm][fn] = MFMA16(a[fm], vh, acc[fm][fn]);
            }
        }
        __syncthreads();
        if (kt < 7) STAGE_AV((kt + 1) * 128);
    }
#undef STAGE_AV

    // epilogue: fn = group; combine in-register; write fp16
    const int lm = (lane >> 4) * 4;
    const int nn = by * 32 + (wn >> 6) * 16 + ln;
    const float b0 = bav[nn], b1 = bav[nn + 512], b2 = bav[nn + 1024], b3 = bav[nn + 1536];
    #pragma unroll
    for (int fm = 0; fm < 4; ++fm) {
        #pragma unroll
        for (int i = 0; i < 4; ++i) {
            int m = bm + wm + fm * 16 + lm + i;
            if (m < M1) {
                float a0 = acc[fm][0][i] + b0;
                float a1 = acc[fm][1][i] + b1;
                float a2 = acc[fm][2][i] + b2;
                float a3 = acc[fm][3][i] + b3;
                ms_inp[(size_t)m * DMEM + nn] = (h16)(a0 * a1 - a2 * a3);
            }
        }
    }
}

// ---------------------------------------------------------------------------
// Chunked cumsum over fp16 ms_inp (fp32 accumulation).
// pass1: per-chunk sums. 64 lanes/chunk x 8 cols (f16x8 = 16B/lane), 4
// chunks per 256-thread block. Grid (16, B).
// ---------------------------------------------------------------------------
__global__ __launch_bounds__(256) void scan_pass1(
    const h16* __restrict__ ms_inp, float* __restrict__ csum)
{
    int b = blockIdx.y;
    int c = blockIdx.x * 4 + (threadIdx.x >> 6);
    int t = threadIdx.x & 63;
    int l0 = c * 128;
    int len = min(128, (L_SZ - 1) - l0);
    const h16* p = ms_inp + ((size_t)b * (L_SZ - 1) + l0) * DMEM + t * 8;
    float s[8] = {0.f, 0.f, 0.f, 0.f, 0.f, 0.f, 0.f, 0.f};
    for (int i = 0; i < len; ++i) {
        f16x8 v = *(const f16x8*)(p + (size_t)i * DMEM);
        #pragma unroll
        for (int j = 0; j < 8; ++j) s[j] += (float)v[j];
    }
    float* q = csum + ((size_t)b * 64 + c) * DMEM + t * 8;
    *(float4*)q       = make_float4(s[0], s[1], s[2], s[3]);
    *(float4*)(q + 4) = make_float4(s[4], s[5], s[6], s[7]);
}

// Wave-parallel exclusive scan of the 64 chunk sums per (b,d).
__global__ __launch_bounds__(256) void scan_pass2(float* __restrict__ csum)
{
    int sid = blockIdx.x * 4 + (threadIdx.x >> 6);
    int lane = threadIdx.x & 63;
    int b = sid >> 9, d = sid & 511;
    float* p = csum + (size_t)b * 64 * DMEM + d;
    float v = p[(size_t)lane * DMEM];
    #pragma unroll
    for (int off = 1; off < 64; off <<= 1) {
        float t = __shfl_up(v, off, 64);
        if (lane >= off) v += t;
    }
    float ex = __shfl_up(v, 1, 64);
    if (lane == 0) ex = 0.f;
    p[(size_t)lane * DMEM] = ex;
}

// pass3: chunk-local inclusive scan + offset -> msh (fp16, swizzled layout).
// Each thread owns one 8-col group = exactly one 16B swizzle block.
__global__ __launch_bounds__(256) void scan_pass3(
    const h16* __restrict__ ms_inp, const float* __restrict__ csum,
    h16* __restrict__ msh)
{
    int b = blockIdx.y;
    int c = blockIdx.x * 4 + (threadIdx.x >> 6);
    int t = threadIdx.x & 63;
    int l0 = c * 128;
    int len = min(128, (L_SZ - 1) - l0);
    const float* q = csum + ((size_t)b * 64 + c) * DMEM + t * 8;
    float run[8];
    #pragma unroll
    for (int j = 0; j < 8; ++j) run[j] = q[j];
    const h16* p = ms_inp + ((size_t)b * (L_SZ - 1) + l0) * DMEM + t * 8;
    if (c == 0) {                        // row l=0: m&7==0 -> identity swizzle
        f16x8 z = {};
        *(f16x8*)(msh + (size_t)b * L_SZ * DMEM + t * 8) = z;
    }
    for (int i = 0; i < len; ++i) {
        f16x8 v = *(const f16x8*)(p + (size_t)i * DMEM);
        f16x8 o;
        #pragma unroll
        for (int j = 0; j < 8; ++j) { run[j] += (float)v[j]; o[j] = (h16)run[j]; }
        int m = b * L_SZ + l0 + 1 + i;
        int db = t ^ (m & 7);
        *(f16x8*)(msh + (size_t)m * DMEM + db * 8) = o;
    }
}

// ---------------------------------------------------------------------------
// GEMM2: [M2 x 1024 (x||ms)] x [1024 x 512] + GELU -> yh (fp16, swizzled).
// Double-buffered issue-early pipeline (r10 structure, kept).
// ---------------------------------------------------------------------------
__global__ __launch_bounds__(256) WAVES_EU(2, 2) void gemm_go_mfma(
    const h16* __restrict__ xh, const h16* __restrict__ msh,
    const h16* __restrict__ Wh,
    const float* __restrict__ bgo, h16* __restrict__ yh)
{
    __shared__ __align__(16) h16 As[2][128 * 64];
    __shared__ __align__(16) h16 Bh[2][128 * 64];

    int bx, by; xcd_remap(bx, by);
    const int tid = threadIdx.x, lane = tid & 63, w = tid >> 6;
    const int wm = (w & 1) * 64, wn = (w >> 1) * 64;
    const int bm = bx * 128, bn = by * 128;
    const int ln = lane & 15, ko = (lane >> 4) * 8;
    const int kk = ln & 7;
    const int wb = w * 1024;

    const char *xP[4], *mP[4], *hP[4];
    {
        const int r8 = lane >> 3, c16 = (lane & 7) * 16;
        #pragma unroll
        for (int i = 0; i < 4; ++i) {
            int row = i * 32 + w * 8 + r8;
            size_t ar = (size_t)(bm + row) * (DM * 2) + c16;
            xP[i] = (const char*)xh + ar;
            mP[i] = (const char*)msh + ar;
            size_t br = (size_t)(bn + row) * (2 * DM * 2) + c16;
            hP[i] = (const char*)Wh + br;
        }
    }

    f32x4 acc[4][4];
    #pragma unroll
    for (int i = 0; i < 4; ++i)
        #pragma unroll
        for (int j = 0; j < 4; ++j) acc[i][j] = (f32x4){0.f, 0.f, 0.f, 0.f};

#define STAGE_GO(tt, sel) do { \
    char* dA = (char*)As[sel]; char* dB = (char*)Bh[sel]; \
    const int bo = (tt) * 128; \
    if ((tt) < 8) { \
        const int ao = (tt) * 128; \
        gl16(xP[0] + ao, dA + 0 * 4096 + wb); gl16(hP[0] + bo, dB + 0 * 4096 + wb); \
        gl16(xP[1] + ao, dA + 1 * 4096 + wb); gl16(hP[1] + bo, dB + 1 * 4096 + wb); \
        gl16(xP[2] + ao, dA + 2 * 4096 + wb); gl16(hP[2] + bo, dB + 2 * 4096 + wb); \
        gl16(xP[3] + ao, dA + 3 * 4096 + wb); gl16(hP[3] + bo, dB + 3 * 4096 + wb); \
    } else { \
        const int ao = ((tt) - 8) * 128; \
        gl16(mP[0] + ao, dA + 0 * 4096 + wb); gl16(hP[0] + bo, dB + 0 * 4096 + wb); \
        gl16(mP[1] + ao, dA + 1 * 4096 + wb); gl16(hP[1] + bo, dB + 1 * 4096 + wb); \
        gl16(mP[2] + ao, dA + 2 * 4096 + wb); gl16(hP[2] + bo, dB + 2 * 4096 + wb); \
        gl16(mP[3] + ao, dA + 3 * 4096 + wb); gl16(hP[3] + bo, dB + 3 * 4096 + wb); \
    } \
} while (0)

    STAGE_GO(0, 0);
    STAGE_GO(1, 1);
    for (int kt = 0; kt < 16; ++kt) {
        if (kt < 15) PIPE_WAIT(8); else PIPE_WAIT(0);
        const h16* A = As[kt & 1];
        const h16* B = Bh[kt & 1];
        #pragma unroll
        for (int s = 0; s < 2; ++s) {
            const int c = s * 32 + ko;
            f16x8 a[4];
            #pragma unroll
            for (int fm = 0; fm < 4; ++fm)
                a[fm] = lds_frag(A, wm + fm * 16 + ln, c, kk);
            #pragma unroll
            for (int fn = 0; fn < 4; ++fn) {
                f16x8 vh = lds_frag(B, wn + fn * 16 + ln, c, kk);
                #pragma unroll
                for (int fm = 0; fm < 4; ++fm)
                    acc[fm][fn] = MFMA16(a[fm], vh, acc[fm][fn]);
            }
        }
        PIPE_POST();
        if (kt + 2 < 16) STAGE_GO(kt + 2, kt & 1);
    }
#undef STAGE_GO

    const int lm = (lane >> 4) * 4;
    #pragma unroll
    for (int fm = 0; fm < 4; ++fm) {
        #pragma unroll
        for (int fn = 0; fn < 4; ++fn) {
            int n = bn + wn + fn * 16 + ln;
            float bias = bgo[n];
            #pragma unroll
            for (int i = 0; i < 4; ++i) {
                int m = bm + wm + fm * 16 + lm + i;
                float t = acc[fm][fn][i] + bias;
                float g = 0.5f * t * (1.0f + erff(t * 0.70710678118654752f));
                int nsw = (((n >> 3) ^ (m & 7)) << 3) | (n & 7);
                yh[(size_t)m * DM + nsw] = (h16)g;
            }
        }
    }
}

// ---------------------------------------------------------------------------
// GEMM3: [M2 x 512] x [512 x 1024(packed 2 groups)] + GLU -> out (fp32).
// Double-buffered issue-early pipeline (r10 structure, kept).
// ---------------------------------------------------------------------------
__global__ __launch_bounds__(256) WAVES_EU(2, 2) void gemm_out_mfma(
    const h16* __restrict__ yh, const h16* __restrict__ Wh,
    const float* __restrict__ bout, float* __restrict__ out)
{
    __shared__ __align__(16) h16 As[2][128 * 64];
    __shared__ __align__(16) h16 Bh[2][128 * 64];

    int bx, by; xcd_remap(bx, by);
    const int tid = threadIdx.x, lane = tid & 63, w = tid >> 6;
    const int wm = (w & 1) * 64, wn = (w >> 1) * 64;
    const int bm = bx * 128;
    const int ln = lane & 15, ko = (lane >> 4) * 8;
    const int kk = ln & 7;
    const int wb = w * 1024;

    const char *aP[4], *hP[4];
    {
        const int r8 = lane >> 3, c16 = (lane & 7) * 16;
        #pragma unroll
        for (int i = 0; i < 4; ++i) {
            int row = i * 32 + w * 8 + r8;
            aP[i] = (const char*)yh + (size_t)(bm + row) * (DM * 2) + c16;
            size_t br = (size_t)(by * 128 + row) * (DM * 2) + c16;
            hP[i] = (const char*)Wh + br;
        }
    }

    f32x4 acc[4][4];
    #pragma unroll
    for (int i = 0; i < 4; ++i)
        #pragma unroll
        for (int j = 0; j < 4; ++j) acc[i][j] = (f32x4){0.f, 0.f, 0.f, 0.f};

#define STAGE_OUT(koff, sel) do { \
    char* dA = (char*)As[sel]; char* dB = (char*)Bh[sel]; \
    gl16(aP[0] + (koff), dA + 0 * 4096 + wb); gl16(hP[0] + (koff), dB + 0 * 4096 + wb); \
    gl16(aP[1] + (koff), dA + 1 * 4096 + wb); gl16(hP[1] + (koff), dB + 1 * 4096 + wb); \
    gl16(aP[2] + (koff), dA + 2 * 4096 + wb); gl16(hP[2] + (koff), dB + 2 * 4096 + wb); \
    gl16(aP[3] + (koff), dA + 3 * 4096 + wb); gl16(hP[3] + (koff), dB + 3 * 4096 + wb); \
} while (0)

    STAGE_OUT(0, 0);
    STAGE_OUT(128, 1);
    for (int kt = 0; kt < 8; ++kt) {
        if (kt < 7) PIPE_WAIT(8); else PIPE_WAIT(0);
        const h16* A = As[kt & 1];
        const h16* B = Bh[kt & 1];
        #pragma unroll
        for (int s = 0; s < 2; ++s) {
            const int c = s * 32 + ko;
            f16x8 a[4];
            #pragma unroll
            for (int fm = 0; fm < 4; ++fm)
                a[fm] = lds_frag(A, wm + fm * 16 + ln, c, kk);
            #pragma unroll
            for (int fn = 0; fn < 4; ++fn) {
                f16x8 vh = lds_frag(B, wn + fn * 16 + ln, c, kk);
                #pragma unroll
                for (int fm = 0; fm < 4; ++fm)
                    acc[fm][fn] = MFMA16(a[fm], vh, acc[fm][fn]);
            }
        }
        PIPE_POST();
        if (kt + 2 < 8) STAGE_OUT((kt + 2) * 128, kt & 1);
    }
#undef STAGE_OUT

    const int lm = (lane >> 4) * 4;
    #pragma unroll
    for (int fm = 0; fm < 4; ++fm) {
        #pragma unroll
        for (int cp = 0; cp < 2; ++cp) {
            int ncol = by * 64 + ((wn >> 5) + cp) * 16 + ln;
            float bz0 = bout[ncol], bz1 = bout[ncol + 512];
            #pragma unroll
            for (int i = 0; i < 4; ++i) {
                int m = bm + wm + fm * 16 + lm + i;
                float z0 = acc[fm][cp * 2 + 0][i] + bz0;
                float z1 = acc[fm][cp * 2 + 1][i] + bz1;
                out[(size_t)m * DM + ncol] = z0 * (1.0f / (1.0f + expf(-z1)));
            }
        }
    }
}

// ---------------------------------------------------------------------------
extern "C" void kernel_launch(void* const* d_in, const int* in_sizes, int n_in,
                              void* d_out, int out_size, void* d_ws, size_t ws_size,
                              hipStream_t stream)
{
    const float* x    = (const float*)d_in[0];
    const float* Wav  = (const float*)d_in[1];
    const float* bav  = (const float*)d_in[2];
    const float* Wgo  = (const float*)d_in[3];
    const float* bgo  = (const float*)d_in[4];
    const float* Wout = (const float*)d_in[5];
    const float* bout = (const float*)d_in[6];
    float* out = (float*)d_out;

    char* ws = (char*)d_ws;
    const size_t MB = 1 << 20;
    h16*   ms_inp = (h16*)ws;                     // 32 MiB [32764,512] fp16
    h16*   yh     = (h16*)(ws + 32 * MB);         // 32 MiB (after scan)
    h16*   xh     = (h16*)(ws + 64 * MB);         // 32 MiB (swizzled fp16)
    h16*   msh    = (h16*)(ws + 96 * MB);         // 32 MiB (swizzled fp16)
    float* csum   = (float*)(ws + 128 * MB);      // 0.5 MiB
    h16*   Wavh   = (h16*)(ws + 129 * MB);        // 2 MiB (packed+swizzled)
    h16*   Wgoh   = (h16*)(ws + 131 * MB);        // 1 MiB
    h16*   Wouth  = (h16*)(ws + 132 * MB);        // 1 MiB

    // 0) precompute fp16 forms (one launch)
    prep_all<<<9216, 256, 0, stream>>>(x, Wgo, Wav, Wout, xh, Wgoh, Wavh, Wouth);
    // 1) av GEMM + NRU combine -> ms_inp (fp16)
    gemm_av_mfma<<<dim3(256, 16), 256, 0, stream>>>(xh, Wavh, bav, ms_inp);
    // 2-4) chunked cumsum -> msh (fp16, swizzled)
    scan_pass1<<<dim3(16, B_SZ), 256, 0, stream>>>(ms_inp, csum);
    scan_pass2<<<512, 256, 0, stream>>>(csum);
    scan_pass3<<<dim3(16, B_SZ), 256, 0, stream>>>(ms_inp, csum, msh);
    // 5) SSM-in GEMM + GELU -> yh (fp16 swizzled)
    gemm_go_mfma<<<dim3(256, 4), 256, 0, stream>>>(xh, msh, Wgoh, bgo, yh);
    // 6) output GEMM + GLU -> out (f32)
    gemm_out_mfma<<<dim3(256, 8), 256, 0, stream>>>(yh, Wouth, bout, out);
}

// Round 12
// 233.376 us; speedup vs baseline: 4.1038x; 1.1818x over previous
//
#include <hip/hip_runtime.h>
#include <hip/hip_bf16.h>
#include <math.h>

// Problem constants
#define B_SZ 4
#define L_SZ 8192
#define DM 512           // D_MODEL
#define DMEM 512         // D_MEM
#define M1 (B_SZ * (L_SZ - 1))   // 32764 rows for the av GEMM
#define M2 (B_SZ * L_SZ)         // 32768 rows for GEMM2/3

typedef _Float16 h16;
typedef __attribute__((ext_vector_type(2))) _Float16 f16x2;
typedef __attribute__((ext_vector_type(8))) _Float16 f16x8;
typedef __attribute__((ext_vector_type(4))) float f32x4;

#define MFMA16(a, b, c) __builtin_amdgcn_mfma_f32_16x16x32_f16((a), (b), (c), 0, 0, 0)
#define WAVES_EU(mn, mx) __attribute__((amdgpu_waves_per_eu(mn, mx)))

// async global->LDS, 16B per lane
__device__ __forceinline__ void gl16(const void* g, void* l) {
    __builtin_amdgcn_global_load_lds(
        (const __attribute__((address_space(1))) void*)g,
        (__attribute__((address_space(3))) void*)l, 16, 0, 0);
}

// Swizzled LDS fragment read from a [128 rows][64 cols] fp16 tile (128 B rows).
__device__ __forceinline__ f16x8 lds_frag(const h16* base, int row, int col, int key) {
    return *(const f16x8*)((const char*)base + row * 128 + ((col * 2) ^ (key << 4)));
}

// XCD swizzle, A-reuse-friendly decode (by fast -> weight panel L2-resident).
__device__ __forceinline__ void xcd_remap(int& bx, int& by) {
    int gx = gridDim.x, gy = gridDim.y;
    int nwg = gx * gy;
    int lin = blockIdx.y * gx + blockIdx.x;
    int chunk = nwg >> 3;
    int l = (lin & 7) * chunk + (lin >> 3);
    by = l % gy;
    bx = l / gy;
}

// ---------------------------------------------------------------------------
// Merged precompute: x conv + all weight packs in ONE launch.
// ---------------------------------------------------------------------------
__global__ __launch_bounds__(256) void prep_all(
    const float* __restrict__ x, const float* __restrict__ Wgo,
    const float* __restrict__ Wav, const float* __restrict__ Wout,
    h16* __restrict__ xh, h16* __restrict__ Wgoh,
    h16* __restrict__ Wavh, h16* __restrict__ Wouth)
{
    int i = blockIdx.x * 256 + threadIdx.x;
    const float* s;
    h16* d;
    if (i < 2097152) {               // x
        int m = i >> 6, bb = i & 63;
        s = x + (size_t)m * 512 + bb * 8;
        d = xh + (size_t)m * 512 + (bb ^ (m & 7)) * 8;
    } else {
        int j = i - 2097152;
        if (j < 65536) {             // Wgo
            int r = j >> 7, bb = j & 127;
            s = Wgo + (size_t)r * 1024 + bb * 8;
            d = Wgoh + (size_t)r * 1024 + (bb ^ (r & 7)) * 8;
        } else if (j < 196608) {     // Wav
            int k = j - 65536;
            int P = k >> 6, bb = k & 63;
            int by = P >> 7, lo = P & 127;
            int half = lo >> 6, g = (lo >> 4) & 3, nl = lo & 15;
            int orig = g * 512 + by * 32 + half * 16 + nl;
            s = Wav + (size_t)orig * 512 + bb * 8;
            d = Wavh + (size_t)P * 512 + (bb ^ (P & 7)) * 8;
        } else {                     // Wout
            int k = j - 196608;
            int P = k >> 6, bb = k & 63;
            int by = P >> 7, lo = P & 127;
            int chunk = lo >> 5, g = (lo >> 4) & 1, nl = lo & 15;
            int orig = g * 512 + by * 64 + chunk * 16 + nl;
            s = Wout + (size_t)orig * 512 + bb * 8;
            d = Wouth + (size_t)P * 512 + (bb ^ (P & 7)) * 8;
        }
    }
    const float4* sv = (const float4*)s;
    float4 v0 = sv[0], v1 = sv[1];
    float vv[8] = {v0.x, v0.y, v0.z, v0.w, v1.x, v1.y, v1.z, v1.w};
    f16x8 hh;
    #pragma unroll
    for (int j = 0; j < 8; ++j) hh[j] = (h16)vv[j];
    *(f16x8*)d = hh;
}

// Pipeline sync helpers for the dbuf kernels (raw barrier keeps prefetch alive)
#define PIPE_WAIT(N) do { \
    asm volatile("s_waitcnt vmcnt(" #N ")" ::: "memory"); \
    __builtin_amdgcn_s_barrier(); \
    asm volatile("" ::: "memory"); \
} while (0)
#define PIPE_POST() do { \
    __builtin_amdgcn_s_barrier(); \
    asm volatile("" ::: "memory"); \
} while (0)

// ---------------------------------------------------------------------------
// GEMM1: [M1 x 512] x [512 x 2048(packed 4 groups)] + NRU combine -> ms_inp
// (fp16). Single-buffer 32KB, 3 blocks/CU (r9-proven structure).
// ---------------------------------------------------------------------------
__global__ __launch_bounds__(256) WAVES_EU(3, 3) void gemm_av_mfma(
    const h16* __restrict__ xh, const h16* __restrict__ Wh,
    const float* __restrict__ bav, h16* __restrict__ ms_inp)
{
    __shared__ __align__(16) h16 As[128 * 64];   // 16 KB each
    __shared__ __align__(16) h16 Bh[128 * 64];

    int bx, by; xcd_remap(bx, by);
    const int tid = threadIdx.x, lane = tid & 63, w = tid >> 6;
    const int wm = (w & 1) * 64, wn = (w >> 1) * 64;
    const int bm = bx * 128;
    const int ln = lane & 15, ko = (lane >> 4) * 8;
    const int kb = ln & 7;
    char* lA = (char*)As; char* lH = (char*)Bh;
    const int wb = w * 1024;

    const char *aP[4], *hP[4];
    {
        const int r8 = lane >> 3, c16 = (lane & 7) * 16;
        #pragma unroll
        for (int i = 0; i < 4; ++i) {
            int row = i * 32 + w * 8 + r8;
            int mg = bm + row; if (mg > M1 - 1) mg = M1 - 1;
            size_t xr = (size_t)mg + (unsigned)mg / (L_SZ - 1);
            aP[i] = (const char*)xh + xr * (DM * 2) + c16;
            size_t br = (size_t)(by * 128 + row) * (DM * 2) + c16;
            hP[i] = (const char*)Wh + br;
        }
    }
    int ka[4];
    #pragma unroll
    for (int fm = 0; fm < 4; ++fm) {
        int m = bm + wm + fm * 16 + ln;
        int mg = m > M1 - 1 ? M1 - 1 : m;
        ka[fm] = (int)((mg + (unsigned)mg / (L_SZ - 1)) & 7);
    }

    f32x4 acc[4][4];
    #pragma unroll
    for (int i = 0; i < 4; ++i)
        #pragma unroll
        for (int j = 0; j < 4; ++j) acc[i][j] = (f32x4){0.f, 0.f, 0.f, 0.f};

#define STAGE_AV(koff) do { \
    gl16(aP[0] + (koff), lA + 0 * 4096 + wb); gl16(hP[0] + (koff), lH + 0 * 4096 + wb); \
    gl16(aP[1] + (koff), lA + 1 * 4096 + wb); gl16(hP[1] + (koff), lH + 1 * 4096 + wb); \
    gl16(aP[2] + (koff), lA + 2 * 4096 + wb); gl16(hP[2] + (koff), lH + 2 * 4096 + wb); \
    gl16(aP[3] + (koff), lA + 3 * 4096 + wb); gl16(hP[3] + (koff), lH + 3 * 4096 + wb); \
} while (0)

    STAGE_AV(0);
    for (int kt = 0; kt < 8; ++kt) {
        asm volatile("s_waitcnt vmcnt(0)" ::: "memory");
        __syncthreads();
        #pragma unroll
        for (int s = 0; s < 2; ++s) {
            const int c = s * 32 + ko;
            f16x8 a[4];
            #pragma unroll
            for (int fm = 0; fm < 4; ++fm)
                a[fm] = lds_frag(As, wm + fm * 16 + ln, c, ka[fm]);
            #pragma unroll
            for (int fn = 0; fn < 4; ++fn) {
                f16x8 vh = lds_frag(Bh, wn + fn * 16 + ln, c, kb);
                #pragma unroll
                for (int fm = 0; fm < 4; ++fm)
                    acc[fm][fn] = MFMA16(a[fm], vh, acc[fm][fn]);
            }
        }
        __syncthreads();
        if (kt < 7) STAGE_AV((kt + 1) * 128);
    }
#undef STAGE_AV

    // epilogue: fn = group; combine in-register; write fp16
    const int lm = (lane >> 4) * 4;
    const int nn = by * 32 + (wn >> 6) * 16 + ln;
    const float b0 = bav[nn], b1 = bav[nn + 512], b2 = bav[nn + 1024], b3 = bav[nn + 1536];
    #pragma unroll
    for (int fm = 0; fm < 4; ++fm) {
        #pragma unroll
        for (int i = 0; i < 4; ++i) {
            int m = bm + wm + fm * 16 + lm + i;
            if (m < M1) {
                float a0 = acc[fm][0][i] + b0;
                float a1 = acc[fm][1][i] + b1;
                float a2 = acc[fm][2][i] + b2;
                float a3 = acc[fm][3][i] + b3;
                ms_inp[(size_t)m * DMEM + nn] = (h16)(a0 * a1 - a2 * a3);
            }
        }
    }
}

// ---------------------------------------------------------------------------
// Chunked cumsum over fp16 ms_inp (fp32 accumulation). Chunk = 32 rows.
// pass1: per-chunk sums. 64 lanes/chunk x 8 cols (f16x8 = 16B/lane), 4
// chunks per 256-thread block. Grid (64, B) = 256 blocks (1/CU).
// csum layout: [b][c=0..255][d=0..511] fp32 (2 MB).
// ---------------------------------------------------------------------------
__global__ __launch_bounds__(256) void scan_pass1(
    const h16* __restrict__ ms_inp, float* __restrict__ csum)
{
    int b = blockIdx.y;
    int c = blockIdx.x * 4 + (threadIdx.x >> 6);    // 0..255
    int t = threadIdx.x & 63;
    int l0 = c * 32;
    int len = min(32, (L_SZ - 1) - l0);
    const h16* p = ms_inp + ((size_t)b * (L_SZ - 1) + l0) * DMEM + t * 8;
    float s[8] = {0.f, 0.f, 0.f, 0.f, 0.f, 0.f, 0.f, 0.f};
    for (int i = 0; i < len; ++i) {
        f16x8 v = *(const f16x8*)(p + (size_t)i * DMEM);
        #pragma unroll
        for (int j = 0; j < 8; ++j) s[j] += (float)v[j];
    }
    float* q = csum + ((size_t)b * 256 + c) * DMEM + t * 8;
    *(float4*)q       = make_float4(s[0], s[1], s[2], s[3]);
    *(float4*)(q + 4) = make_float4(s[4], s[5], s[6], s[7]);
}

// pass2: block-parallel exclusive scan of the 256 chunk sums per (b,d).
// One 256-thread block per (b,d); grid 2048. Reads are strided but csum is
// L2-resident (2 MB, just written).
__global__ __launch_bounds__(256) void scan_pass2(float* __restrict__ csum)
{
    __shared__ float wsum[4];
    int b = blockIdx.x >> 9, d = blockIdx.x & 511;
    int t = threadIdx.x, lane = t & 63, wv = t >> 6;
    float* p = csum + (size_t)b * 256 * DMEM + d;
    float v = p[(size_t)t * DMEM];
    #pragma unroll
    for (int off = 1; off < 64; off <<= 1) {
        float u = __shfl_up(v, off, 64);
        if (lane >= off) v += u;
    }
    if (lane == 63) wsum[wv] = v;
    __syncthreads();
    float add = 0.f;
    #pragma unroll
    for (int i = 0; i < 4; ++i) if (i < wv) add += wsum[i];
    v += add;
    float ex = __shfl_up(v, 1, 64);
    if (lane == 0) ex = add;
    p[(size_t)t * DMEM] = ex;
}

// pass3: chunk-local inclusive scan + offset -> msh (fp16, swizzled layout).
// Each thread owns one 8-col group = exactly one 16B swizzle block.
__global__ __launch_bounds__(256) void scan_pass3(
    const h16* __restrict__ ms_inp, const float* __restrict__ csum,
    h16* __restrict__ msh)
{
    int b = blockIdx.y;
    int c = blockIdx.x * 4 + (threadIdx.x >> 6);
    int t = threadIdx.x & 63;
    int l0 = c * 32;
    int len = min(32, (L_SZ - 1) - l0);
    const float* q = csum + ((size_t)b * 256 + c) * DMEM + t * 8;
    float run[8];
    #pragma unroll
    for (int j = 0; j < 8; ++j) run[j] = q[j];
    const h16* p = ms_inp + ((size_t)b * (L_SZ - 1) + l0) * DMEM + t * 8;
    if (c == 0) {                        // row l=0: m&7==0 -> identity swizzle
        f16x8 z = {};
        *(f16x8*)(msh + (size_t)b * L_SZ * DMEM + t * 8) = z;
    }
    for (int i = 0; i < len; ++i) {
        f16x8 v = *(const f16x8*)(p + (size_t)i * DMEM);
        f16x8 o;
        #pragma unroll
        for (int j = 0; j < 8; ++j) { run[j] += (float)v[j]; o[j] = (h16)run[j]; }
        int m = b * L_SZ + l0 + 1 + i;
        int db = t ^ (m & 7);
        *(f16x8*)(msh + (size_t)m * DMEM + db * 8) = o;
    }
}

// ---------------------------------------------------------------------------
// GEMM2: [M2 x 1024 (x||ms)] x [1024 x 512] + GELU -> yh (fp16, swizzled).
// Double-buffered issue-early pipeline.
// ---------------------------------------------------------------------------
__global__ __launch_bounds__(256) WAVES_EU(2, 2) void gemm_go_mfma(
    const h16* __restrict__ xh, const h16* __restrict__ msh,
    const h16* __restrict__ Wh,
    const float* __restrict__ bgo, h16* __restrict__ yh)
{
    __shared__ __align__(16) h16 As[2][128 * 64];
    __shared__ __align__(16) h16 Bh[2][128 * 64];

    int bx, by; xcd_remap(bx, by);
    const int tid = threadIdx.x, lane = tid & 63, w = tid >> 6;
    const int wm = (w & 1) * 64, wn = (w >> 1) * 64;
    const int bm = bx * 128, bn = by * 128;
    const int ln = lane & 15, ko = (lane >> 4) * 8;
    const int kk = ln & 7;
    const int wb = w * 1024;

    const char *xP[4], *mP[4], *hP[4];
    {
        const int r8 = lane >> 3, c16 = (lane & 7) * 16;
        #pragma unroll
        for (int i = 0; i < 4; ++i) {
            int row = i * 32 + w * 8 + r8;
            size_t ar = (size_t)(bm + row) * (DM * 2) + c16;
            xP[i] = (const char*)xh + ar;
            mP[i] = (const char*)msh + ar;
            size_t br = (size_t)(bn + row) * (2 * DM * 2) + c16;
            hP[i] = (const char*)Wh + br;
        }
    }

    f32x4 acc[4][4];
    #pragma unroll
    for (int i = 0; i < 4; ++i)
        #pragma unroll
        for (int j = 0; j < 4; ++j) acc[i][j] = (f32x4){0.f, 0.f, 0.f, 0.f};

#define STAGE_GO(tt, sel) do { \
    char* dA = (char*)As[sel]; char* dB = (char*)Bh[sel]; \
    const int bo = (tt) * 128; \
    if ((tt) < 8) { \
        const int ao = (tt) * 128; \
        gl16(xP[0] + ao, dA + 0 * 4096 + wb); gl16(hP[0] + bo, dB + 0 * 4096 + wb); \
        gl16(xP[1] + ao, dA + 1 * 4096 + wb); gl16(hP[1] + bo, dB + 1 * 4096 + wb); \
        gl16(xP[2] + ao, dA + 2 * 4096 + wb); gl16(hP[2] + bo, dB + 2 * 4096 + wb); \
        gl16(xP[3] + ao, dA + 3 * 4096 + wb); gl16(hP[3] + bo, dB + 3 * 4096 + wb); \
    } else { \
        const int ao = ((tt) - 8) * 128; \
        gl16(mP[0] + ao, dA + 0 * 4096 + wb); gl16(hP[0] + bo, dB + 0 * 4096 + wb); \
        gl16(mP[1] + ao, dA + 1 * 4096 + wb); gl16(hP[1] + bo, dB + 1 * 4096 + wb); \
        gl16(mP[2] + ao, dA + 2 * 4096 + wb); gl16(hP[2] + bo, dB + 2 * 4096 + wb); \
        gl16(mP[3] + ao, dA + 3 * 4096 + wb); gl16(hP[3] + bo, dB + 3 * 4096 + wb); \
    } \
} while (0)

    STAGE_GO(0, 0);
    STAGE_GO(1, 1);
    for (int kt = 0; kt < 16; ++kt) {
        if (kt < 15) PIPE_WAIT(8); else PIPE_WAIT(0);
        const h16* A = As[kt & 1];
        const h16* B = Bh[kt & 1];
        #pragma unroll
        for (int s = 0; s < 2; ++s) {
            const int c = s * 32 + ko;
            f16x8 a[4];
            #pragma unroll
            for (int fm = 0; fm < 4; ++fm)
                a[fm] = lds_frag(A, wm + fm * 16 + ln, c, kk);
            #pragma unroll
            for (int fn = 0; fn < 4; ++fn) {
                f16x8 vh = lds_frag(B, wn + fn * 16 + ln, c, kk);
                #pragma unroll
                for (int fm = 0; fm < 4; ++fm)
                    acc[fm][fn] = MFMA16(a[fm], vh, acc[fm][fn]);
            }
        }
        PIPE_POST();
        if (kt + 2 < 16) STAGE_GO(kt + 2, kt & 1);
    }
#undef STAGE_GO

    const int lm = (lane >> 4) * 4;
    #pragma unroll
    for (int fm = 0; fm < 4; ++fm) {
        #pragma unroll
        for (int fn = 0; fn < 4; ++fn) {
            int n = bn + wn + fn * 16 + ln;
            float bias = bgo[n];
            #pragma unroll
            for (int i = 0; i < 4; ++i) {
                int m = bm + wm + fm * 16 + lm + i;
                float t = acc[fm][fn][i] + bias;
                float g = 0.5f * t * (1.0f + erff(t * 0.70710678118654752f));
                int nsw = (((n >> 3) ^ (m & 7)) << 3) | (n & 7);
                yh[(size_t)m * DM + nsw] = (h16)g;
            }
        }
    }
}

// ---------------------------------------------------------------------------
// GEMM3: [M2 x 512] x [512 x 1024(packed 2 groups)] + GLU -> out (fp32).
// Double-buffered issue-early pipeline.
// ---------------------------------------------------------------------------
__global__ __launch_bounds__(256) WAVES_EU(2, 2) void gemm_out_mfma(
    const h16* __restrict__ yh, const h16* __restrict__ Wh,
    const float* __restrict__ bout, float* __restrict__ out)
{
    __shared__ __align__(16) h16 As[2][128 * 64];
    __shared__ __align__(16) h16 Bh[2][128 * 64];

    int bx, by; xcd_remap(bx, by);
    const int tid = threadIdx.x, lane = tid & 63, w = tid >> 6;
    const int wm = (w & 1) * 64, wn = (w >> 1) * 64;
    const int bm = bx * 128;
    const int ln = lane & 15, ko = (lane >> 4) * 8;
    const int kk = ln & 7;
    const int wb = w * 1024;

    const char *aP[4], *hP[4];
    {
        const int r8 = lane >> 3, c16 = (lane & 7) * 16;
        #pragma unroll
        for (int i = 0; i < 4; ++i) {
            int row = i * 32 + w * 8 + r8;
            aP[i] = (const char*)yh + (size_t)(bm + row) * (DM * 2) + c16;
            size_t br = (size_t)(by * 128 + row) * (DM * 2) + c16;
            hP[i] = (const char*)Wh + br;
        }
    }

    f32x4 acc[4][4];
    #pragma unroll
    for (int i = 0; i < 4; ++i)
        #pragma unroll
        for (int j = 0; j < 4; ++j) acc[i][j] = (f32x4){0.f, 0.f, 0.f, 0.f};

#define STAGE_OUT(koff, sel) do { \
    char* dA = (char*)As[sel]; char* dB = (char*)Bh[sel]; \
    gl16(aP[0] + (koff), dA + 0 * 4096 + wb); gl16(hP[0] + (koff), dB + 0 * 4096 + wb); \
    gl16(aP[1] + (koff), dA + 1 * 4096 + wb); gl16(hP[1] + (koff), dB + 1 * 4096 + wb); \
    gl16(aP[2] + (koff), dA + 2 * 4096 + wb); gl16(hP[2] + (koff), dB + 2 * 4096 + wb); \
    gl16(aP[3] + (koff), dA + 3 * 4096 + wb); gl16(hP[3] + (koff), dB + 3 * 4096 + wb); \
} while (0)

    STAGE_OUT(0, 0);
    STAGE_OUT(128, 1);
    for (int kt = 0; kt < 8; ++kt) {
        if (kt < 7) PIPE_WAIT(8); else PIPE_WAIT(0);
        const h16* A = As[kt & 1];
        const h16* B = Bh[kt & 1];
        #pragma unroll
        for (int s = 0; s < 2; ++s) {
            const int c = s * 32 + ko;
            f16x8 a[4];
            #pragma unroll
            for (int fm = 0; fm < 4; ++fm)
                a[fm] = lds_frag(A, wm + fm * 16 + ln, c, kk);
            #pragma unroll
            for (int fn = 0; fn < 4; ++fn) {
                f16x8 vh = lds_frag(B, wn + fn * 16 + ln, c, kk);
                #pragma unroll
                for (int fm = 0; fm < 4; ++fm)
                    acc[fm][fn] = MFMA16(a[fm], vh, acc[fm][fn]);
            }
        }
        PIPE_POST();
        if (kt + 2 < 8) STAGE_OUT((kt + 2) * 128, kt & 1);
    }
#undef STAGE_OUT

    const int lm = (lane >> 4) * 4;
    #pragma unroll
    for (int fm = 0; fm < 4; ++fm) {
        #pragma unroll
        for (int cp = 0; cp < 2; ++cp) {
            int ncol = by * 64 + ((wn >> 5) + cp) * 16 + ln;
            float bz0 = bout[ncol], bz1 = bout[ncol + 512];
            #pragma unroll
            for (int i = 0; i < 4; ++i) {
                int m = bm + wm + fm * 16 + lm + i;
                float z0 = acc[fm][cp * 2 + 0][i] + bz0;
                float z1 = acc[fm][cp * 2 + 1][i] + bz1;
                out[(size_t)m * DM + ncol] = z0 * (1.0f / (1.0f + expf(-z1)));
            }
        }
    }
}

// ---------------------------------------------------------------------------
extern "C" void kernel_launch(void* const* d_in, const int* in_sizes, int n_in,
                              void* d_out, int out_size, void* d_ws, size_t ws_size,
                              hipStream_t stream)
{
    const float* x    = (const float*)d_in[0];
    const float* Wav  = (const float*)d_in[1];
    const float* bav  = (const float*)d_in[2];
    const float* Wgo  = (const float*)d_in[3];
    const float* bgo  = (const float*)d_in[4];
    const float* Wout = (const float*)d_in[5];
    const float* bout = (const float*)d_in[6];
    float* out = (float*)d_out;

    char* ws = (char*)d_ws;
    const size_t MB = 1 << 20;
    h16*   ms_inp = (h16*)ws;                     // 32 MiB [32764,512] fp16
    h16*   yh     = (h16*)(ws + 32 * MB);         // 32 MiB (after scan)
    h16*   xh     = (h16*)(ws + 64 * MB);         // 32 MiB (swizzled fp16)
    h16*   msh    = (h16*)(ws + 96 * MB);         // 32 MiB (swizzled fp16)
    h16*   Wavh   = (h16*)(ws + 129 * MB);        // 2 MiB (packed+swizzled)
    h16*   Wgoh   = (h16*)(ws + 131 * MB);        // 1 MiB
    h16*   Wouth  = (h16*)(ws + 132 * MB);        // 1 MiB
    float* csum   = (float*)(ws + 133 * MB);      // 2 MiB [B][256][512] f32

    // 0) precompute fp16 forms (one launch)
    prep_all<<<9216, 256, 0, stream>>>(x, Wgo, Wav, Wout, xh, Wgoh, Wavh, Wouth);
    // 1) av GEMM + NRU combine -> ms_inp (fp16)
    gemm_av_mfma<<<dim3(256, 16), 256, 0, stream>>>(xh, Wavh, bav, ms_inp);
    // 2-4) chunked cumsum -> msh (fp16, swizzled)
    scan_pass1<<<dim3(64, B_SZ), 256, 0, stream>>>(ms_inp, csum);
    scan_pass2<<<2048, 256, 0, stream>>>(csum);
    scan_pass3<<<dim3(64, B_SZ), 256, 0, stream>>>(ms_inp, csum, msh);
    // 5) SSM-in GEMM + GELU -> yh (fp16 swizzled)
    gemm_go_mfma<<<dim3(256, 4), 256, 0, stream>>>(xh, msh, Wgoh, bgo, yh);
    // 6) output GEMM + GLU -> out (f32)
    gemm_out_mfma<<<dim3(256, 8), 256, 0, stream>>>(yh, Wouth, bout, out);
}

// Round 13
// 232.887 us; speedup vs baseline: 4.1124x; 1.0021x over previous
//
#include <hip/hip_runtime.h>
#include <hip/hip_bf16.h>
#include <math.h>

// Problem constants
#define B_SZ 4
#define L_SZ 8192
#define DM 512           // D_MODEL
#define DMEM 512         // D_MEM
#define M1 (B_SZ * (L_SZ - 1))   // 32764 rows for the av GEMM
#define M2 (B_SZ * L_SZ)         // 32768 rows for GEMM2/3

typedef _Float16 h16;
typedef __attribute__((ext_vector_type(2))) _Float16 f16x2;
typedef __attribute__((ext_vector_type(8))) _Float16 f16x8;
typedef __attribute__((ext_vector_type(4))) float f32x4;

#define MFMA16(a, b, c) __builtin_amdgcn_mfma_f32_16x16x32_f16((a), (b), (c), 0, 0, 0)
#define WAVES_EU(mn, mx) __attribute__((amdgpu_waves_per_eu(mn, mx)))

// async global->LDS, 16B per lane
__device__ __forceinline__ void gl16(const void* g, void* l) {
    __builtin_amdgcn_global_load_lds(
        (const __attribute__((address_space(1))) void*)g,
        (__attribute__((address_space(3))) void*)l, 16, 0, 0);
}

// Swizzled LDS fragment read from a [128 rows][64 cols] fp16 tile (128 B rows).
__device__ __forceinline__ f16x8 lds_frag(const h16* base, int row, int col, int key) {
    return *(const f16x8*)((const char*)base + row * 128 + ((col * 2) ^ (key << 4)));
}

// XCD swizzle, A-reuse-friendly decode (by fast -> weight panel L2-resident).
__device__ __forceinline__ void xcd_remap(int& bx, int& by) {
    int gx = gridDim.x, gy = gridDim.y;
    int nwg = gx * gy;
    int lin = blockIdx.y * gx + blockIdx.x;
    int chunk = nwg >> 3;
    int l = (lin & 7) * chunk + (lin >> 3);
    by = l % gy;
    bx = l / gy;
}

// ---------------------------------------------------------------------------
// Merged precompute: x conv + all weight packs in ONE launch.
//   i in [0, 2097152):            x [32768][512] -> xh (fp16, row-swizzled)
//   j = i - 2097152:
//     j in [0, 65536):            Wgo [512][1024] row-swizzle
//     j in [65536, 196608):       Wav pack P = by*256 + c*64 + g*16 + nl
//                                 (orig = g*512 + by*64 + c*16 + nl) for 256-wide tiles
//     j in [196608, 262144):      Wout pack P = by*128 + (chunk*32 + g*16 + nl)
// ---------------------------------------------------------------------------
__global__ __launch_bounds__(256) void prep_all(
    const float* __restrict__ x, const float* __restrict__ Wgo,
    const float* __restrict__ Wav, const float* __restrict__ Wout,
    h16* __restrict__ xh, h16* __restrict__ Wgoh,
    h16* __restrict__ Wavh, h16* __restrict__ Wouth)
{
    int i = blockIdx.x * 256 + threadIdx.x;
    const float* s;
    h16* d;
    if (i < 2097152) {               // x
        int m = i >> 6, bb = i & 63;
        s = x + (size_t)m * 512 + bb * 8;
        d = xh + (size_t)m * 512 + (bb ^ (m & 7)) * 8;
    } else {
        int j = i - 2097152;
        if (j < 65536) {             // Wgo
            int r = j >> 7, bb = j & 127;
            s = Wgo + (size_t)r * 1024 + bb * 8;
            d = Wgoh + (size_t)r * 1024 + (bb ^ (r & 7)) * 8;
        } else if (j < 196608) {     // Wav (256-wide packed tiles)
            int k = j - 65536;
            int P = k >> 6, bb = k & 63;
            int by = P >> 8, lo = P & 255;
            int c = lo >> 6, g = (lo >> 4) & 3, nl = lo & 15;
            int orig = g * 512 + by * 64 + c * 16 + nl;
            s = Wav + (size_t)orig * 512 + bb * 8;
            d = Wavh + (size_t)P * 512 + (bb ^ (P & 7)) * 8;
        } else {                     // Wout
            int k = j - 196608;
            int P = k >> 6, bb = k & 63;
            int by = P >> 7, lo = P & 127;
            int chunk = lo >> 5, g = (lo >> 4) & 1, nl = lo & 15;
            int orig = g * 512 + by * 64 + chunk * 16 + nl;
            s = Wout + (size_t)orig * 512 + bb * 8;
            d = Wouth + (size_t)P * 512 + (bb ^ (P & 7)) * 8;
        }
    }
    const float4* sv = (const float4*)s;
    float4 v0 = sv[0], v1 = sv[1];
    float vv[8] = {v0.x, v0.y, v0.z, v0.w, v1.x, v1.y, v1.z, v1.w};
    f16x8 hh;
    #pragma unroll
    for (int j = 0; j < 8; ++j) hh[j] = (h16)vv[j];
    *(f16x8*)d = hh;
}

// Pipeline sync helpers (raw barrier keeps prefetch alive)
#define PIPE_WAIT(N) do { \
    asm volatile("s_waitcnt vmcnt(" #N ")" ::: "memory"); \
    __builtin_amdgcn_s_barrier(); \
    asm volatile("" ::: "memory"); \
} while (0)
#define PIPE_POST() do { \
    __builtin_amdgcn_s_barrier(); \
    asm volatile("" ::: "memory"); \
} while (0)

// ---------------------------------------------------------------------------
// GEMM1: [M1 x 512] x [512 x 2048(packed 4 groups)] + NRU combine -> ms_inp
// (fp16). 256x256(packed) tile, BK=64, 8 waves (2Mx4N), counted-vmcnt
// pipeline (8 loads in flight across barriers), 128 KB LDS, 1 block/CU.
// ---------------------------------------------------------------------------
__global__ __launch_bounds__(512) WAVES_EU(2, 2) void gemm_av_mfma(
    const h16* __restrict__ xh, const h16* __restrict__ Wh,
    const float* __restrict__ bav, h16* __restrict__ ms_inp)
{
    __shared__ __align__(16) h16 As[2][2][128 * 64];   // [dbuf][half] 64 KB
    __shared__ __align__(16) h16 Bs[2][2][128 * 64];   // 64 KB

    int bx, by; xcd_remap(bx, by);                     // grid (128, 8)
    const int tid = threadIdx.x, lane = tid & 63, w = tid >> 6;
    const int wr = w >> 2;              // 0..1  (M half)
    const int wc = w & 3;               // 0..3  (N chunk)
    const int bm = bx * 256;
    const int ln = lane & 15, ko = (lane >> 4) * 8;
    const int kb = ln & 7;
    const int bhalf = wc >> 1;          // B half this wave reads
    const int brow0 = (wc & 1) * 64;    // row offset within that half

    // staging sources: per (half, i): thread covers row (h*128 + i*64 + tid>>3),
    // 16B block (tid&7). Memory is pre-swizzled; BK=64 tile = one 8-block
    // granule per row -> stage granule-linearly, swizzle applied at read.
    const char *aS[2][2], *bS[2][2];
    {
        const int r = tid >> 3, cb = tid & 7;
        #pragma unroll
        for (int h = 0; h < 2; ++h)
            #pragma unroll
            for (int i = 0; i < 2; ++i) {
                int row = h * 128 + i * 64 + r;
                int mg = bm + row; if (mg > M1 - 1) mg = M1 - 1;
                size_t xr = (size_t)mg + (unsigned)mg / (L_SZ - 1);
                aS[h][i] = (const char*)xh + xr * 1024 + cb * 16;
                int P = by * 256 + row;
                bS[h][i] = (const char*)Wh + (size_t)P * 1024 + cb * 16;
            }
    }
    // A fragment swizzle keys (memory-row & 7), 8 fm values
    int ka[8];
    #pragma unroll
    for (int fm = 0; fm < 8; ++fm) {
        int m = bm + wr * 128 + fm * 16 + ln;
        int mg = m > M1 - 1 ? M1 - 1 : m;
        ka[fm] = (int)((mg + (unsigned)mg / (L_SZ - 1)) & 7);
    }

    f32x4 acc[8][4];
    #pragma unroll
    for (int i = 0; i < 8; ++i)
        #pragma unroll
        for (int j = 0; j < 4; ++j) acc[i][j] = (f32x4){0.f, 0.f, 0.f, 0.f};

    // stage one tile (all 4 halves, 8 gl16/thread) into dbuf dd
#define STAGE_T(dd, koff) do { \
    char* lA = (char*)As + (dd) * 32768 + w * 1024; \
    char* lB = (char*)Bs + (dd) * 32768 + w * 1024; \
    gl16(aS[0][0] + (koff), lA);                 gl16(bS[0][0] + (koff), lB); \
    gl16(aS[0][1] + (koff), lA + 8192);          gl16(bS[0][1] + (koff), lB + 8192); \
    gl16(aS[1][0] + (koff), lA + 16384);         gl16(bS[1][0] + (koff), lB + 16384); \
    gl16(aS[1][1] + (koff), lA + 24576);         gl16(bS[1][1] + (koff), lB + 24576); \
} while (0)

    STAGE_T(0, 0);                      // prologue: tile 0
    for (int t = 0; t < 8; ++t) {
        const int d = t & 1;
        // boundary: all waves done reading dbuf d^1 (tile t-1) -> safe to stage
        __builtin_amdgcn_s_barrier();
        asm volatile("" ::: "memory");
        if (t < 7) {
            STAGE_T(d ^ 1, (t + 1) * 128);
            asm volatile("s_waitcnt vmcnt(8)" ::: "memory");   // own tile-t loads landed
        } else {
            asm volatile("s_waitcnt vmcnt(0)" ::: "memory");
        }
        __builtin_amdgcn_s_barrier();   // collective: all waves' tile-t pieces landed
        asm volatile("" ::: "memory");

        const h16* A = &As[d][wr][0];
        const h16* B = &Bs[d][bhalf][0];
        // b-frags for the whole tile (4 fn x 2 ks)
        f16x8 bf[4][2];
        #pragma unroll
        for (int fn = 0; fn < 4; ++fn)
            #pragma unroll
            for (int ks = 0; ks < 2; ++ks)
                bf[fn][ks] = lds_frag(B, brow0 + fn * 16 + ln, ks * 32 + ko, kb);
        // 4 phases: 2 fm each, 16 MFMA per phase
        #pragma unroll
        for (int p = 0; p < 4; ++p) {
            f16x8 a[2][2];
            #pragma unroll
            for (int j = 0; j < 2; ++j)
                #pragma unroll
                for (int ks = 0; ks < 2; ++ks)
                    a[j][ks] = lds_frag(A, (2 * p + j) * 16 + ln, ks * 32 + ko, ka[2 * p + j]);
            __builtin_amdgcn_s_setprio(1);
            #pragma unroll
            for (int j = 0; j < 2; ++j)
                #pragma unroll
                for (int fn = 0; fn < 4; ++fn)
                    #pragma unroll
                    for (int ks = 0; ks < 2; ++ks)
                        acc[2 * p + j][fn] = MFMA16(a[j][ks], bf[fn][ks], acc[2 * p + j][fn]);
            __builtin_amdgcn_s_setprio(0);
            __builtin_amdgcn_sched_barrier(0);
        }
    }
#undef STAGE_T

    // epilogue: fn = group; combine in-register; write fp16
    const int lm = (lane >> 4) * 4;
    const int nn = by * 64 + wc * 16 + ln;
    const float b0 = bav[nn], b1 = bav[nn + 512], b2 = bav[nn + 1024], b3 = bav[nn + 1536];
    #pragma unroll
    for (int fm = 0; fm < 8; ++fm) {
        #pragma unroll
        for (int i = 0; i < 4; ++i) {
            int m = bm + wr * 128 + fm * 16 + lm + i;
            if (m < M1) {
                float a0 = acc[fm][0][i] + b0;
                float a1 = acc[fm][1][i] + b1;
                float a2 = acc[fm][2][i] + b2;
                float a3 = acc[fm][3][i] + b3;
                ms_inp[(size_t)m * DMEM + nn] = (h16)(a0 * a1 - a2 * a3);
            }
        }
    }
}

// ---------------------------------------------------------------------------
// Chunked cumsum over fp16 ms_inp (fp32 accumulation). Chunk = 32 rows.
// ---------------------------------------------------------------------------
__global__ __launch_bounds__(256) void scan_pass1(
    const h16* __restrict__ ms_inp, float* __restrict__ csum)
{
    int b = blockIdx.y;
    int c = blockIdx.x * 4 + (threadIdx.x >> 6);    // 0..255
    int t = threadIdx.x & 63;
    int l0 = c * 32;
    int len = min(32, (L_SZ - 1) - l0);
    const h16* p = ms_inp + ((size_t)b * (L_SZ - 1) + l0) * DMEM + t * 8;
    float s[8] = {0.f, 0.f, 0.f, 0.f, 0.f, 0.f, 0.f, 0.f};
    for (int i = 0; i < len; ++i) {
        f16x8 v = *(const f16x8*)(p + (size_t)i * DMEM);
        #pragma unroll
        for (int j = 0; j < 8; ++j) s[j] += (float)v[j];
    }
    float* q = csum + ((size_t)b * 256 + c) * DMEM + t * 8;
    *(float4*)q       = make_float4(s[0], s[1], s[2], s[3]);
    *(float4*)(q + 4) = make_float4(s[4], s[5], s[6], s[7]);
}

__global__ __launch_bounds__(256) void scan_pass2(float* __restrict__ csum)
{
    __shared__ float wsum[4];
    int b = blockIdx.x >> 9, d = blockIdx.x & 511;
    int t = threadIdx.x, lane = t & 63, wv = t >> 6;
    float* p = csum + (size_t)b * 256 * DMEM + d;
    float v = p[(size_t)t * DMEM];
    #pragma unroll
    for (int off = 1; off < 64; off <<= 1) {
        float u = __shfl_up(v, off, 64);
        if (lane >= off) v += u;
    }
    if (lane == 63) wsum[wv] = v;
    __syncthreads();
    float add = 0.f;
    #pragma unroll
    for (int i = 0; i < 4; ++i) if (i < wv) add += wsum[i];
    v += add;
    float ex = __shfl_up(v, 1, 64);
    if (lane == 0) ex = add;
    p[(size_t)t * DMEM] = ex;
}

__global__ __launch_bounds__(256) void scan_pass3(
    const h16* __restrict__ ms_inp, const float* __restrict__ csum,
    h16* __restrict__ msh)
{
    int b = blockIdx.y;
    int c = blockIdx.x * 4 + (threadIdx.x >> 6);
    int t = threadIdx.x & 63;
    int l0 = c * 32;
    int len = min(32, (L_SZ - 1) - l0);
    const float* q = csum + ((size_t)b * 256 + c) * DMEM + t * 8;
    float run[8];
    #pragma unroll
    for (int j = 0; j < 8; ++j) run[j] = q[j];
    const h16* p = ms_inp + ((size_t)b * (L_SZ - 1) + l0) * DMEM + t * 8;
    if (c == 0) {
        f16x8 z = {};
        *(f16x8*)(msh + (size_t)b * L_SZ * DMEM + t * 8) = z;
    }
    for (int i = 0; i < len; ++i) {
        f16x8 v = *(const f16x8*)(p + (size_t)i * DMEM);
        f16x8 o;
        #pragma unroll
        for (int j = 0; j < 8; ++j) { run[j] += (float)v[j]; o[j] = (h16)run[j]; }
        int m = b * L_SZ + l0 + 1 + i;
        int db = t ^ (m & 7);
        *(f16x8*)(msh + (size_t)m * DMEM + db * 8) = o;
    }
}

// ---------------------------------------------------------------------------
// GEMM2: [M2 x 1024 (x||ms)] x [1024 x 512] + GELU -> yh (fp16, swizzled).
// Double-buffered issue-early pipeline (r11 structure, unchanged).
// ---------------------------------------------------------------------------
__global__ __launch_bounds__(256) WAVES_EU(2, 2) void gemm_go_mfma(
    const h16* __restrict__ xh, const h16* __restrict__ msh,
    const h16* __restrict__ Wh,
    const float* __restrict__ bgo, h16* __restrict__ yh)
{
    __shared__ __align__(16) h16 As[2][128 * 64];
    __shared__ __align__(16) h16 Bh[2][128 * 64];

    int bx, by; xcd_remap(bx, by);
    const int tid = threadIdx.x, lane = tid & 63, w = tid >> 6;
    const int wm = (w & 1) * 64, wn = (w >> 1) * 64;
    const int bm = bx * 128, bn = by * 128;
    const int ln = lane & 15, ko = (lane >> 4) * 8;
    const int kk = ln & 7;
    const int wb = w * 1024;

    const char *xP[4], *mP[4], *hP[4];
    {
        const int r8 = lane >> 3, c16 = (lane & 7) * 16;
        #pragma unroll
        for (int i = 0; i < 4; ++i) {
            int row = i * 32 + w * 8 + r8;
            size_t ar = (size_t)(bm + row) * (DM * 2) + c16;
            xP[i] = (const char*)xh + ar;
            mP[i] = (const char*)msh + ar;
            size_t br = (size_t)(bn + row) * (2 * DM * 2) + c16;
            hP[i] = (const char*)Wh + br;
        }
    }

    f32x4 acc[4][4];
    #pragma unroll
    for (int i = 0; i < 4; ++i)
        #pragma unroll
        for (int j = 0; j < 4; ++j) acc[i][j] = (f32x4){0.f, 0.f, 0.f, 0.f};

#define STAGE_GO(tt, sel) do { \
    char* dA = (char*)As[sel]; char* dB = (char*)Bh[sel]; \
    const int bo = (tt) * 128; \
    if ((tt) < 8) { \
        const int ao = (tt) * 128; \
        gl16(xP[0] + ao, dA + 0 * 4096 + wb); gl16(hP[0] + bo, dB + 0 * 4096 + wb); \
        gl16(xP[1] + ao, dA + 1 * 4096 + wb); gl16(hP[1] + bo, dB + 1 * 4096 + wb); \
        gl16(xP[2] + ao, dA + 2 * 4096 + wb); gl16(hP[2] + bo, dB + 2 * 4096 + wb); \
        gl16(xP[3] + ao, dA + 3 * 4096 + wb); gl16(hP[3] + bo, dB + 3 * 4096 + wb); \
    } else { \
        const int ao = ((tt) - 8) * 128; \
        gl16(mP[0] + ao, dA + 0 * 4096 + wb); gl16(hP[0] + bo, dB + 0 * 4096 + wb); \
        gl16(mP[1] + ao, dA + 1 * 4096 + wb); gl16(hP[1] + bo, dB + 1 * 4096 + wb); \
        gl16(mP[2] + ao, dA + 2 * 4096 + wb); gl16(hP[2] + bo, dB + 2 * 4096 + wb); \
        gl16(mP[3] + ao, dA + 3 * 4096 + wb); gl16(hP[3] + bo, dB + 3 * 4096 + wb); \
    } \
} while (0)

    STAGE_GO(0, 0);
    STAGE_GO(1, 1);
    for (int kt = 0; kt < 16; ++kt) {
        if (kt < 15) PIPE_WAIT(8); else PIPE_WAIT(0);
        const h16* A = As[kt & 1];
        const h16* B = Bh[kt & 1];
        #pragma unroll
        for (int s = 0; s < 2; ++s) {
            const int c = s * 32 + ko;
            f16x8 a[4];
            #pragma unroll
            for (int fm = 0; fm < 4; ++fm)
                a[fm] = lds_frag(A, wm + fm * 16 + ln, c, kk);
            #pragma unroll
            for (int fn = 0; fn < 4; ++fn) {
                f16x8 vh = lds_frag(B, wn + fn * 16 + ln, c, kk);
                #pragma unroll
                for (int fm = 0; fm < 4; ++fm)
                    acc[fm][fn] = MFMA16(a[fm], vh, acc[fm][fn]);
            }
        }
        PIPE_POST();
        if (kt + 2 < 16) STAGE_GO(kt + 2, kt & 1);
    }
#undef STAGE_GO

    const int lm = (lane >> 4) * 4;
    #pragma unroll
    for (int fm = 0; fm < 4; ++fm) {
        #pragma unroll
        for (int fn = 0; fn < 4; ++fn) {
            int n = bn + wn + fn * 16 + ln;
            float bias = bgo[n];
            #pragma unroll
            for (int i = 0; i < 4; ++i) {
                int m = bm + wm + fm * 16 + lm + i;
                float t = acc[fm][fn][i] + bias;
                float g = 0.5f * t * (1.0f + erff(t * 0.70710678118654752f));
                int nsw = (((n >> 3) ^ (m & 7)) << 3) | (n & 7);
                yh[(size_t)m * DM + nsw] = (h16)g;
            }
        }
    }
}

// ---------------------------------------------------------------------------
// GEMM3: [M2 x 512] x [512 x 1024(packed 2 groups)] + GLU -> out (fp32).
// Double-buffered issue-early pipeline (r11 structure, unchanged).
// ---------------------------------------------------------------------------
__global__ __launch_bounds__(256) WAVES_EU(2, 2) void gemm_out_mfma(
    const h16* __restrict__ yh, const h16* __restrict__ Wh,
    const float* __restrict__ bout, float* __restrict__ out)
{
    __shared__ __align__(16) h16 As[2][128 * 64];
    __shared__ __align__(16) h16 Bh[2][128 * 64];

    int bx, by; xcd_remap(bx, by);
    const int tid = threadIdx.x, lane = tid & 63, w = tid >> 6;
    const int wm = (w & 1) * 64, wn = (w >> 1) * 64;
    const int bm = bx * 128;
    const int ln = lane & 15, ko = (lane >> 4) * 8;
    const int kk = ln & 7;
    const int wb = w * 1024;

    const char *aP[4], *hP[4];
    {
        const int r8 = lane >> 3, c16 = (lane & 7) * 16;
        #pragma unroll
        for (int i = 0; i < 4; ++i) {
            int row = i * 32 + w * 8 + r8;
            aP[i] = (const char*)yh + (size_t)(bm + row) * (DM * 2) + c16;
            size_t br = (size_t)(by * 128 + row) * (DM * 2) + c16;
            hP[i] = (const char*)Wh + br;
        }
    }

    f32x4 acc[4][4];
    #pragma unroll
    for (int i = 0; i < 4; ++i)
        #pragma unroll
        for (int j = 0; j < 4; ++j) acc[i][j] = (f32x4){0.f, 0.f, 0.f, 0.f};

#define STAGE_OUT(koff, sel) do { \
    char* dA = (char*)As[sel]; char* dB = (char*)Bh[sel]; \
    gl16(aP[0] + (koff), dA + 0 * 4096 + wb); gl16(hP[0] + (koff), dB + 0 * 4096 + wb); \
    gl16(aP[1] + (koff), dA + 1 * 4096 + wb); gl16(hP[1] + (koff), dB + 1 * 4096 + wb); \
    gl16(aP[2] + (koff), dA + 2 * 4096 + wb); gl16(hP[2] + (koff), dB + 2 * 4096 + wb); \
    gl16(aP[3] + (koff), dA + 3 * 4096 + wb); gl16(hP[3] + (koff), dB + 3 * 4096 + wb); \
} while (0)

    STAGE_OUT(0, 0);
    STAGE_OUT(128, 1);
    for (int kt = 0; kt < 8; ++kt) {
        if (kt < 7) PIPE_WAIT(8); else PIPE_WAIT(0);
        const h16* A = As[kt & 1];
        const h16* B = Bh[kt & 1];
        #pragma unroll
        for (int s = 0; s < 2; ++s) {
            const int c = s * 32 + ko;
            f16x8 a[4];
            #pragma unroll
            for (int fm = 0; fm < 4; ++fm)
                a[fm] = lds_frag(A, wm + fm * 16 + ln, c, kk);
            #pragma unroll
            for (int fn = 0; fn < 4; ++fn) {
                f16x8 vh = lds_frag(B, wn + fn * 16 + ln, c, kk);
                #pragma unroll
                for (int fm = 0; fm < 4; ++fm)
                    acc[fm][fn] = MFMA16(a[fm], vh, acc[fm][fn]);
            }
        }
        PIPE_POST();
        if (kt + 2 < 8) STAGE_OUT((kt + 2) * 128, kt & 1);
    }
#undef STAGE_OUT

    const int lm = (lane >> 4) * 4;
    #pragma unroll
    for (int fm = 0; fm < 4; ++fm) {
        #pragma unroll
        for (int cp = 0; cp < 2; ++cp) {
            int ncol = by * 64 + ((wn >> 5) + cp) * 16 + ln;
            float bz0 = bout[ncol], bz1 = bout[ncol + 512];
            #pragma unroll
            for (int i = 0; i < 4; ++i) {
                int m = bm + wm + fm * 16 + lm + i;
                float z0 = acc[fm][cp * 2 + 0][i] + bz0;
                float z1 = acc[fm][cp * 2 + 1][i] + bz1;
                out[(size_t)m * DM + ncol] = z0 * (1.0f / (1.0f + expf(-z1)));
            }
        }
    }
}

// ---------------------------------------------------------------------------
extern "C" void kernel_launch(void* const* d_in, const int* in_sizes, int n_in,
                              void* d_out, int out_size, void* d_ws, size_t ws_size,
                              hipStream_t stream)
{
    const float* x    = (const float*)d_in[0];
    const float* Wav  = (const float*)d_in[1];
    const float* bav  = (const float*)d_in[2];
    const float* Wgo  = (const float*)d_in[3];
    const float* bgo  = (const float*)d_in[4];
    const float* Wout = (const float*)d_in[5];
    const float* bout = (const float*)d_in[6];
    float* out = (float*)d_out;

    char* ws = (char*)d_ws;
    const size_t MB = 1 << 20;
    h16*   ms_inp = (h16*)ws;                     // 32 MiB [32764,512] fp16
    h16*   yh     = (h16*)(ws + 32 * MB);         // 32 MiB (after scan)
    h16*   xh     = (h16*)(ws + 64 * MB);         // 32 MiB (swizzled fp16)
    h16*   msh    = (h16*)(ws + 96 * MB);         // 32 MiB (swizzled fp16)
    h16*   Wavh   = (h16*)(ws + 129 * MB);        // 2 MiB (packed+swizzled)
    h16*   Wgoh   = (h16*)(ws + 131 * MB);        // 1 MiB
    h16*   Wouth  = (h16*)(ws + 132 * MB);        // 1 MiB
    float* csum   = (float*)(ws + 133 * MB);      // 2 MiB [B][256][512] f32

    // 0) precompute fp16 forms (one launch)
    prep_all<<<9216, 256, 0, stream>>>(x, Wgo, Wav, Wout, xh, Wgoh, Wavh, Wouth);
    // 1) av GEMM + NRU combine -> ms_inp (fp16); 256^2 counted-vmcnt pipeline
    gemm_av_mfma<<<dim3(128, 8), 512, 0, stream>>>(xh, Wavh, bav, ms_inp);
    // 2-4) chunked cumsum -> msh (fp16, swizzled)
    scan_pass1<<<dim3(64, B_SZ), 256, 0, stream>>>(ms_inp, csum);
    scan_pass2<<<2048, 256, 0, stream>>>(csum);
    scan_pass3<<<dim3(64, B_SZ), 256, 0, stream>>>(ms_inp, csum, msh);
    // 5) SSM-in GEMM + GELU -> yh (fp16 swizzled)
    gemm_go_mfma<<<dim3(256, 4), 256, 0, stream>>>(xh, msh, Wgoh, bgo, yh);
    // 6) output GEMM + GLU -> out (f32)
    gemm_out_mfma<<<dim3(256, 8), 256, 0, stream>>>(yh, Wouth, bout, out);
}

// Round 14
// 229.343 us; speedup vs baseline: 4.1760x; 1.0154x over previous
//
#include <hip/hip_runtime.h>
#include <hip/hip_bf16.h>
#include <math.h>

// Problem constants
#define B_SZ 4
#define L_SZ 8192
#define DM 512           // D_MODEL
#define DMEM 512         // D_MEM
#define M1 (B_SZ * (L_SZ - 1))   // 32764 rows for the av GEMM
#define M2 (B_SZ * L_SZ)         // 32768 rows for GEMM2/3

typedef _Float16 h16;
typedef __attribute__((ext_vector_type(2))) _Float16 f16x2;
typedef __attribute__((ext_vector_type(8))) _Float16 f16x8;
typedef __attribute__((ext_vector_type(4))) float f32x4;

#define MFMA16(a, b, c) __builtin_amdgcn_mfma_f32_16x16x32_f16((a), (b), (c), 0, 0, 0)
#define WAVES_EU(mn, mx) __attribute__((amdgpu_waves_per_eu(mn, mx)))

// async global->LDS, 16B per lane
__device__ __forceinline__ void gl16(const void* g, void* l) {
    __builtin_amdgcn_global_load_lds(
        (const __attribute__((address_space(1))) void*)g,
        (__attribute__((address_space(3))) void*)l, 16, 0, 0);
}

// Swizzled LDS fragment read from a [128 rows][64 cols] fp16 tile (128 B rows).
__device__ __forceinline__ f16x8 lds_frag(const h16* base, int row, int col, int key) {
    return *(const f16x8*)((const char*)base + row * 128 + ((col * 2) ^ (key << 4)));
}

// XCD swizzle, A-reuse-friendly decode (by fast -> weight panel L2-resident).
__device__ __forceinline__ void xcd_remap(int& bx, int& by) {
    int gx = gridDim.x, gy = gridDim.y;
    int nwg = gx * gy;
    int lin = blockIdx.y * gx + blockIdx.x;
    int chunk = nwg >> 3;
    int l = (lin & 7) * chunk + (lin >> 3);
    by = l % gy;
    bx = l / gy;
}

// ---------------------------------------------------------------------------
// Merged precompute: x conv + all weight packs in ONE launch.
//   i in [0, 2097152):            x [32768][512] -> xh (fp16, row-swizzled)
//   j = i - 2097152:
//     j in [0, 65536):            Wgo [512][1024] row-swizzle
//     j in [65536, 196608):       Wav pack P = by*128 + (half*64 + g*16 + nl)
//     j in [196608, 262144):      Wout pack P = by*128 + (chunk*32 + g*16 + nl)
// ---------------------------------------------------------------------------
__global__ __launch_bounds__(256) void prep_all(
    const float* __restrict__ x, const float* __restrict__ Wgo,
    const float* __restrict__ Wav, const float* __restrict__ Wout,
    h16* __restrict__ xh, h16* __restrict__ Wgoh,
    h16* __restrict__ Wavh, h16* __restrict__ Wouth)
{
    int i = blockIdx.x * 256 + threadIdx.x;
    const float* s;
    h16* d;
    if (i < 2097152) {               // x
        int m = i >> 6, bb = i & 63;
        s = x + (size_t)m * 512 + bb * 8;
        d = xh + (size_t)m * 512 + (bb ^ (m & 7)) * 8;
    } else {
        int j = i - 2097152;
        if (j < 65536) {             // Wgo
            int r = j >> 7, bb = j & 127;
            s = Wgo + (size_t)r * 1024 + bb * 8;
            d = Wgoh + (size_t)r * 1024 + (bb ^ (r & 7)) * 8;
        } else if (j < 196608) {     // Wav
            int k = j - 65536;
            int P = k >> 6, bb = k & 63;
            int by = P >> 7, lo = P & 127;
            int half = lo >> 6, g = (lo >> 4) & 3, nl = lo & 15;
            int orig = g * 512 + by * 32 + half * 16 + nl;
            s = Wav + (size_t)orig * 512 + bb * 8;
            d = Wavh + (size_t)P * 512 + (bb ^ (P & 7)) * 8;
        } else {                     // Wout
            int k = j - 196608;
            int P = k >> 6, bb = k & 63;
            int by = P >> 7, lo = P & 127;
            int chunk = lo >> 5, g = (lo >> 4) & 1, nl = lo & 15;
            int orig = g * 512 + by * 64 + chunk * 16 + nl;
            s = Wout + (size_t)orig * 512 + bb * 8;
            d = Wouth + (size_t)P * 512 + (bb ^ (P & 7)) * 8;
        }
    }
    const float4* sv = (const float4*)s;
    float4 v0 = sv[0], v1 = sv[1];
    float vv[8] = {v0.x, v0.y, v0.z, v0.w, v1.x, v1.y, v1.z, v1.w};
    f16x8 hh;
    #pragma unroll
    for (int j = 0; j < 8; ++j) hh[j] = (h16)vv[j];
    *(f16x8*)d = hh;
}

// Pipeline sync helpers for the dbuf kernels (raw barrier keeps prefetch alive)
#define PIPE_WAIT(N) do { \
    asm volatile("s_waitcnt vmcnt(" #N ")" ::: "memory"); \
    __builtin_amdgcn_s_barrier(); \
    asm volatile("" ::: "memory"); \
} while (0)
#define PIPE_POST() do { \
    __builtin_amdgcn_s_barrier(); \
    asm volatile("" ::: "memory"); \
} while (0)

// ---------------------------------------------------------------------------
// GEMM1: [M1 x 512] x [512 x 2048(packed 4 groups)] + NRU combine -> ms_inp
// (fp16). Single-buffer 32KB (r11-proven). WAVES_EU(4,4): 4 blocks/CU for
// extra cross-block TLP to hide the per-tile vmcnt drain.
// ---------------------------------------------------------------------------
__global__ __launch_bounds__(256) WAVES_EU(4, 4) void gemm_av_mfma(
    const h16* __restrict__ xh, const h16* __restrict__ Wh,
    const float* __restrict__ bav, h16* __restrict__ ms_inp)
{
    __shared__ __align__(16) h16 As[128 * 64];   // 16 KB each
    __shared__ __align__(16) h16 Bh[128 * 64];

    int bx, by; xcd_remap(bx, by);
    const int tid = threadIdx.x, lane = tid & 63, w = tid >> 6;
    const int wm = (w & 1) * 64, wn = (w >> 1) * 64;
    const int bm = bx * 128;
    const int ln = lane & 15, ko = (lane >> 4) * 8;
    const int kb = ln & 7;
    char* lA = (char*)As; char* lH = (char*)Bh;
    const int wb = w * 1024;

    const char *aP[4], *hP[4];
    {
        const int r8 = lane >> 3, c16 = (lane & 7) * 16;
        #pragma unroll
        for (int i = 0; i < 4; ++i) {
            int row = i * 32 + w * 8 + r8;
            int mg = bm + row; if (mg > M1 - 1) mg = M1 - 1;
            size_t xr = (size_t)mg + (unsigned)mg / (L_SZ - 1);
            aP[i] = (const char*)xh + xr * (DM * 2) + c16;
            size_t br = (size_t)(by * 128 + row) * (DM * 2) + c16;
            hP[i] = (const char*)Wh + br;
        }
    }
    int ka[4];
    #pragma unroll
    for (int fm = 0; fm < 4; ++fm) {
        int m = bm + wm + fm * 16 + ln;
        int mg = m > M1 - 1 ? M1 - 1 : m;
        ka[fm] = (int)((mg + (unsigned)mg / (L_SZ - 1)) & 7);
    }

    f32x4 acc[4][4];
    #pragma unroll
    for (int i = 0; i < 4; ++i)
        #pragma unroll
        for (int j = 0; j < 4; ++j) acc[i][j] = (f32x4){0.f, 0.f, 0.f, 0.f};

#define STAGE_AV(koff) do { \
    gl16(aP[0] + (koff), lA + 0 * 4096 + wb); gl16(hP[0] + (koff), lH + 0 * 4096 + wb); \
    gl16(aP[1] + (koff), lA + 1 * 4096 + wb); gl16(hP[1] + (koff), lH + 1 * 4096 + wb); \
    gl16(aP[2] + (koff), lA + 2 * 4096 + wb); gl16(hP[2] + (koff), lH + 2 * 4096 + wb); \
    gl16(aP[3] + (koff), lA + 3 * 4096 + wb); gl16(hP[3] + (koff), lH + 3 * 4096 + wb); \
} while (0)

    STAGE_AV(0);
    for (int kt = 0; kt < 8; ++kt) {
        asm volatile("s_waitcnt vmcnt(0)" ::: "memory");
        __syncthreads();
        #pragma unroll
        for (int s = 0; s < 2; ++s) {
            const int c = s * 32 + ko;
            f16x8 a[4];
            #pragma unroll
            for (int fm = 0; fm < 4; ++fm)
                a[fm] = lds_frag(As, wm + fm * 16 + ln, c, ka[fm]);
            #pragma unroll
            for (int fn = 0; fn < 4; ++fn) {
                f16x8 vh = lds_frag(Bh, wn + fn * 16 + ln, c, kb);
                #pragma unroll
                for (int fm = 0; fm < 4; ++fm)
                    acc[fm][fn] = MFMA16(a[fm], vh, acc[fm][fn]);
            }
        }
        __syncthreads();
        if (kt < 7) STAGE_AV((kt + 1) * 128);
    }
#undef STAGE_AV

    // epilogue: fn = group; combine in-register; write fp16
    const int lm = (lane >> 4) * 4;
    const int nn = by * 32 + (wn >> 6) * 16 + ln;
    const float b0 = bav[nn], b1 = bav[nn + 512], b2 = bav[nn + 1024], b3 = bav[nn + 1536];
    #pragma unroll
    for (int fm = 0; fm < 4; ++fm) {
        #pragma unroll
        for (int i = 0; i < 4; ++i) {
            int m = bm + wm + fm * 16 + lm + i;
            if (m < M1) {
                float a0 = acc[fm][0][i] + b0;
                float a1 = acc[fm][1][i] + b1;
                float a2 = acc[fm][2][i] + b2;
                float a3 = acc[fm][3][i] + b3;
                ms_inp[(size_t)m * DMEM + nn] = (h16)(a0 * a1 - a2 * a3);
            }
        }
    }
}

// ---------------------------------------------------------------------------
// Chunked cumsum over fp16 ms_inp (fp32 accumulation). Chunk = 32 rows.
// ---------------------------------------------------------------------------
__global__ __launch_bounds__(256) void scan_pass1(
    const h16* __restrict__ ms_inp, float* __restrict__ csum)
{
    int b = blockIdx.y;
    int c = blockIdx.x * 4 + (threadIdx.x >> 6);    // 0..255
    int t = threadIdx.x & 63;
    int l0 = c * 32;
    int len = min(32, (L_SZ - 1) - l0);
    const h16* p = ms_inp + ((size_t)b * (L_SZ - 1) + l0) * DMEM + t * 8;
    float s[8] = {0.f, 0.f, 0.f, 0.f, 0.f, 0.f, 0.f, 0.f};
    for (int i = 0; i < len; ++i) {
        f16x8 v = *(const f16x8*)(p + (size_t)i * DMEM);
        #pragma unroll
        for (int j = 0; j < 8; ++j) s[j] += (float)v[j];
    }
    float* q = csum + ((size_t)b * 256 + c) * DMEM + t * 8;
    *(float4*)q       = make_float4(s[0], s[1], s[2], s[3]);
    *(float4*)(q + 4) = make_float4(s[4], s[5], s[6], s[7]);
}

__global__ __launch_bounds__(256) void scan_pass2(float* __restrict__ csum)
{
    __shared__ float wsum[4];
    int b = blockIdx.x >> 9, d = blockIdx.x & 511;
    int t = threadIdx.x, lane = t & 63, wv = t >> 6;
    float* p = csum + (size_t)b * 256 * DMEM + d;
    float v = p[(size_t)t * DMEM];
    #pragma unroll
    for (int off = 1; off < 64; off <<= 1) {
        float u = __shfl_up(v, off, 64);
        if (lane >= off) v += u;
    }
    if (lane == 63) wsum[wv] = v;
    __syncthreads();
    float add = 0.f;
    #pragma unroll
    for (int i = 0; i < 4; ++i) if (i < wv) add += wsum[i];
    v += add;
    float ex = __shfl_up(v, 1, 64);
    if (lane == 0) ex = add;
    p[(size_t)t * DMEM] = ex;
}

__global__ __launch_bounds__(256) void scan_pass3(
    const h16* __restrict__ ms_inp, const float* __restrict__ csum,
    h16* __restrict__ msh)
{
    int b = blockIdx.y;
    int c = blockIdx.x * 4 + (threadIdx.x >> 6);
    int t = threadIdx.x & 63;
    int l0 = c * 32;
    int len = min(32, (L_SZ - 1) - l0);
    const float* q = csum + ((size_t)b * 256 + c) * DMEM + t * 8;
    float run[8];
    #pragma unroll
    for (int j = 0; j < 8; ++j) run[j] = q[j];
    const h16* p = ms_inp + ((size_t)b * (L_SZ - 1) + l0) * DMEM + t * 8;
    if (c == 0) {
        f16x8 z = {};
        *(f16x8*)(msh + (size_t)b * L_SZ * DMEM + t * 8) = z;
    }
    for (int i = 0; i < len; ++i) {
        f16x8 v = *(const f16x8*)(p + (size_t)i * DMEM);
        f16x8 o;
        #pragma unroll
        for (int j = 0; j < 8; ++j) { run[j] += (float)v[j]; o[j] = (h16)run[j]; }
        int m = b * L_SZ + l0 + 1 + i;
        int db = t ^ (m & 7);
        *(f16x8*)(msh + (size_t)m * DMEM + db * 8) = o;
    }
}

// ---------------------------------------------------------------------------
// GEMM2: [M2 x 1024 (x||ms)] x [1024 x 512] + GELU -> yh (fp16, swizzled).
// Double-buffered issue-early pipeline.
// ---------------------------------------------------------------------------
__global__ __launch_bounds__(256) WAVES_EU(2, 2) void gemm_go_mfma(
    const h16* __restrict__ xh, const h16* __restrict__ msh,
    const h16* __restrict__ Wh,
    const float* __restrict__ bgo, h16* __restrict__ yh)
{
    __shared__ __align__(16) h16 As[2][128 * 64];
    __shared__ __align__(16) h16 Bh[2][128 * 64];

    int bx, by; xcd_remap(bx, by);
    const int tid = threadIdx.x, lane = tid & 63, w = tid >> 6;
    const int wm = (w & 1) * 64, wn = (w >> 1) * 64;
    const int bm = bx * 128, bn = by * 128;
    const int ln = lane & 15, ko = (lane >> 4) * 8;
    const int kk = ln & 7;
    const int wb = w * 1024;

    const char *xP[4], *mP[4], *hP[4];
    {
        const int r8 = lane >> 3, c16 = (lane & 7) * 16;
        #pragma unroll
        for (int i = 0; i < 4; ++i) {
            int row = i * 32 + w * 8 + r8;
            size_t ar = (size_t)(bm + row) * (DM * 2) + c16;
            xP[i] = (const char*)xh + ar;
            mP[i] = (const char*)msh + ar;
            size_t br = (size_t)(bn + row) * (2 * DM * 2) + c16;
            hP[i] = (const char*)Wh + br;
        }
    }

    f32x4 acc[4][4];
    #pragma unroll
    for (int i = 0; i < 4; ++i)
        #pragma unroll
        for (int j = 0; j < 4; ++j) acc[i][j] = (f32x4){0.f, 0.f, 0.f, 0.f};

#define STAGE_GO(tt, sel) do { \
    char* dA = (char*)As[sel]; char* dB = (char*)Bh[sel]; \
    const int bo = (tt) * 128; \
    if ((tt) < 8) { \
        const int ao = (tt) * 128; \
        gl16(xP[0] + ao, dA + 0 * 4096 + wb); gl16(hP[0] + bo, dB + 0 * 4096 + wb); \
        gl16(xP[1] + ao, dA + 1 * 4096 + wb); gl16(hP[1] + bo, dB + 1 * 4096 + wb); \
        gl16(xP[2] + ao, dA + 2 * 4096 + wb); gl16(hP[2] + bo, dB + 2 * 4096 + wb); \
        gl16(xP[3] + ao, dA + 3 * 4096 + wb); gl16(hP[3] + bo, dB + 3 * 4096 + wb); \
    } else { \
        const int ao = ((tt) - 8) * 128; \
        gl16(mP[0] + ao, dA + 0 * 4096 + wb); gl16(hP[0] + bo, dB + 0 * 4096 + wb); \
        gl16(mP[1] + ao, dA + 1 * 4096 + wb); gl16(hP[1] + bo, dB + 1 * 4096 + wb); \
        gl16(mP[2] + ao, dA + 2 * 4096 + wb); gl16(hP[2] + bo, dB + 2 * 4096 + wb); \
        gl16(mP[3] + ao, dA + 3 * 4096 + wb); gl16(hP[3] + bo, dB + 3 * 4096 + wb); \
    } \
} while (0)

    STAGE_GO(0, 0);
    STAGE_GO(1, 1);
    for (int kt = 0; kt < 16; ++kt) {
        if (kt < 15) PIPE_WAIT(8); else PIPE_WAIT(0);
        const h16* A = As[kt & 1];
        const h16* B = Bh[kt & 1];
        #pragma unroll
        for (int s = 0; s < 2; ++s) {
            const int c = s * 32 + ko;
            f16x8 a[4];
            #pragma unroll
            for (int fm = 0; fm < 4; ++fm)
                a[fm] = lds_frag(A, wm + fm * 16 + ln, c, kk);
            #pragma unroll
            for (int fn = 0; fn < 4; ++fn) {
                f16x8 vh = lds_frag(B, wn + fn * 16 + ln, c, kk);
                #pragma unroll
                for (int fm = 0; fm < 4; ++fm)
                    acc[fm][fn] = MFMA16(a[fm], vh, acc[fm][fn]);
            }
        }
        PIPE_POST();
        if (kt + 2 < 16) STAGE_GO(kt + 2, kt & 1);
    }
#undef STAGE_GO

    const int lm = (lane >> 4) * 4;
    #pragma unroll
    for (int fm = 0; fm < 4; ++fm) {
        #pragma unroll
        for (int fn = 0; fn < 4; ++fn) {
            int n = bn + wn + fn * 16 + ln;
            float bias = bgo[n];
            #pragma unroll
            for (int i = 0; i < 4; ++i) {
                int m = bm + wm + fm * 16 + lm + i;
                float t = acc[fm][fn][i] + bias;
                float g = 0.5f * t * (1.0f + erff(t * 0.70710678118654752f));
                int nsw = (((n >> 3) ^ (m & 7)) << 3) | (n & 7);
                yh[(size_t)m * DM + nsw] = (h16)g;
            }
        }
    }
}

// ---------------------------------------------------------------------------
// GEMM3: [M2 x 512] x [512 x 1024(packed 2 groups)] + GLU -> out (fp32).
// Double-buffered issue-early pipeline.
// ---------------------------------------------------------------------------
__global__ __launch_bounds__(256) WAVES_EU(2, 2) void gemm_out_mfma(
    const h16* __restrict__ yh, const h16* __restrict__ Wh,
    const float* __restrict__ bout, float* __restrict__ out)
{
    __shared__ __align__(16) h16 As[2][128 * 64];
    __shared__ __align__(16) h16 Bh[2][128 * 64];

    int bx, by; xcd_remap(bx, by);
    const int tid = threadIdx.x, lane = tid & 63, w = tid >> 6;
    const int wm = (w & 1) * 64, wn = (w >> 1) * 64;
    const int bm = bx * 128;
    const int ln = lane & 15, ko = (lane >> 4) * 8;
    const int kk = ln & 7;
    const int wb = w * 1024;

    const char *aP[4], *hP[4];
    {
        const int r8 = lane >> 3, c16 = (lane & 7) * 16;
        #pragma unroll
        for (int i = 0; i < 4; ++i) {
            int row = i * 32 + w * 8 + r8;
            aP[i] = (const char*)yh + (size_t)(bm + row) * (DM * 2) + c16;
            size_t br = (size_t)(by * 128 + row) * (DM * 2) + c16;
            hP[i] = (const char*)Wh + br;
        }
    }

    f32x4 acc[4][4];
    #pragma unroll
    for (int i = 0; i < 4; ++i)
        #pragma unroll
        for (int j = 0; j < 4; ++j) acc[i][j] = (f32x4){0.f, 0.f, 0.f, 0.f};

#define STAGE_OUT(koff, sel) do { \
    char* dA = (char*)As[sel]; char* dB = (char*)Bh[sel]; \
    gl16(aP[0] + (koff), dA + 0 * 4096 + wb); gl16(hP[0] + (koff), dB + 0 * 4096 + wb); \
    gl16(aP[1] + (koff), dA + 1 * 4096 + wb); gl16(hP[1] + (koff), dB + 1 * 4096 + wb); \
    gl16(aP[2] + (koff), dA + 2 * 4096 + wb); gl16(hP[2] + (koff), dB + 2 * 4096 + wb); \
    gl16(aP[3] + (koff), dA + 3 * 4096 + wb); gl16(hP[3] + (koff), dB + 3 * 4096 + wb); \
} while (0)

    STAGE_OUT(0, 0);
    STAGE_OUT(128, 1);
    for (int kt = 0; kt < 8; ++kt) {
        if (kt < 7) PIPE_WAIT(8); else PIPE_WAIT(0);
        const h16* A = As[kt & 1];
        const h16* B = Bh[kt & 1];
        #pragma unroll
        for (int s = 0; s < 2; ++s) {
            const int c = s * 32 + ko;
            f16x8 a[4];
            #pragma unroll
            for (int fm = 0; fm < 4; ++fm)
                a[fm] = lds_frag(A, wm + fm * 16 + ln, c, kk);
            #pragma unroll
            for (int fn = 0; fn < 4; ++fn) {
                f16x8 vh = lds_frag(B, wn + fn * 16 + ln, c, kk);
                #pragma unroll
                for (int fm = 0; fm < 4; ++fm)
                    acc[fm][fn] = MFMA16(a[fm], vh, acc[fm][fn]);
            }
        }
        PIPE_POST();
        if (kt + 2 < 8) STAGE_OUT((kt + 2) * 128, kt & 1);
    }
#undef STAGE_OUT

    const int lm = (lane >> 4) * 4;
    #pragma unroll
    for (int fm = 0; fm < 4; ++fm) {
        #pragma unroll
        for (int cp = 0; cp < 2; ++cp) {
            int ncol = by * 64 + ((wn >> 5) + cp) * 16 + ln;
            float bz0 = bout[ncol], bz1 = bout[ncol + 512];
            #pragma unroll
            for (int i = 0; i < 4; ++i) {
                int m = bm + wm + fm * 16 + lm + i;
                float z0 = acc[fm][cp * 2 + 0][i] + bz0;
                float z1 = acc[fm][cp * 2 + 1][i] + bz1;
                out[(size_t)m * DM + ncol] = z0 * (1.0f / (1.0f + expf(-z1)));
            }
        }
    }
}

// ---------------------------------------------------------------------------
extern "C" void kernel_launch(void* const* d_in, const int* in_sizes, int n_in,
                              void* d_out, int out_size, void* d_ws, size_t ws_size,
                              hipStream_t stream)
{
    const float* x    = (const float*)d_in[0];
    const float* Wav  = (const float*)d_in[1];
    const float* bav  = (const float*)d_in[2];
    const float* Wgo  = (const float*)d_in[3];
    const float* bgo  = (const float*)d_in[4];
    const float* Wout = (const float*)d_in[5];
    const float* bout = (const float*)d_in[6];
    float* out = (float*)d_out;

    char* ws = (char*)d_ws;
    const size_t MB = 1 << 20;
    h16*   ms_inp = (h16*)ws;                     // 32 MiB [32764,512] fp16
    h16*   yh     = (h16*)(ws + 32 * MB);         // 32 MiB (after scan)
    h16*   xh     = (h16*)(ws + 64 * MB);         // 32 MiB (swizzled fp16)
    h16*   msh    = (h16*)(ws + 96 * MB);         // 32 MiB (swizzled fp16)
    h16*   Wavh   = (h16*)(ws + 129 * MB);        // 2 MiB (packed+swizzled)
    h16*   Wgoh   = (h16*)(ws + 131 * MB);        // 1 MiB
    h16*   Wouth  = (h16*)(ws + 132 * MB);        // 1 MiB
    float* csum   = (float*)(ws + 133 * MB);      // 2 MiB [B][256][512] f32

    // 0) precompute fp16 forms (one launch)
    prep_all<<<9216, 256, 0, stream>>>(x, Wgo, Wav, Wout, xh, Wgoh, Wavh, Wouth);
    // 1) av GEMM + NRU combine -> ms_inp (fp16)
    gemm_av_mfma<<<dim3(256, 16), 256, 0, stream>>>(xh, Wavh, bav, ms_inp);
    // 2-4) chunked cumsum -> msh (fp16, swizzled)
    scan_pass1<<<dim3(64, B_SZ), 256, 0, stream>>>(ms_inp, csum);
    scan_pass2<<<2048, 256, 0, stream>>>(csum);
    scan_pass3<<<dim3(64, B_SZ), 256, 0, stream>>>(ms_inp, csum, msh);
    // 5) SSM-in GEMM + GELU -> yh (fp16 swizzled)
    gemm_go_mfma<<<dim3(256, 4), 256, 0, stream>>>(xh, msh, Wgoh, bgo, yh);
    // 6) output GEMM + GLU -> out (f32)
    gemm_out_mfma<<<dim3(256, 8), 256, 0, stream>>>(yh, Wouth, bout, out);
}